// Round 1
// baseline (2852.258 us; speedup 1.0000x reference)
//
#include <hip/hip_runtime.h>
#include <hip/hip_bf16.h>
#include <math.h>

#define NB 2
#define NS 2048
#define ND 1024
#define NH 16
#define NHD 64
#define NDFF 4096

typedef __attribute__((ext_vector_type(4))) float f32x4;
typedef __attribute__((ext_vector_type(8))) short bf16x8;

__device__ __forceinline__ short f2bf(float f) {
  union { float f; unsigned u; } v; v.f = f;
  unsigned r = v.u + 0x7fffu + ((v.u >> 16) & 1u);
  return (short)(r >> 16);
}
__device__ __forceinline__ float bf2f(unsigned short u) {
  union { unsigned u; float f; } v; v.u = ((unsigned)u) << 16; return v.f;
}
__device__ __forceinline__ float softplus_f(float x) {
  return fmaxf(x, 0.f) + log1pf(__expf(-fabsf(x)));
}

// ---------------- GEMM: C = A @ W + bias (optional relu). A: MxK (f32 or bf16),
// W: KxN f32 (converted to bf16 during LDS staging, stored transposed [n][k]).
#define BM 128
#define BN 128
#define BKK 32
#define LDK 40  // padded LDS row stride in shorts (80B: 16B-aligned, breaks bank pattern)

template<int AF32, int RELU, int OUTBF16>
__device__ __forceinline__ void gemm_body(const void* __restrict__ Av,
    const float* __restrict__ W, const float* __restrict__ bias,
    void* __restrict__ Cv, int M, int N, int K) {
  __shared__ short lsA[BM][LDK];
  __shared__ short lsB[BN][LDK];
  const int tid = threadIdx.x;
  const int row0 = blockIdx.y * BM, col0 = blockIdx.x * BN;
  const int wave = tid >> 6, lane = tid & 63;
  const int wr = wave >> 1, wc = wave & 1;            // 2x2 waves of 64x64
  const int lr = lane & 15, lk8 = (lane >> 4) << 3;   // fragment row/col + k-group
  const int arow = tid >> 1, akb = (tid & 1) << 4;    // A staging map
  const int bkk = tid >> 3, bnb = (tid & 7) << 4;     // W staging map
  f32x4 acc[4][4];
#pragma unroll
  for (int m = 0; m < 4; m++)
#pragma unroll
    for (int n = 0; n < 4; n++) acc[m][n] = 0.f;

  for (int k0 = 0; k0 < K; k0 += BKK) {
    if (AF32) {
      const float* src = (const float*)Av + (size_t)(row0 + arow) * K + k0 + akb;
#pragma unroll
      for (int i = 0; i < 4; i++) {
        float4 t = ((const float4*)src)[i];
        lsA[arow][akb + 4*i + 0] = f2bf(t.x);
        lsA[arow][akb + 4*i + 1] = f2bf(t.y);
        lsA[arow][akb + 4*i + 2] = f2bf(t.z);
        lsA[arow][akb + 4*i + 3] = f2bf(t.w);
      }
    } else {
      const short* src = (const short*)Av + (size_t)(row0 + arow) * K + k0 + akb;
      ((int4*)&lsA[arow][akb])[0] = ((const int4*)src)[0];
      ((int4*)&lsA[arow][akb])[1] = ((const int4*)src)[1];
    }
    {
      const float* srcw = W + (size_t)(k0 + bkk) * N + col0 + bnb;
#pragma unroll
      for (int i = 0; i < 4; i++) {
        float4 t = ((const float4*)srcw)[i];
        lsB[bnb + 4*i + 0][bkk] = f2bf(t.x);
        lsB[bnb + 4*i + 1][bkk] = f2bf(t.y);
        lsB[bnb + 4*i + 2][bkk] = f2bf(t.z);
        lsB[bnb + 4*i + 3][bkk] = f2bf(t.w);
      }
    }
    __syncthreads();
    bf16x8 af[4], bfg[4];
#pragma unroll
    for (int m = 0; m < 4; m++)
      af[m] = *(const bf16x8*)&lsA[wr*64 + m*16 + lr][lk8];
#pragma unroll
    for (int n = 0; n < 4; n++)
      bfg[n] = *(const bf16x8*)&lsB[wc*64 + n*16 + lr][lk8];
#pragma unroll
    for (int m = 0; m < 4; m++)
#pragma unroll
      for (int n = 0; n < 4; n++)
        acc[m][n] = __builtin_amdgcn_mfma_f32_16x16x32_bf16(af[m], bfg[n], acc[m][n], 0, 0, 0);
    __syncthreads();
  }
  const int r4 = (lane >> 4) << 2;
#pragma unroll
  for (int m = 0; m < 4; m++) {
#pragma unroll
    for (int n = 0; n < 4; n++) {
      const int col = col0 + wc*64 + n*16 + lr;
      const float bv = bias[col];
#pragma unroll
      for (int r = 0; r < 4; r++) {
        const int row = row0 + wr*64 + m*16 + r4 + r;
        float val = acc[m][n][r] + bv;
        if (RELU) val = fmaxf(val, 0.f);
        if (OUTBF16) ((short*)Cv)[(size_t)row * N + col] = f2bf(val);
        else ((float*)Cv)[(size_t)row * N + col] = val;
      }
    }
  }
}

__global__ __launch_bounds__(256) void k_qkv(const float* __restrict__ x,
    const float* wq, const float* bq, float* q,
    const float* wk, const float* bk, float* k,
    const float* wv, const float* bv, float* v) {
  const float* W; const float* bs; float* C;
  if (blockIdx.z == 0)      { W = wq; bs = bq; C = q; }
  else if (blockIdx.z == 1) { W = wk; bs = bk; C = k; }
  else                      { W = wv; bs = bv; C = v; }
  gemm_body<1, 0, 0>(x, W, bs, C, NB*NS, ND, ND);
}
__global__ __launch_bounds__(256) void k_gemm_f32(const float* A, const float* W,
    const float* bs, float* C, int M, int N, int K) {
  gemm_body<1, 0, 0>(A, W, bs, C, M, N, K);
}
__global__ __launch_bounds__(256) void k_gemm_relu_bf16(const float* A, const float* W,
    const float* bs, short* C, int M, int N, int K) {
  gemm_body<1, 1, 1>(A, W, bs, C, M, N, K);
}
__global__ __launch_bounds__(256) void k_gemm_bf16a(const short* A, const float* W,
    const float* bs, float* C, int M, int N, int K) {
  gemm_body<0, 0, 0>(A, W, bs, C, M, N, K);
}

// ---------------- PoPE ----------------
// q buffer layout from GEMM: [b][s][h][hd]. qp out: [b][h][s][128] f32.
__global__ __launch_bounds__(256) void k_pope_q(const float* __restrict__ q,
    const int* __restrict__ positions, float* __restrict__ qp) {
  size_t t = (size_t)blockIdx.x * 256 + threadIdx.x;
  const int d = (int)(t & 63);
  const int h = (int)((t >> 6) & 15);
  const int s = (int)((t >> 10) & 2047);
  const int b = (int)(t >> 21);
  const float val = q[t];
  const float mu = softplus_f(val);
  const float freq = __expf(-(float)d * (float)(9.210340371976184 / 64.0));
  const float ph = (float)positions[s] * freq;
  float sn, cs; sincosf(ph, &sn, &cs);
  const size_t o = (((size_t)(b*16 + h) * NS + s) * 128) + d;
  qp[o] = mu * cs;
  qp[o + 64] = mu * sn;
}

// kp out: TRANSPOSED [b][h][d(128)][s] f32 so attention staging is coalesced.
__global__ __launch_bounds__(256) void k_pope_k(const float* __restrict__ kin,
    const int* __restrict__ positions, const float* __restrict__ phb,
    float* __restrict__ kp) {
  __shared__ float tile[128][65];
  const int bh = blockIdx.y, b = bh >> 4, h = bh & 15;
  const int s0 = blockIdx.x * 64;
  for (int i = threadIdx.x; i < 64 * 64; i += 256) {
    const int d = i & 63, sl = i >> 6;
    const float val = kin[(((size_t)b * NS + s0 + sl) * NH + h) * NHD + d];
    const float mu = softplus_f(val);
    const float freq = __expf(-(float)d * (float)(9.210340371976184 / 64.0));
    float cb = phb[h * 64 + d];
    cb = fminf(fmaxf(cb, -6.283185307179586f), 0.f);
    const float ph = (float)positions[s0 + sl] * freq + cb;
    float sn, cs; sincosf(ph, &sn, &cs);
    tile[d][sl] = mu * cs;
    tile[d + 64][sl] = mu * sn;
  }
  __syncthreads();
  for (int i = threadIdx.x; i < 128 * 64; i += 256) {
    const int d = i >> 6, sl = i & 63;
    kp[((size_t)(bh * 128 + d)) * NS + s0 + sl] = tile[d][sl];
  }
}

// ---------------- Attention (causal, softmax1) ----------------
// block = (b,h, 32 q-rows); 4 waves x 8 rows; 64-key chunks staged in LDS.
__global__ __launch_bounds__(256) void k_attn(const float* __restrict__ qp,
    const float* __restrict__ kp, const float* __restrict__ v,
    float* __restrict__ attn) {
  __shared__ float kp_l[128][64];          // 32KB, [d][j]
  __shared__ unsigned short v_l[64][64];   // 8KB bf16, [j][dd]
  __shared__ float qp_l[32][128];          // 16KB
  __shared__ float p_l[4][64];             // 1KB
  const int bh = blockIdx.y, b = bh >> 4, h = bh & 15;
  const int q0 = (int)(gridDim.x - 1 - blockIdx.x) * 32;  // big tiles first
  const int tid = threadIdx.x, wave = tid >> 6, lane = tid & 63;
  const float* qpb = qp + ((size_t)bh * NS + q0) * 128;
  for (int i = tid; i < 32 * 128; i += 256) qp_l[i >> 7][i & 127] = qpb[i];
  const float* kpb = kp + (size_t)bh * 128 * NS;
  const float* vb = v + ((size_t)b * NS * NH + h) * NHD;
  float mr[8], lsum[8], O[8];
#pragma unroll
  for (int r = 0; r < 8; r++) { mr[r] = -INFINITY; lsum[r] = 0.f; O[r] = 0.f; }
  const int nch = (q0 + 31) / 64 + 1;
  for (int c = 0; c < nch; c++) {
    const int kb = c * 64;
    for (int i = tid; i < 128 * 64; i += 256) {
      const int d = i >> 6, j = i & 63;
      kp_l[d][j] = kpb[(size_t)d * NS + kb + j];
    }
    for (int i = tid; i < 64 * 64; i += 256) {
      const int j = i >> 6, dd = i & 63;
      v_l[j][dd] = (unsigned short)f2bf(vb[(size_t)(kb + j) * (NH*NHD) + dd]);
    }
    __syncthreads();
#pragma unroll
    for (int r = 0; r < 8; r++) {
      const int qrow = wave * 8 + r;
      const int qi = q0 + qrow;
      if (qi >= kb) {
        float s0 = 0.f, s1 = 0.f, s2 = 0.f, s3 = 0.f;
#pragma unroll 8
        for (int d = 0; d < 128; d += 4) {
          s0 += qp_l[qrow][d + 0] * kp_l[d + 0][lane];
          s1 += qp_l[qrow][d + 1] * kp_l[d + 1][lane];
          s2 += qp_l[qrow][d + 2] * kp_l[d + 2][lane];
          s3 += qp_l[qrow][d + 3] * kp_l[d + 3][lane];
        }
        float sc = ((s0 + s1) + (s2 + s3)) * 0.08838834764831845f;
        const bool valid = (kb + lane) <= qi;
        sc = valid ? sc : -INFINITY;
        float cm = sc;
#pragma unroll
        for (int off = 32; off; off >>= 1) cm = fmaxf(cm, __shfl_xor(cm, off));
        const float nm = fmaxf(mr[r], cm);
        const float fac = __expf(mr[r] - nm);   // first chunk: exp(-inf)=0
        const float p = valid ? __expf(sc - nm) : 0.f;
        float cs = p;
#pragma unroll
        for (int off = 32; off; off >>= 1) cs += __shfl_xor(cs, off);
        lsum[r] = lsum[r] * fac + cs;
        mr[r] = nm;
        p_l[wave][lane] = p;
        float o0 = 0.f, o1 = 0.f, o2 = 0.f, o3 = 0.f;
#pragma unroll 4
        for (int j = 0; j < 64; j += 4) {
          o0 += p_l[wave][j + 0] * bf2f(v_l[j + 0][lane]);
          o1 += p_l[wave][j + 1] * bf2f(v_l[j + 1][lane]);
          o2 += p_l[wave][j + 2] * bf2f(v_l[j + 2][lane]);
          o3 += p_l[wave][j + 3] * bf2f(v_l[j + 3][lane]);
        }
        O[r] = O[r] * fac + ((o0 + o1) + (o2 + o3));
      }
    }
    __syncthreads();
  }
#pragma unroll
  for (int r = 0; r < 8; r++) {
    const int qi = q0 + wave * 8 + r;
    const float denom = __expf(-mr[r]) + lsum[r];
    attn[((size_t)(b * NS + qi) * NH + h) * NHD + lane] = O[r] / denom;
  }
}

// ---------------- LayerNorm: out = LN(A + R) * g + be ----------------
__global__ __launch_bounds__(256) void k_ln(const float* __restrict__ A,
    const float* __restrict__ R, const float* __restrict__ g,
    const float* __restrict__ be, float* __restrict__ out) {
  const int row = blockIdx.x, tid = threadIdx.x;
  const float4 a = ((const float4*)(A + (size_t)row * ND))[tid];
  const float4 r = ((const float4*)(R + (size_t)row * ND))[tid];
  const float x0 = a.x + r.x, x1 = a.y + r.y, x2 = a.z + r.z, x3 = a.w + r.w;
  float s = x0 + x1 + x2 + x3;
  float sq = x0*x0 + x1*x1 + x2*x2 + x3*x3;
#pragma unroll
  for (int off = 32; off; off >>= 1) {
    s  += __shfl_xor(s, off);
    sq += __shfl_xor(sq, off);
  }
  __shared__ float ss[4], ssq[4];
  const int wave = tid >> 6, lane = tid & 63;
  if (lane == 0) { ss[wave] = s; ssq[wave] = sq; }
  __syncthreads();
  s = ss[0] + ss[1] + ss[2] + ss[3];
  sq = ssq[0] + ssq[1] + ssq[2] + ssq[3];
  const float mu = s * (1.f / (float)ND);
  const float var = sq * (1.f / (float)ND) - mu * mu;
  const float rstd = rsqrtf(var + 1e-5f);
  const float4 gg = ((const float4*)g)[tid];
  const float4 bb = ((const float4*)be)[tid];
  float4 o;
  o.x = (x0 - mu) * rstd * gg.x + bb.x;
  o.y = (x1 - mu) * rstd * gg.y + bb.y;
  o.z = (x2 - mu) * rstd * gg.z + bb.z;
  o.w = (x3 - mu) * rstd * gg.w + bb.w;
  ((float4*)(out + (size_t)row * ND))[tid] = o;
}

extern "C" void kernel_launch(void* const* d_in, const int* in_sizes, int n_in,
                              void* d_out, int out_size, void* d_ws, size_t ws_size,
                              hipStream_t stream) {
  const float* x   = (const float*)d_in[0];
  const int*   pos = (const int*)d_in[1];
  const float* wq  = (const float*)d_in[2];
  const float* bq  = (const float*)d_in[3];
  const float* wk  = (const float*)d_in[4];
  const float* bk  = (const float*)d_in[5];
  const float* wv  = (const float*)d_in[6];
  const float* bv  = (const float*)d_in[7];
  const float* wo  = (const float*)d_in[8];
  const float* bo  = (const float*)d_in[9];
  const float* phb = (const float*)d_in[10];
  const float* w1  = (const float*)d_in[11];
  const float* b1  = (const float*)d_in[12];
  const float* w2  = (const float*)d_in[13];
  const float* b2  = (const float*)d_in[14];
  const float* g1  = (const float*)d_in[15];
  const float* be1 = (const float*)d_in[16];
  const float* g2  = (const float*)d_in[17];
  const float* be2 = (const float*)d_in[18];

  char* ws = (char*)d_ws;
  const size_t MB = 1024 * 1024;
  if (ws_size < 112 * MB) return;
  float* qb    = (float*)(ws + 0 * MB);     // 16MB
  float* kbuf  = (float*)(ws + 16 * MB);    // 16MB
  float* vbuf  = (float*)(ws + 32 * MB);    // 16MB
  float* qp    = (float*)(ws + 48 * MB);    // 32MB
  float* kp    = (float*)(ws + 80 * MB);    // 32MB -> ends 112MB
  float* attnb = (float*)(ws + 0 * MB);     // reuse qb
  float* attnC = (float*)(ws + 16 * MB);    // reuse kbuf
  float* hbuf  = (float*)(ws + 48 * MB);    // reuse qp (dead after attn)
  short* ffh   = (short*)(ws + 80 * MB);    // reuse kp (dead after attn), 32MB bf16
  float* ffC   = (float*)(ws + 32 * MB);    // reuse vbuf

  dim3 blk(256);
  k_qkv<<<dim3(ND / BN, (NB * NS) / BM, 3), blk, 0, stream>>>(
      x, wq, bq, qb, wk, bk, kbuf, wv, bv, vbuf);
  k_pope_q<<<dim3((NB * NS * ND) / 256), blk, 0, stream>>>(qb, pos, qp);
  k_pope_k<<<dim3(NS / 64, NB * NH), blk, 0, stream>>>(kbuf, pos, phb, kp);
  k_attn<<<dim3(NS / 32, NB * NH), blk, 0, stream>>>(qp, kp, vbuf, attnb);
  k_gemm_f32<<<dim3(ND / BN, (NB * NS) / BM), blk, 0, stream>>>(
      attnb, wo, bo, attnC, NB * NS, ND, ND);
  k_ln<<<dim3(NB * NS), blk, 0, stream>>>(x, attnC, g1, be1, hbuf);
  k_gemm_relu_bf16<<<dim3(NDFF / BN, (NB * NS) / BM), blk, 0, stream>>>(
      hbuf, w1, b1, ffh, NB * NS, NDFF, ND);
  k_gemm_bf16a<<<dim3(ND / BN, (NB * NS) / BM), blk, 0, stream>>>(
      ffh, w2, b2, ffC, NB * NS, ND, NDFF);
  k_ln<<<dim3(NB * NS), blk, 0, stream>>>(hbuf, ffC, g2, be2, (float*)d_out);
}

// Round 2
// 685.682 us; speedup vs baseline: 4.1597x; 4.1597x over previous
//
#include <hip/hip_runtime.h>
#include <hip/hip_bf16.h>
#include <math.h>

#define NB 2
#define NS 2048
#define ND 1024
#define NH 16
#define NHD 64
#define NDFF 4096

typedef __attribute__((ext_vector_type(4))) float f32x4;
typedef __attribute__((ext_vector_type(8))) short bf16x8;

__device__ __forceinline__ short f2bf(float f) {
  union { float f; unsigned u; } v; v.f = f;
  unsigned r = v.u + 0x7fffu + ((v.u >> 16) & 1u);
  return (short)(r >> 16);
}
__device__ __forceinline__ float bf2f(unsigned short u) {
  union { unsigned u; float f; } v; v.u = ((unsigned)u) << 16; return v.f;
}
__device__ __forceinline__ float softplus_f(float x) {
  return fmaxf(x, 0.f) + log1pf(__expf(-fabsf(x)));
}

// ---------------- GEMM: C = A @ W + bias (optional relu). A: MxK (f32 or bf16),
// W: KxN f32 (converted to bf16 during LDS staging, stored transposed [n][k]).
#define BM 128
#define BN 128
#define BKK 32
#define LDK 40  // padded LDS row stride in shorts

template<int AF32, int RELU, int OUTBF16>
__device__ __forceinline__ void gemm_body(const void* __restrict__ Av,
    const float* __restrict__ W, const float* __restrict__ bias,
    void* __restrict__ Cv, int M, int N, int K) {
  __shared__ short lsA[BM][LDK];
  __shared__ short lsB[BN][LDK];
  const int tid = threadIdx.x;
  const int row0 = blockIdx.y * BM, col0 = blockIdx.x * BN;
  const int wave = tid >> 6, lane = tid & 63;
  const int wr = wave >> 1, wc = wave & 1;            // 2x2 waves of 64x64
  const int lr = lane & 15, lk8 = (lane >> 4) << 3;   // fragment row/col + k-group
  const int arow = tid >> 1, akb = (tid & 1) << 4;    // A staging map
  const int bkk = tid >> 3, bnb = (tid & 7) << 4;     // W staging map
  f32x4 acc[4][4];
#pragma unroll
  for (int m = 0; m < 4; m++)
#pragma unroll
    for (int n = 0; n < 4; n++) acc[m][n] = 0.f;

  for (int k0 = 0; k0 < K; k0 += BKK) {
    if (AF32) {
      const float* src = (const float*)Av + (size_t)(row0 + arow) * K + k0 + akb;
#pragma unroll
      for (int i = 0; i < 4; i++) {
        float4 t = ((const float4*)src)[i];
        lsA[arow][akb + 4*i + 0] = f2bf(t.x);
        lsA[arow][akb + 4*i + 1] = f2bf(t.y);
        lsA[arow][akb + 4*i + 2] = f2bf(t.z);
        lsA[arow][akb + 4*i + 3] = f2bf(t.w);
      }
    } else {
      const short* src = (const short*)Av + (size_t)(row0 + arow) * K + k0 + akb;
      ((int4*)&lsA[arow][akb])[0] = ((const int4*)src)[0];
      ((int4*)&lsA[arow][akb])[1] = ((const int4*)src)[1];
    }
    {
      const float* srcw = W + (size_t)(k0 + bkk) * N + col0 + bnb;
#pragma unroll
      for (int i = 0; i < 4; i++) {
        float4 t = ((const float4*)srcw)[i];
        lsB[bnb + 4*i + 0][bkk] = f2bf(t.x);
        lsB[bnb + 4*i + 1][bkk] = f2bf(t.y);
        lsB[bnb + 4*i + 2][bkk] = f2bf(t.z);
        lsB[bnb + 4*i + 3][bkk] = f2bf(t.w);
      }
    }
    __syncthreads();
    bf16x8 af[4], bfg[4];
#pragma unroll
    for (int m = 0; m < 4; m++)
      af[m] = *(const bf16x8*)&lsA[wr*64 + m*16 + lr][lk8];
#pragma unroll
    for (int n = 0; n < 4; n++)
      bfg[n] = *(const bf16x8*)&lsB[wc*64 + n*16 + lr][lk8];
#pragma unroll
    for (int m = 0; m < 4; m++)
#pragma unroll
      for (int n = 0; n < 4; n++)
        acc[m][n] = __builtin_amdgcn_mfma_f32_16x16x32_bf16(af[m], bfg[n], acc[m][n], 0, 0, 0);
    __syncthreads();
  }
  const int r4 = (lane >> 4) << 2;
#pragma unroll
  for (int m = 0; m < 4; m++) {
#pragma unroll
    for (int n = 0; n < 4; n++) {
      const int col = col0 + wc*64 + n*16 + lr;
      const float bv = bias[col];
#pragma unroll
      for (int r = 0; r < 4; r++) {
        const int row = row0 + wr*64 + m*16 + r4 + r;
        float val = acc[m][n][r] + bv;
        if (RELU) val = fmaxf(val, 0.f);
        if (OUTBF16) ((short*)Cv)[(size_t)row * N + col] = f2bf(val);
        else ((float*)Cv)[(size_t)row * N + col] = val;
      }
    }
  }
}

__global__ __launch_bounds__(256) void k_qkv(const float* __restrict__ x,
    const float* wq, const float* bq, float* q,
    const float* wk, const float* bk, float* k,
    const float* wv, const float* bv, float* v) {
  const float* W; const float* bs; float* C;
  if (blockIdx.z == 0)      { W = wq; bs = bq; C = q; }
  else if (blockIdx.z == 1) { W = wk; bs = bk; C = k; }
  else                      { W = wv; bs = bv; C = v; }
  gemm_body<1, 0, 0>(x, W, bs, C, NB*NS, ND, ND);
}
__global__ __launch_bounds__(256) void k_gemm_f32(const float* A, const float* W,
    const float* bs, float* C, int M, int N, int K) {
  gemm_body<1, 0, 0>(A, W, bs, C, M, N, K);
}
__global__ __launch_bounds__(256) void k_gemm_relu_bf16(const float* A, const float* W,
    const float* bs, short* C, int M, int N, int K) {
  gemm_body<1, 1, 1>(A, W, bs, C, M, N, K);
}
__global__ __launch_bounds__(256) void k_gemm_bf16a(const short* A, const float* W,
    const float* bs, float* C, int M, int N, int K) {
  gemm_body<0, 0, 0>(A, W, bs, C, M, N, K);
}

// ---------------- PoPE ----------------
// q buffer layout from GEMM: [b][s][h][hd]. qp out: [b][h][s][128] bf16.
__global__ __launch_bounds__(256) void k_pope_q(const float* __restrict__ q,
    const int* __restrict__ positions, short* __restrict__ qp) {
  size_t t = (size_t)blockIdx.x * 256 + threadIdx.x;
  const int d = (int)(t & 63);
  const int h = (int)((t >> 6) & 15);
  const int s = (int)((t >> 10) & 2047);
  const int b = (int)(t >> 21);
  const float val = q[t];
  const float mu = softplus_f(val);
  const float freq = __expf(-(float)d * (float)(9.210340371976184 / 64.0));
  const float ph = (float)positions[s] * freq;
  float sn, cs; sincosf(ph, &sn, &cs);
  const size_t o = (((size_t)(b*16 + h) * NS + s) * 128) + d;
  qp[o] = f2bf(mu * cs);
  qp[o + 64] = f2bf(mu * sn);
}

// kp out: [b][h][s][128] bf16 (with clamped phase bias).
__global__ __launch_bounds__(256) void k_pope_k(const float* __restrict__ kin,
    const int* __restrict__ positions, const float* __restrict__ phb,
    short* __restrict__ kp) {
  size_t t = (size_t)blockIdx.x * 256 + threadIdx.x;
  const int d = (int)(t & 63);
  const int h = (int)((t >> 6) & 15);
  const int s = (int)((t >> 10) & 2047);
  const int b = (int)(t >> 21);
  const float val = kin[t];
  const float mu = softplus_f(val);
  const float freq = __expf(-(float)d * (float)(9.210340371976184 / 64.0));
  float cb = phb[h * 64 + d];
  cb = fminf(fmaxf(cb, -6.283185307179586f), 0.f);
  const float ph = (float)positions[s] * freq + cb;
  float sn, cs; sincosf(ph, &sn, &cs);
  const size_t o = (((size_t)(b*16 + h) * NS + s) * 128) + d;
  kp[o] = f2bf(mu * cs);
  kp[o + 64] = f2bf(mu * sn);
}

// V pre-transpose: v [b][s][h][64] f32 -> vt [b][h][64][s] bf16.
__global__ __launch_bounds__(256) void k_prep_v(const float* __restrict__ v,
    short* __restrict__ vt) {
  __shared__ float tile[64][65];
  const int bh = blockIdx.y, b = bh >> 4, h = bh & 15;
  const int s0 = blockIdx.x * 64;
  for (int i = threadIdx.x; i < 64 * 64; i += 256) {
    const int d = i & 63, sl = i >> 6;
    tile[d][sl] = v[(((size_t)b * NS + s0 + sl) * NH + h) * NHD + d];
  }
  __syncthreads();
  for (int i = threadIdx.x; i < 64 * 64; i += 256) {
    const int d = i >> 6, sl = i & 63;
    vt[((size_t)bh * 64 + d) * NS + s0 + sl] = f2bf(tile[d][sl]);
  }
}

// ---------------- Attention (causal, softmax1), MFMA flash ----------------
// block = (b,h, 64 q-rows); 4 waves x 16 rows; 64-key chunks.
__global__ __launch_bounds__(256) void k_attn_mfma(
    const short* __restrict__ qp, const short* __restrict__ kp,
    const short* __restrict__ vt, short* __restrict__ attn) {
  __shared__ short q_l[64][136];
  __shared__ short kp_l[64][136];
  __shared__ short v_l[64][72];
  __shared__ short p_l[4][16][72];
  const int bh = blockIdx.y, b = bh >> 4, h = bh & 15;
  const int q0 = (int)(gridDim.x - 1 - blockIdx.x) * 64;  // heavy tiles first
  const int tid = threadIdx.x, wave = tid >> 6, lane = tid & 63;
  const int lr = lane & 15, lk = lane >> 4;
  {
    const short* src = qp + ((size_t)bh * NS + q0) * 128;
    for (int i = tid; i < 64 * 16; i += 256) {
      const int r = i >> 4, c8 = (i & 15) * 8;
      *(bf16x8*)&q_l[r][c8] = *(const bf16x8*)&src[r * 128 + c8];
    }
  }
  __syncthreads();
  bf16x8 aq[4];
#pragma unroll
  for (int ks = 0; ks < 4; ks++)
    aq[ks] = *(const bf16x8*)&q_l[wave * 16 + lr][ks * 32 + lk * 8];

  f32x4 acc_o[4];
  float m_r[4], l_r[4];
#pragma unroll
  for (int r = 0; r < 4; r++) { m_r[r] = -INFINITY; l_r[r] = 0.f; }
#pragma unroll
  for (int n = 0; n < 4; n++) acc_o[n] = 0.f;

  const short* kpb = kp + (size_t)bh * NS * 128;
  const short* vtb = vt + (size_t)bh * 64 * NS;
  const int nch = q0 / 64 + 1;
  for (int c = 0; c < nch; c++) {
    const int kb = c * 64;
    for (int i = tid; i < 1024; i += 256) {
      const int r = i >> 4, c8 = (i & 15) * 8;
      *(bf16x8*)&kp_l[r][c8] = *(const bf16x8*)&kpb[(size_t)(kb + r) * 128 + c8];
    }
    for (int i = tid; i < 512; i += 256) {
      const int r = i >> 3, c8 = (i & 7) * 8;
      *(bf16x8*)&v_l[r][c8] = *(const bf16x8*)&vtb[(size_t)r * NS + kb + c8];
    }
    __syncthreads();
    // S = Q K^T  (per wave: 16 q-rows x 64 keys)
    f32x4 s_acc[4];
#pragma unroll
    for (int n = 0; n < 4; n++) s_acc[n] = 0.f;
#pragma unroll
    for (int ks = 0; ks < 4; ks++) {
      bf16x8 bk_[4];
#pragma unroll
      for (int n = 0; n < 4; n++)
        bk_[n] = *(const bf16x8*)&kp_l[n * 16 + lr][ks * 32 + lk * 8];
#pragma unroll
      for (int n = 0; n < 4; n++)
        s_acc[n] = __builtin_amdgcn_mfma_f32_16x16x32_bf16(aq[ks], bk_[n], s_acc[n], 0, 0, 0);
    }
    // online softmax1
    const float scale = 0.08838834764831845f;
    float pmax[4];
#pragma unroll
    for (int r = 0; r < 4; r++) pmax[r] = -INFINITY;
    const bool diag = (kb == q0);
#pragma unroll
    for (int n = 0; n < 4; n++) {
#pragma unroll
      for (int r = 0; r < 4; r++) {
        float sv = s_acc[n][r] * scale;
        if (diag) {
          const int col = n * 16 + lr;
          const int row = wave * 16 + lk * 4 + r;
          sv = (col <= row) ? sv : -INFINITY;
        }
        s_acc[n][r] = sv;
        pmax[r] = fmaxf(pmax[r], sv);
      }
    }
#pragma unroll
    for (int off = 8; off; off >>= 1)
#pragma unroll
      for (int r = 0; r < 4; r++) pmax[r] = fmaxf(pmax[r], __shfl_xor(pmax[r], off));
    float fac[4], rs[4];
#pragma unroll
    for (int r = 0; r < 4; r++) {
      const float nm = fmaxf(m_r[r], pmax[r]);
      fac[r] = __expf(m_r[r] - nm);
      m_r[r] = nm;
      rs[r] = 0.f;
    }
#pragma unroll
    for (int n = 0; n < 4; n++) {
#pragma unroll
      for (int r = 0; r < 4; r++) {
        const float p = __expf(s_acc[n][r] - m_r[r]);
        s_acc[n][r] = p;
        rs[r] += p;
      }
    }
#pragma unroll
    for (int off = 8; off; off >>= 1)
#pragma unroll
      for (int r = 0; r < 4; r++) rs[r] += __shfl_xor(rs[r], off);
#pragma unroll
    for (int r = 0; r < 4; r++) l_r[r] = l_r[r] * fac[r] + rs[r];
    // P -> wave-private LDS (same-wave RAW: ordered, no barrier)
#pragma unroll
    for (int n = 0; n < 4; n++)
#pragma unroll
      for (int r = 0; r < 4; r++)
        p_l[wave][lk * 4 + r][n * 16 + lr] = f2bf(s_acc[n][r]);
    // O rescale + PV
#pragma unroll
    for (int n = 0; n < 4; n++)
#pragma unroll
      for (int r = 0; r < 4; r++) acc_o[n][r] *= fac[r];
#pragma unroll
    for (int ks = 0; ks < 2; ks++) {
      const bf16x8 ap = *(const bf16x8*)&p_l[wave][lr][ks * 32 + lk * 8];
      bf16x8 bv_[4];
#pragma unroll
      for (int nd = 0; nd < 4; nd++)
        bv_[nd] = *(const bf16x8*)&v_l[nd * 16 + lr][ks * 32 + lk * 8];
#pragma unroll
      for (int nd = 0; nd < 4; nd++)
        acc_o[nd] = __builtin_amdgcn_mfma_f32_16x16x32_bf16(ap, bv_[nd], acc_o[nd], 0, 0, 0);
    }
    __syncthreads();
  }
  float inv[4];
#pragma unroll
  for (int r = 0; r < 4; r++) inv[r] = 1.f / (__expf(-m_r[r]) + l_r[r]);
#pragma unroll
  for (int nd = 0; nd < 4; nd++) {
#pragma unroll
    for (int r = 0; r < 4; r++) {
      const int row = q0 + wave * 16 + lk * 4 + r;
      const int d = nd * 16 + lr;
      attn[(((size_t)b * NS + row) * NH + h) * NHD + d] = f2bf(acc_o[nd][r] * inv[r]);
    }
  }
}

// ---------------- LayerNorm: out = LN(A + R) * g + be ----------------
__global__ __launch_bounds__(256) void k_ln(const float* __restrict__ A,
    const float* __restrict__ R, const float* __restrict__ g,
    const float* __restrict__ be, float* __restrict__ out) {
  const int row = blockIdx.x, tid = threadIdx.x;
  const float4 a = ((const float4*)(A + (size_t)row * ND))[tid];
  const float4 r = ((const float4*)(R + (size_t)row * ND))[tid];
  const float x0 = a.x + r.x, x1 = a.y + r.y, x2 = a.z + r.z, x3 = a.w + r.w;
  float s = x0 + x1 + x2 + x3;
  float sq = x0*x0 + x1*x1 + x2*x2 + x3*x3;
#pragma unroll
  for (int off = 32; off; off >>= 1) {
    s  += __shfl_xor(s, off);
    sq += __shfl_xor(sq, off);
  }
  __shared__ float ss[4], ssq[4];
  const int wave = tid >> 6, lane = tid & 63;
  if (lane == 0) { ss[wave] = s; ssq[wave] = sq; }
  __syncthreads();
  s = ss[0] + ss[1] + ss[2] + ss[3];
  sq = ssq[0] + ssq[1] + ssq[2] + ssq[3];
  const float mu = s * (1.f / (float)ND);
  const float var = sq * (1.f / (float)ND) - mu * mu;
  const float rstd = rsqrtf(var + 1e-5f);
  const float4 gg = ((const float4*)g)[tid];
  const float4 bb = ((const float4*)be)[tid];
  float4 o;
  o.x = (x0 - mu) * rstd * gg.x + bb.x;
  o.y = (x1 - mu) * rstd * gg.y + bb.y;
  o.z = (x2 - mu) * rstd * gg.z + bb.z;
  o.w = (x3 - mu) * rstd * gg.w + bb.w;
  ((float4*)(out + (size_t)row * ND))[tid] = o;
}

extern "C" void kernel_launch(void* const* d_in, const int* in_sizes, int n_in,
                              void* d_out, int out_size, void* d_ws, size_t ws_size,
                              hipStream_t stream) {
  const float* x   = (const float*)d_in[0];
  const int*   pos = (const int*)d_in[1];
  const float* wq  = (const float*)d_in[2];
  const float* bq  = (const float*)d_in[3];
  const float* wk  = (const float*)d_in[4];
  const float* bk  = (const float*)d_in[5];
  const float* wv  = (const float*)d_in[6];
  const float* bv  = (const float*)d_in[7];
  const float* wo  = (const float*)d_in[8];
  const float* bo  = (const float*)d_in[9];
  const float* phb = (const float*)d_in[10];
  const float* w1  = (const float*)d_in[11];
  const float* b1  = (const float*)d_in[12];
  const float* w2  = (const float*)d_in[13];
  const float* b2  = (const float*)d_in[14];
  const float* g1  = (const float*)d_in[15];
  const float* be1 = (const float*)d_in[16];
  const float* g2  = (const float*)d_in[17];
  const float* be2 = (const float*)d_in[18];

  char* ws = (char*)d_ws;
  const size_t MB = 1024 * 1024;
  if (ws_size < 112 * MB) return;
  float* qb    = (float*)(ws + 0 * MB);     // 16MB
  float* kbuf  = (float*)(ws + 16 * MB);    // 16MB
  float* vbuf  = (float*)(ws + 32 * MB);    // 16MB
  short* qp    = (short*)(ws + 48 * MB);    // 16MB bf16
  short* kp    = (short*)(ws + 64 * MB);    // 16MB bf16
  short* vt    = (short*)(ws + 80 * MB);    // 8MB bf16
  short* attnb = (short*)(ws + 0 * MB);     // reuse qb (8MB bf16)
  float* attnC = (float*)(ws + 16 * MB);    // reuse kbuf
  float* hbuf  = (float*)(ws + 48 * MB);    // reuse qp
  short* ffh   = (short*)(ws + 80 * MB);    // reuse vt + tail (32MB bf16)
  float* ffC   = (float*)(ws + 32 * MB);    // reuse vbuf

  dim3 blk(256);
  k_qkv<<<dim3(ND / BN, (NB * NS) / BM, 3), blk, 0, stream>>>(
      x, wq, bq, qb, wk, bk, kbuf, wv, bv, vbuf);
  k_pope_q<<<dim3((NB * NS * ND) / 256), blk, 0, stream>>>(qb, pos, qp);
  k_pope_k<<<dim3((NB * NS * ND) / 256), blk, 0, stream>>>(kbuf, pos, phb, kp);
  k_prep_v<<<dim3(NS / 64, NB * NH), blk, 0, stream>>>(vbuf, vt);
  k_attn_mfma<<<dim3(NS / 64, NB * NH), blk, 0, stream>>>(qp, kp, vt, attnb);
  k_gemm_bf16a<<<dim3(ND / BN, (NB * NS) / BM), blk, 0, stream>>>(
      attnb, wo, bo, attnC, NB * NS, ND, ND);
  k_ln<<<dim3(NB * NS), blk, 0, stream>>>(x, attnC, g1, be1, hbuf);
  k_gemm_relu_bf16<<<dim3(NDFF / BN, (NB * NS) / BM), blk, 0, stream>>>(
      hbuf, w1, b1, ffh, NB * NS, NDFF, ND);
  k_gemm_bf16a<<<dim3(ND / BN, (NB * NS) / BM), blk, 0, stream>>>(
      ffh, w2, b2, ffC, NB * NS, ND, NDFF);
  k_ln<<<dim3(NB * NS), blk, 0, stream>>>(hbuf, ffC, g2, be2, (float*)d_out);
}

// Round 3
// 636.263 us; speedup vs baseline: 4.4828x; 1.0777x over previous
//
#include <hip/hip_runtime.h>
#include <hip/hip_bf16.h>
#include <math.h>

#define NB 2
#define NS 2048
#define ND 1024
#define NH 16
#define NHD 64
#define NDFF 4096

typedef __attribute__((ext_vector_type(4))) float f32x4;
typedef __attribute__((ext_vector_type(8))) short bf16x8;

__device__ __forceinline__ short f2bf(float f) {
  union { float f; unsigned u; } v; v.f = f;
  unsigned r = v.u + 0x7fffu + ((v.u >> 16) & 1u);
  return (short)(r >> 16);
}
__device__ __forceinline__ float bf2f(unsigned short u) {
  union { unsigned u; float f; } v; v.u = ((unsigned)u) << 16; return v.f;
}
__device__ __forceinline__ float softplus_f(float x) {
  return fmaxf(x, 0.f) + log1pf(__expf(-fabsf(x)));
}

// ============ prep kernels ============
// W [K][N] f32 -> Wt [N][K] bf16 (transpose + convert)
__global__ __launch_bounds__(256) void k_wt(const float* __restrict__ W,
    short* __restrict__ Wt, int K, int N) {
  __shared__ float t[64][65];
  const int k0 = blockIdx.y * 64, n0 = blockIdx.x * 64;
  for (int i = threadIdx.x; i < 4096; i += 256) {
    const int r = i >> 6, c = i & 63;
    t[r][c] = W[(size_t)(k0 + r) * N + n0 + c];
  }
  __syncthreads();
  for (int i = threadIdx.x; i < 4096; i += 256) {
    const int r = i >> 6, c = i & 63;
    Wt[(size_t)(n0 + r) * K + k0 + c] = f2bf(t[c][r]);
  }
}

// x f32 -> bf16 (8 elems/thread)
__global__ __launch_bounds__(256) void k_xb(const float* __restrict__ x,
    short* __restrict__ xb, int n8) {
  const int i = blockIdx.x * 256 + threadIdx.x;
  if (i >= n8) return;
  const float4 a = ((const float4*)x)[i * 2];
  const float4 b = ((const float4*)x)[i * 2 + 1];
  short tmp[8] = { f2bf(a.x), f2bf(a.y), f2bf(a.z), f2bf(a.w),
                   f2bf(b.x), f2bf(b.y), f2bf(b.z), f2bf(b.w) };
  *(int4*)&xb[(size_t)i * 8] = *(const int4*)tmp;
}

// vb bf16 [b][s][h*64+d] -> vt bf16 [bh][d][s]
__global__ __launch_bounds__(256) void k_prep_v(const short* __restrict__ vb,
    short* __restrict__ vt) {
  __shared__ short t[64][72];
  const int bh = blockIdx.y, b = bh >> 4, h = bh & 15;
  const int s0 = blockIdx.x * 64;
  for (int i = threadIdx.x; i < 512; i += 256) {
    const int sl = i >> 3, d8 = (i & 7) * 8;
    int4 vv = *(const int4*)&vb[((size_t)(b * NS + s0 + sl) * NH + h) * NHD + d8];
    const short* sp = (const short*)&vv;
#pragma unroll
    for (int j = 0; j < 8; j++) t[d8 + j][sl] = sp[j];
  }
  __syncthreads();
  for (int i = threadIdx.x; i < 512; i += 256) {
    const int d = i >> 3, c8 = (i & 7) * 8;
    *(int4*)&vt[((size_t)bh * 64 + d) * NS + s0 + c8] = *(const int4*)&t[d][c8];
  }
}

// ============ GEMM core: A bf16 [M][K] @ Wt bf16 [N][K] -> acc f32 ============
#define BKK 32
#define LDK 40  // padded LDS row stride in shorts

__device__ __forceinline__ void gemm_core(const short* __restrict__ A,
    const short* __restrict__ Wt, const int K, const int row0, const int col0,
    short (*lsA)[LDK], short (*lsB)[LDK], f32x4 acc[4][4]) {
  const int tid = threadIdx.x;
  const int lane = tid & 63, wave = tid >> 6;
  const int lr = lane & 15, lk8 = (lane >> 4) << 3;
  const int wr = wave >> 1, wc = wave & 1;
  const int arow = tid >> 1, akb = (tid & 1) << 4;
#pragma unroll
  for (int m = 0; m < 4; m++)
#pragma unroll
    for (int n = 0; n < 4; n++) acc[m][n] = 0.f;
  for (int k0 = 0; k0 < K; k0 += BKK) {
    const short* sa = &A[(size_t)(row0 + arow) * K + k0 + akb];
    const short* sb = &Wt[(size_t)(col0 + arow) * K + k0 + akb];
    const int4 a0 = ((const int4*)sa)[0], a1 = ((const int4*)sa)[1];
    const int4 b0 = ((const int4*)sb)[0], b1 = ((const int4*)sb)[1];
    ((int4*)&lsA[arow][akb])[0] = a0;
    ((int4*)&lsA[arow][akb])[1] = a1;
    ((int4*)&lsB[arow][akb])[0] = b0;
    ((int4*)&lsB[arow][akb])[1] = b1;
    __syncthreads();
    bf16x8 af[4], bf_[4];
#pragma unroll
    for (int m = 0; m < 4; m++)
      af[m] = *(const bf16x8*)&lsA[wr * 64 + m * 16 + lr][lk8];
#pragma unroll
    for (int n = 0; n < 4; n++)
      bf_[n] = *(const bf16x8*)&lsB[wc * 64 + n * 16 + lr][lk8];
#pragma unroll
    for (int m = 0; m < 4; m++)
#pragma unroll
      for (int n = 0; n < 4; n++)
        acc[m][n] = __builtin_amdgcn_mfma_f32_16x16x32_bf16(af[m], bf_[n], acc[m][n], 0, 0, 0);
    __syncthreads();
  }
}

template<int RELU, int OUTBF16>
__global__ __launch_bounds__(256) void k_gemm(const short* __restrict__ A,
    const short* __restrict__ Wt, const float* __restrict__ bias,
    void* __restrict__ C, int M, int N, int K) {
  __shared__ short lsA[128][LDK], lsB[128][LDK];
  f32x4 acc[4][4];
  const int row0 = blockIdx.y * 128, col0 = blockIdx.x * 128;
  gemm_core(A, Wt, K, row0, col0, lsA, lsB, acc);
  const int lane = threadIdx.x & 63, wave = threadIdx.x >> 6;
  const int lr = lane & 15, r4 = (lane >> 4) << 2;
  const int wr = wave >> 1, wc = wave & 1;
#pragma unroll
  for (int m = 0; m < 4; m++) {
#pragma unroll
    for (int n = 0; n < 4; n++) {
      const int col = col0 + wc * 64 + n * 16 + lr;
      const float bv = bias[col];
#pragma unroll
      for (int r = 0; r < 4; r++) {
        const int row = row0 + wr * 64 + m * 16 + r4 + r;
        float val = acc[m][n][r] + bv;
        if (RELU) val = fmaxf(val, 0.f);
        if (OUTBF16) ((short*)C)[(size_t)row * N + col] = f2bf(val);
        else ((float*)C)[(size_t)row * N + col] = val;
      }
    }
  }
}

// QKV GEMM with fused PoPE epilogue. z=0: q->qp[bh][s][128], z=1: k->kp,
// z=2: v->vb bf16 [b][s][1024].
__global__ __launch_bounds__(256) void k_qkv_pope(const short* __restrict__ xb,
    const short* __restrict__ wqT, const float* __restrict__ bq,
    const short* __restrict__ wkT, const float* __restrict__ bk,
    const short* __restrict__ wvT, const float* __restrict__ bv,
    const int* __restrict__ positions, const float* __restrict__ phb,
    short* __restrict__ qp, short* __restrict__ kp, short* __restrict__ vb) {
  __shared__ short lsA[128][LDK], lsB[128][LDK];
  const int z = blockIdx.z;
  const short* Wt = (z == 0) ? wqT : (z == 1) ? wkT : wvT;
  const float* bias = (z == 0) ? bq : (z == 1) ? bk : bv;
  f32x4 acc[4][4];
  const int row0 = blockIdx.y * 128, col0 = blockIdx.x * 128;
  gemm_core(xb, Wt, ND, row0, col0, lsA, lsB, acc);
  const int lane = threadIdx.x & 63, wave = threadIdx.x >> 6;
  const int lr = lane & 15, r4 = (lane >> 4) << 2;
  const int wr = wave >> 1, wc = wave & 1;
  if (z == 2) {
#pragma unroll
    for (int m = 0; m < 4; m++)
#pragma unroll
      for (int n = 0; n < 4; n++) {
        const int col = col0 + wc * 64 + n * 16 + lr;
        const float bvs = bias[col];
#pragma unroll
        for (int r = 0; r < 4; r++) {
          const int row = row0 + wr * 64 + m * 16 + r4 + r;
          vb[(size_t)row * ND + col] = f2bf(acc[m][n][r] + bvs);
        }
      }
  } else {
    short* outp = (z == 0) ? qp : kp;
#pragma unroll
    for (int n = 0; n < 4; n++) {
      const int col = col0 + wc * 64 + n * 16 + lr;
      const int h = col >> 6, d = col & 63;
      const float freq = __expf(-(float)d * (float)(9.210340371976184 / 64.0));
      float cb = 0.f;
      if (z == 1) {
        cb = phb[h * 64 + d];
        cb = fminf(fmaxf(cb, -6.283185307179586f), 0.f);
      }
      const float bvs = bias[col];
#pragma unroll
      for (int m = 0; m < 4; m++) {
#pragma unroll
        for (int r = 0; r < 4; r++) {
          const int row = row0 + wr * 64 + m * 16 + r4 + r;
          const int b = row >> 11, s = row & 2047;
          const float mu = softplus_f(acc[m][n][r] + bvs);
          const float ph = (float)positions[s] * freq + cb;
          float sn, cs; sincosf(ph, &sn, &cs);
          const size_t o = (((size_t)(b * 16 + h) * NS + s) * 128) + d;
          outp[o] = f2bf(mu * cs);
          outp[o + 64] = f2bf(mu * sn);
        }
      }
    }
  }
}

// ============ Attention (causal, softmax1), MFMA flash ============
// 512 threads = 8 waves; q-tile 128 rows (16/wave); 64-key chunks, double-buffered.
__global__ __launch_bounds__(512) void k_attn2(
    const short* __restrict__ qp, const short* __restrict__ kp,
    const short* __restrict__ vt, short* __restrict__ attn) {
  __shared__ short kp_l[2][64][136];
  __shared__ short v_l[2][64][72];
  __shared__ short p_l[8][16][72];
  const int bh = blockIdx.y, b = bh >> 4, h = bh & 15;
  const int q0 = (int)(gridDim.x - 1 - blockIdx.x) * 128;  // heavy tiles first
  const int tid = threadIdx.x, wave = tid >> 6, lane = tid & 63;
  const int lr = lane & 15, lk = lane >> 4;

  bf16x8 aq[4];
  {
    const short* qrow = qp + ((size_t)bh * NS + q0 + wave * 16 + lr) * 128;
#pragma unroll
    for (int ks = 0; ks < 4; ks++)
      aq[ks] = *(const bf16x8*)&qrow[ks * 32 + lk * 8];
  }

  f32x4 acc_o[4];
  float m_r[4], l_r[4];
#pragma unroll
  for (int r = 0; r < 4; r++) { m_r[r] = -INFINITY; l_r[r] = 0.f; }
#pragma unroll
  for (int n = 0; n < 4; n++) acc_o[n] = 0.f;

  const short* kpb = kp + (size_t)bh * NS * 128;
  const short* vtb = vt + (size_t)bh * 64 * NS;
  const int nch = q0 / 64 + 2;

  const int krow = tid >> 3, kcol = (tid & 7) * 16;  // kp staging: 2 int4/thread
  const int vrow = tid >> 3, vcol = (tid & 7) * 8;   // v staging: 1 int4/thread

  int4 rk0, rk1, rv;
  {
    const short* s = &kpb[(size_t)krow * 128 + kcol];
    rk0 = ((const int4*)s)[0]; rk1 = ((const int4*)s)[1];
    rv = *(const int4*)&vtb[(size_t)vrow * NS + vcol];
  }
  ((int4*)&kp_l[0][krow][kcol])[0] = rk0;
  ((int4*)&kp_l[0][krow][kcol])[1] = rk1;
  *(int4*)&v_l[0][vrow][vcol] = rv;
  __syncthreads();

  for (int c = 0; c < nch; c++) {
    const int kb = c * 64;
    const int cur = c & 1;
    const bool more = (c + 1) < nch;
    if (more) {
      const int kb2 = kb + 64;
      const short* s = &kpb[(size_t)(kb2 + krow) * 128 + kcol];
      rk0 = ((const int4*)s)[0]; rk1 = ((const int4*)s)[1];
      rv = *(const int4*)&vtb[(size_t)vrow * NS + kb2 + vcol];
    }
    if (q0 + wave * 16 + 15 >= kb) {  // wave has unmasked rows in this chunk
      f32x4 s_acc[4];
#pragma unroll
      for (int n = 0; n < 4; n++) s_acc[n] = 0.f;
#pragma unroll
      for (int ks = 0; ks < 4; ks++) {
        bf16x8 bk_[4];
#pragma unroll
        for (int n = 0; n < 4; n++)
          bk_[n] = *(const bf16x8*)&kp_l[cur][n * 16 + lr][ks * 32 + lk * 8];
#pragma unroll
        for (int n = 0; n < 4; n++)
          s_acc[n] = __builtin_amdgcn_mfma_f32_16x16x32_bf16(aq[ks], bk_[n], s_acc[n], 0, 0, 0);
      }
      const float scale = 0.08838834764831845f;
      float pmax[4];
#pragma unroll
      for (int r = 0; r < 4; r++) pmax[r] = -INFINITY;
#pragma unroll
      for (int n = 0; n < 4; n++) {
#pragma unroll
        for (int r = 0; r < 4; r++) {
          const int rel = q0 + wave * 16 + lk * 4 + r - kb;  // >=0 for active wave
          float sv = s_acc[n][r] * scale;
          sv = (n * 16 + lr <= rel) ? sv : -INFINITY;
          s_acc[n][r] = sv;
          pmax[r] = fmaxf(pmax[r], sv);
        }
      }
#pragma unroll
      for (int off = 8; off; off >>= 1)
#pragma unroll
        for (int r = 0; r < 4; r++) pmax[r] = fmaxf(pmax[r], __shfl_xor(pmax[r], off));
      float fac[4], rs[4];
#pragma unroll
      for (int r = 0; r < 4; r++) {
        const float nm = fmaxf(m_r[r], pmax[r]);
        fac[r] = __expf(m_r[r] - nm);
        m_r[r] = nm;
        rs[r] = 0.f;
      }
#pragma unroll
      for (int n = 0; n < 4; n++) {
#pragma unroll
        for (int r = 0; r < 4; r++) {
          const float p = __expf(s_acc[n][r] - m_r[r]);
          s_acc[n][r] = p;
          rs[r] += p;
        }
      }
#pragma unroll
      for (int off = 8; off; off >>= 1)
#pragma unroll
        for (int r = 0; r < 4; r++) rs[r] += __shfl_xor(rs[r], off);
#pragma unroll
      for (int r = 0; r < 4; r++) l_r[r] = l_r[r] * fac[r] + rs[r];
      // P -> wave-private LDS strip (same-wave RAW, no barrier)
#pragma unroll
      for (int n = 0; n < 4; n++)
#pragma unroll
        for (int r = 0; r < 4; r++)
          p_l[wave][lk * 4 + r][n * 16 + lr] = f2bf(s_acc[n][r]);
#pragma unroll
      for (int n = 0; n < 4; n++)
#pragma unroll
        for (int r = 0; r < 4; r++) acc_o[n][r] *= fac[r];
#pragma unroll
      for (int ks = 0; ks < 2; ks++) {
        const bf16x8 ap = *(const bf16x8*)&p_l[wave][lr][ks * 32 + lk * 8];
        bf16x8 bv_[4];
#pragma unroll
        for (int nd = 0; nd < 4; nd++)
          bv_[nd] = *(const bf16x8*)&v_l[cur][nd * 16 + lr][ks * 32 + lk * 8];
#pragma unroll
        for (int nd = 0; nd < 4; nd++)
          acc_o[nd] = __builtin_amdgcn_mfma_f32_16x16x32_bf16(ap, bv_[nd], acc_o[nd], 0, 0, 0);
      }
    }
    __syncthreads();
    if (more) {
      ((int4*)&kp_l[cur ^ 1][krow][kcol])[0] = rk0;
      ((int4*)&kp_l[cur ^ 1][krow][kcol])[1] = rk1;
      *(int4*)&v_l[cur ^ 1][vrow][vcol] = rv;
    }
    __syncthreads();
  }
  float inv[4];
#pragma unroll
  for (int r = 0; r < 4; r++) inv[r] = 1.f / (__expf(-m_r[r]) + l_r[r]);
#pragma unroll
  for (int nd = 0; nd < 4; nd++) {
#pragma unroll
    for (int r = 0; r < 4; r++) {
      const int row = q0 + wave * 16 + lk * 4 + r;
      const int d = nd * 16 + lr;
      attn[(((size_t)b * NS + row) * NH + h) * NHD + d] = f2bf(acc_o[nd][r] * inv[r]);
    }
  }
}

// ============ LayerNorm: out = LN(A + R) * g + be ============
template<int ABF16, int OUTBF16>
__global__ __launch_bounds__(256) void k_ln(const void* __restrict__ Av,
    const float* __restrict__ R, const float* __restrict__ g,
    const float* __restrict__ be, void* __restrict__ out) {
  const int row = blockIdx.x, tid = threadIdx.x;
  float x0, x1, x2, x3;
  if (ABF16) {
    const short* A = (const short*)Av + (size_t)row * ND + tid * 4;
    short4 a = *(const short4*)A;
    x0 = bf2f((unsigned short)a.x); x1 = bf2f((unsigned short)a.y);
    x2 = bf2f((unsigned short)a.z); x3 = bf2f((unsigned short)a.w);
  } else {
    const float4 a = ((const float4*)((const float*)Av + (size_t)row * ND))[tid];
    x0 = a.x; x1 = a.y; x2 = a.z; x3 = a.w;
  }
  const float4 r = ((const float4*)(R + (size_t)row * ND))[tid];
  x0 += r.x; x1 += r.y; x2 += r.z; x3 += r.w;
  float s = x0 + x1 + x2 + x3;
  float sq = x0 * x0 + x1 * x1 + x2 * x2 + x3 * x3;
#pragma unroll
  for (int off = 32; off; off >>= 1) {
    s += __shfl_xor(s, off);
    sq += __shfl_xor(sq, off);
  }
  __shared__ float ss[4], ssq[4];
  const int wave = tid >> 6, lane = tid & 63;
  if (lane == 0) { ss[wave] = s; ssq[wave] = sq; }
  __syncthreads();
  s = ss[0] + ss[1] + ss[2] + ss[3];
  sq = ssq[0] + ssq[1] + ssq[2] + ssq[3];
  const float mu = s * (1.f / (float)ND);
  const float var = sq * (1.f / (float)ND) - mu * mu;
  const float rstd = rsqrtf(var + 1e-5f);
  const float4 gg = ((const float4*)g)[tid];
  const float4 bb = ((const float4*)be)[tid];
  const float o0 = (x0 - mu) * rstd * gg.x + bb.x;
  const float o1 = (x1 - mu) * rstd * gg.y + bb.y;
  const float o2 = (x2 - mu) * rstd * gg.z + bb.z;
  const float o3 = (x3 - mu) * rstd * gg.w + bb.w;
  if (OUTBF16) {
    short4 ov = { f2bf(o0), f2bf(o1), f2bf(o2), f2bf(o3) };
    *(short4*)((short*)out + (size_t)row * ND + tid * 4) = ov;
  } else {
    float4 ov = { o0, o1, o2, o3 };
    ((float4*)((float*)out + (size_t)row * ND))[tid] = ov;
  }
}

extern "C" void kernel_launch(void* const* d_in, const int* in_sizes, int n_in,
                              void* d_out, int out_size, void* d_ws, size_t ws_size,
                              hipStream_t stream) {
  const float* x   = (const float*)d_in[0];
  const int*   pos = (const int*)d_in[1];
  const float* wq  = (const float*)d_in[2];
  const float* bq  = (const float*)d_in[3];
  const float* wk  = (const float*)d_in[4];
  const float* bk  = (const float*)d_in[5];
  const float* wv  = (const float*)d_in[6];
  const float* bv  = (const float*)d_in[7];
  const float* wo  = (const float*)d_in[8];
  const float* bo  = (const float*)d_in[9];
  const float* phb = (const float*)d_in[10];
  const float* w1  = (const float*)d_in[11];
  const float* b1  = (const float*)d_in[12];
  const float* w2  = (const float*)d_in[13];
  const float* b2  = (const float*)d_in[14];
  const float* g1  = (const float*)d_in[15];
  const float* be1 = (const float*)d_in[16];
  const float* g2  = (const float*)d_in[17];
  const float* be2 = (const float*)d_in[18];

  char* ws = (char*)d_ws;
  const size_t MB = 1024 * 1024;
  if (ws_size < 112 * MB) return;
  short* qp    = (short*)(ws + 0 * MB);    // 16MB [bh][s][128]
  short* kp    = (short*)(ws + 16 * MB);   // 16MB
  short* vb    = (short*)(ws + 32 * MB);   // 8MB [b][s][1024]
  short* vt    = (short*)(ws + 40 * MB);   // 8MB [bh][64][s]
  short* xb    = (short*)(ws + 48 * MB);   // 8MB
  short* attnb = (short*)(ws + 56 * MB);   // 8MB
  float* attnC = (float*)(ws + 64 * MB);   // 16MB
  short* hb    = (short*)(ws + 80 * MB);   // 8MB
  short* ffh   = (short*)(ws + 0 * MB);    // 32MB (reuse qp+kp after attn)
  float* ffC   = (float*)(ws + 32 * MB);   // 16MB (reuse vb+vt after attn)
  short* wqT   = (short*)(ws + 88 * MB);   // 2MB
  short* wkT   = (short*)(ws + 90 * MB);   // 2MB
  short* wvT   = (short*)(ws + 92 * MB);   // 2MB
  short* woT   = (short*)(ws + 94 * MB);   // 2MB
  short* w1T   = (short*)(ws + 96 * MB);   // 8MB [DFF][D]
  short* w2T   = (short*)(ws + 104 * MB);  // 8MB [D][DFF] -> ends 112MB

  dim3 blk(256);
  // prep: weight transposes + x conversion
  k_wt<<<dim3(16, 16), blk, 0, stream>>>(wq, wqT, ND, ND);
  k_wt<<<dim3(16, 16), blk, 0, stream>>>(wk, wkT, ND, ND);
  k_wt<<<dim3(16, 16), blk, 0, stream>>>(wv, wvT, ND, ND);
  k_wt<<<dim3(16, 16), blk, 0, stream>>>(wo, woT, ND, ND);
  k_wt<<<dim3(64, 16), blk, 0, stream>>>(w1, w1T, ND, NDFF);
  k_wt<<<dim3(16, 64), blk, 0, stream>>>(w2, w2T, NDFF, ND);
  k_xb<<<dim3((NB * NS * ND / 8 + 255) / 256), blk, 0, stream>>>(x, xb, NB * NS * ND / 8);
  // QKV + fused PoPE
  k_qkv_pope<<<dim3(ND / 128, (NB * NS) / 128, 3), blk, 0, stream>>>(
      xb, wqT, bq, wkT, bk, wvT, bv, pos, phb, qp, kp, vb);
  k_prep_v<<<dim3(NS / 64, NB * NH), blk, 0, stream>>>(vb, vt);
  // attention
  k_attn2<<<dim3(NS / 128, NB * NH), dim3(512), 0, stream>>>(qp, kp, vt, attnb);
  // wo projection
  k_gemm<0, 0><<<dim3(ND / 128, (NB * NS) / 128), blk, 0, stream>>>(
      attnb, woT, bo, attnC, NB * NS, ND, ND);
  // ln1 -> hb (bf16)
  k_ln<0, 1><<<dim3(NB * NS), blk, 0, stream>>>(x, attnC, g1, be1, hb);
  // ffn
  k_gemm<1, 1><<<dim3(NDFF / 128, (NB * NS) / 128), blk, 0, stream>>>(
      hb, w1T, b1, ffh, NB * NS, NDFF, ND);
  k_gemm<0, 0><<<dim3(ND / 128, (NB * NS) / 128), blk, 0, stream>>>(
      ffh, w2T, b2, ffC, NB * NS, ND, NDFF);
  // ln2 -> out (f32)
  k_ln<1, 0><<<dim3(NB * NS), blk, 0, stream>>>(hb, ffC, g2, be2, (float*)d_out);
}

// Round 4
// 625.622 us; speedup vs baseline: 4.5591x; 1.0170x over previous
//
#include <hip/hip_runtime.h>
#include <hip/hip_bf16.h>
#include <math.h>

#define NB 2
#define NS 2048
#define ND 1024
#define NH 16
#define NHD 64
#define NDFF 4096

typedef __attribute__((ext_vector_type(4))) float f32x4;
typedef __attribute__((ext_vector_type(8))) short bf16x8;

__device__ __forceinline__ short f2bf(float f) {
  union { float f; unsigned u; } v; v.f = f;
  unsigned r = v.u + 0x7fffu + ((v.u >> 16) & 1u);
  return (short)(r >> 16);
}
__device__ __forceinline__ float bf2f(unsigned short u) {
  union { unsigned u; float f; } v; v.u = ((unsigned)u) << 16; return v.f;
}
__device__ __forceinline__ float softplus_f(float x) {
  return fmaxf(x, 0.f) + log1pf(__expf(-fabsf(x)));
}

// ============ prep kernels ============
// W [K][N] f32 -> Wt [N][K] bf16 (transpose + convert)
__global__ __launch_bounds__(256) void k_wt(const float* __restrict__ W,
    short* __restrict__ Wt, int K, int N) {
  __shared__ float t[64][65];
  const int k0 = blockIdx.y * 64, n0 = blockIdx.x * 64;
  for (int i = threadIdx.x; i < 4096; i += 256) {
    const int r = i >> 6, c = i & 63;
    t[r][c] = W[(size_t)(k0 + r) * N + n0 + c];
  }
  __syncthreads();
  for (int i = threadIdx.x; i < 4096; i += 256) {
    const int r = i >> 6, c = i & 63;
    Wt[(size_t)(n0 + r) * K + k0 + c] = f2bf(t[c][r]);
  }
}

// x f32 -> bf16 (8 elems/thread)
__global__ __launch_bounds__(256) void k_xb(const float* __restrict__ x,
    short* __restrict__ xb, int n8) {
  const int i = blockIdx.x * 256 + threadIdx.x;
  if (i >= n8) return;
  const float4 a = ((const float4*)x)[i * 2];
  const float4 b = ((const float4*)x)[i * 2 + 1];
  short tmp[8] = { f2bf(a.x), f2bf(a.y), f2bf(a.z), f2bf(a.w),
                   f2bf(b.x), f2bf(b.y), f2bf(b.z), f2bf(b.w) };
  *(int4*)&xb[(size_t)i * 8] = *(const int4*)tmp;
}

// ============ GEMM core: A bf16 [M][K] @ Wt bf16 [N][K] -> acc f32 ============
#define BKK 32
#define LDK 40  // padded LDS row stride in shorts

__device__ __forceinline__ void gemm_core(const short* __restrict__ A,
    const short* __restrict__ Wt, const int K, const int row0, const int col0,
    short (*lsA)[LDK], short (*lsB)[LDK], f32x4 acc[4][4]) {
  const int tid = threadIdx.x;
  const int lane = tid & 63, wave = tid >> 6;
  const int lr = lane & 15, lk8 = (lane >> 4) << 3;
  const int wr = wave >> 1, wc = wave & 1;
  const int arow = tid >> 1, akb = (tid & 1) << 4;
#pragma unroll
  for (int m = 0; m < 4; m++)
#pragma unroll
    for (int n = 0; n < 4; n++) acc[m][n] = 0.f;
  for (int k0 = 0; k0 < K; k0 += BKK) {
    const short* sa = &A[(size_t)(row0 + arow) * K + k0 + akb];
    const short* sb = &Wt[(size_t)(col0 + arow) * K + k0 + akb];
    const int4 a0 = ((const int4*)sa)[0], a1 = ((const int4*)sa)[1];
    const int4 b0 = ((const int4*)sb)[0], b1 = ((const int4*)sb)[1];
    ((int4*)&lsA[arow][akb])[0] = a0;
    ((int4*)&lsA[arow][akb])[1] = a1;
    ((int4*)&lsB[arow][akb])[0] = b0;
    ((int4*)&lsB[arow][akb])[1] = b1;
    __syncthreads();
    bf16x8 af[4], bf_[4];
#pragma unroll
    for (int m = 0; m < 4; m++)
      af[m] = *(const bf16x8*)&lsA[wr * 64 + m * 16 + lr][lk8];
#pragma unroll
    for (int n = 0; n < 4; n++)
      bf_[n] = *(const bf16x8*)&lsB[wc * 64 + n * 16 + lr][lk8];
#pragma unroll
    for (int m = 0; m < 4; m++)
#pragma unroll
      for (int n = 0; n < 4; n++)
        acc[m][n] = __builtin_amdgcn_mfma_f32_16x16x32_bf16(af[m], bf_[n], acc[m][n], 0, 0, 0);
    __syncthreads();
  }
}

template<int RELU, int OUTBF16>
__global__ __launch_bounds__(256) void k_gemm(const short* __restrict__ A,
    const short* __restrict__ Wt, const float* __restrict__ bias,
    void* __restrict__ C, int M, int N, int K) {
  __shared__ short lsA[128][LDK], lsB[128][LDK];
  f32x4 acc[4][4];
  const int row0 = blockIdx.y * 128, col0 = blockIdx.x * 128;
  gemm_core(A, Wt, K, row0, col0, lsA, lsB, acc);
  const int lane = threadIdx.x & 63, wave = threadIdx.x >> 6;
  const int lr = lane & 15, r4 = (lane >> 4) << 2;
  const int wr = wave >> 1, wc = wave & 1;
#pragma unroll
  for (int m = 0; m < 4; m++) {
#pragma unroll
    for (int n = 0; n < 4; n++) {
      const int col = col0 + wc * 64 + n * 16 + lr;
      const float bv = bias[col];
#pragma unroll
      for (int r = 0; r < 4; r++) {
        const int row = row0 + wr * 64 + m * 16 + r4 + r;
        float val = acc[m][n][r] + bv;
        if (RELU) val = fmaxf(val, 0.f);
        if (OUTBF16) ((short*)C)[(size_t)row * N + col] = f2bf(val);
        else ((float*)C)[(size_t)row * N + col] = val;
      }
    }
  }
}

// QKV GEMM with fused PoPE epilogue, LDS-staged coalesced writes.
// z=0: q->qp [bh][s][128], z=1: k->kp, z=2: v->vt [bh][d][s] (transposed).
__global__ __launch_bounds__(256) void k_qkv_pope(const short* __restrict__ xb,
    const short* __restrict__ wqT, const float* __restrict__ bq,
    const short* __restrict__ wkT, const float* __restrict__ bk,
    const short* __restrict__ wvT, const float* __restrict__ bv,
    const int* __restrict__ positions, const float* __restrict__ phb,
    short* __restrict__ qp, short* __restrict__ kp, short* __restrict__ vt) {
  __shared__ short lsA[128][LDK], lsB[128][LDK];
  __shared__ union {
    short strip[32][264];   // z<2: rows x {head0:cos64,sin64 | head1:cos64,sin64}
    short vstrip[128][40];  // z=2: [local col][local row] transpose strip
  } u;
  const int z = blockIdx.z;
  const short* Wt = (z == 0) ? wqT : (z == 1) ? wkT : wvT;
  const float* bias = (z == 0) ? bq : (z == 1) ? bk : bv;
  f32x4 acc[4][4];
  const int row0 = blockIdx.y * 128, col0 = blockIdx.x * 128;
  gemm_core(xb, Wt, ND, row0, col0, lsA, lsB, acc);
  const int tid = threadIdx.x;
  const int lane = tid & 63, wave = tid >> 6;
  const int lr = lane & 15, r4 = (lane >> 4) << 2;
  const int wr = wave >> 1, wc = wave & 1;
  const int bidx = row0 >> 11;          // batch (tile never crosses b)
  const int srow0 = row0 & 2047;        // s of tile row 0
  const int h0 = col0 >> 6;             // first head covered by this tile

  if (z == 2) {
    short* vtb = vt;
#pragma unroll
    for (int m = 0; m < 4; m++) {
      // stage transposed: vstrip[local col][local row]
#pragma unroll
      for (int n = 0; n < 4; n++) {
        const int c = wc * 64 + n * 16 + lr;
        const float bvs = bias[col0 + c];
#pragma unroll
        for (int r = 0; r < 4; r++)
          u.vstrip[c][wr * 16 + r4 + r] = f2bf(acc[m][n][r] + bvs);
      }
      __syncthreads();
      // write: 512 int4, 2/thread; each int4 = 8 consecutive s
#pragma unroll
      for (int t = 0; t < 2; t++) {
        const int idx = t * 256 + tid;
        const int c = idx >> 2, j8 = (idx & 3) * 8;
        const int h = h0 + (c >> 6), d = c & 63;
        const int s = srow0 + (j8 >> 4) * 64 + m * 16 + (j8 & 15);
        *(int4*)&vtb[(((size_t)(bidx * NH + h) * NHD + d) * NS) + s] =
            *(const int4*)&u.vstrip[c][j8];
      }
      __syncthreads();
    }
  } else {
    short* outp = (z == 0) ? qp : kp;
    // per-n constants
    float freq_n[4], cb_n[4], bias_n[4];
#pragma unroll
    for (int n = 0; n < 4; n++) {
      const int col = col0 + wc * 64 + n * 16 + lr;
      const int h = col >> 6, d = col & 63;
      freq_n[n] = __expf(-(float)d * (float)(9.210340371976184 / 64.0));
      float cb = 0.f;
      if (z == 1) {
        cb = phb[h * 64 + d];
        cb = fminf(fmaxf(cb, -6.283185307179586f), 0.f);
      }
      cb_n[n] = cb;
      bias_n[n] = bias[col];
    }
#pragma unroll
    for (int m = 0; m < 4; m++) {
      // stage: strip[lrow][wc*128 + {d | 64+d}]
#pragma unroll
      for (int r = 0; r < 4; r++) {
        const int gr = row0 + wr * 64 + m * 16 + r4 + r;
        const float posf = (float)positions[gr & 2047];
#pragma unroll
        for (int n = 0; n < 4; n++) {
          const int d = n * 16 + lr;
          const float mu = softplus_f(acc[m][n][r] + bias_n[n]);
          const float ph = posf * freq_n[n] + cb_n[n];
          float sn, cs; sincosf(ph, &sn, &cs);
          const int lrow = wr * 16 + r4 + r;
          u.strip[lrow][wc * 128 + d] = f2bf(mu * cs);
          u.strip[lrow][wc * 128 + 64 + d] = f2bf(mu * sn);
        }
      }
      __syncthreads();
      // write: 1024 int4, 4/thread; 16B contiguous inside 256B runs
#pragma unroll
      for (int t = 0; t < 4; t++) {
        const int idx = t * 256 + tid;
        const int lrow = idx >> 5, ic8 = (idx & 31) * 8;
        const int hh = ic8 >> 7, dfrag = ic8 & 127;
        const int gr = row0 + (lrow >> 4) * 64 + m * 16 + (lrow & 15);
        const int s = gr & 2047;
        const size_t o = (((size_t)(bidx * NH + h0 + hh) * NS + s) * 128) + dfrag;
        *(int4*)&outp[o] = *(const int4*)&u.strip[lrow][ic8];
      }
      __syncthreads();
    }
  }
}

// ============ Attention (causal, softmax1), MFMA flash ============
// 512 threads = 8 waves; q-tile 128 rows (16/wave); 64-key chunks, double-buffered.
__global__ __launch_bounds__(512) void k_attn2(
    const short* __restrict__ qp, const short* __restrict__ kp,
    const short* __restrict__ vt, short* __restrict__ attn) {
  __shared__ short kp_l[2][64][136];
  __shared__ short v_l[2][64][72];
  __shared__ short p_l[8][16][72];
  const int bh = blockIdx.y, b = bh >> 4, h = bh & 15;
  const int q0 = (int)(gridDim.x - 1 - blockIdx.x) * 128;  // heavy tiles first
  const int tid = threadIdx.x, wave = tid >> 6, lane = tid & 63;
  const int lr = lane & 15, lk = lane >> 4;

  bf16x8 aq[4];
  {
    const short* qrow = qp + ((size_t)bh * NS + q0 + wave * 16 + lr) * 128;
#pragma unroll
    for (int ks = 0; ks < 4; ks++)
      aq[ks] = *(const bf16x8*)&qrow[ks * 32 + lk * 8];
  }

  f32x4 acc_o[4];
  float m_r[4], l_r[4];
#pragma unroll
  for (int r = 0; r < 4; r++) { m_r[r] = -INFINITY; l_r[r] = 0.f; }
#pragma unroll
  for (int n = 0; n < 4; n++) acc_o[n] = 0.f;

  const short* kpb = kp + (size_t)bh * NS * 128;
  const short* vtb = vt + (size_t)bh * 64 * NS;
  const int nch = q0 / 64 + 2;

  const int krow = tid >> 3, kcol = (tid & 7) * 16;  // kp staging: 2 int4/thread
  const int vrow = tid >> 3, vcol = (tid & 7) * 8;   // v staging: 1 int4/thread

  int4 rk0, rk1, rv;
  {
    const short* s = &kpb[(size_t)krow * 128 + kcol];
    rk0 = ((const int4*)s)[0]; rk1 = ((const int4*)s)[1];
    rv = *(const int4*)&vtb[(size_t)vrow * NS + vcol];
  }
  ((int4*)&kp_l[0][krow][kcol])[0] = rk0;
  ((int4*)&kp_l[0][krow][kcol])[1] = rk1;
  *(int4*)&v_l[0][vrow][vcol] = rv;
  __syncthreads();

  for (int c = 0; c < nch; c++) {
    const int kb = c * 64;
    const int cur = c & 1;
    const bool more = (c + 1) < nch;
    if (more) {
      const int kb2 = kb + 64;
      const short* s = &kpb[(size_t)(kb2 + krow) * 128 + kcol];
      rk0 = ((const int4*)s)[0]; rk1 = ((const int4*)s)[1];
      rv = *(const int4*)&vtb[(size_t)vrow * NS + kb2 + vcol];
    }
    if (q0 + wave * 16 + 15 >= kb) {  // wave has unmasked rows in this chunk
      f32x4 s_acc[4];
#pragma unroll
      for (int n = 0; n < 4; n++) s_acc[n] = 0.f;
#pragma unroll
      for (int ks = 0; ks < 4; ks++) {
        bf16x8 bk_[4];
#pragma unroll
        for (int n = 0; n < 4; n++)
          bk_[n] = *(const bf16x8*)&kp_l[cur][n * 16 + lr][ks * 32 + lk * 8];
#pragma unroll
        for (int n = 0; n < 4; n++)
          s_acc[n] = __builtin_amdgcn_mfma_f32_16x16x32_bf16(aq[ks], bk_[n], s_acc[n], 0, 0, 0);
      }
      const float scale = 0.08838834764831845f;
      float pmax[4];
#pragma unroll
      for (int r = 0; r < 4; r++) pmax[r] = -INFINITY;
#pragma unroll
      for (int n = 0; n < 4; n++) {
#pragma unroll
        for (int r = 0; r < 4; r++) {
          const int rel = q0 + wave * 16 + lk * 4 + r - kb;  // >=0 for active wave
          float sv = s_acc[n][r] * scale;
          sv = (n * 16 + lr <= rel) ? sv : -INFINITY;
          s_acc[n][r] = sv;
          pmax[r] = fmaxf(pmax[r], sv);
        }
      }
#pragma unroll
      for (int off = 8; off; off >>= 1)
#pragma unroll
        for (int r = 0; r < 4; r++) pmax[r] = fmaxf(pmax[r], __shfl_xor(pmax[r], off));
      float fac[4], rs[4];
#pragma unroll
      for (int r = 0; r < 4; r++) {
        const float nm = fmaxf(m_r[r], pmax[r]);
        fac[r] = __expf(m_r[r] - nm);
        m_r[r] = nm;
        rs[r] = 0.f;
      }
#pragma unroll
      for (int n = 0; n < 4; n++) {
#pragma unroll
        for (int r = 0; r < 4; r++) {
          const float p = __expf(s_acc[n][r] - m_r[r]);
          s_acc[n][r] = p;
          rs[r] += p;
        }
      }
#pragma unroll
      for (int off = 8; off; off >>= 1)
#pragma unroll
        for (int r = 0; r < 4; r++) rs[r] += __shfl_xor(rs[r], off);
#pragma unroll
      for (int r = 0; r < 4; r++) l_r[r] = l_r[r] * fac[r] + rs[r];
      // P -> wave-private LDS strip (same-wave RAW, no barrier)
#pragma unroll
      for (int n = 0; n < 4; n++)
#pragma unroll
        for (int r = 0; r < 4; r++)
          p_l[wave][lk * 4 + r][n * 16 + lr] = f2bf(s_acc[n][r]);
#pragma unroll
      for (int n = 0; n < 4; n++)
#pragma unroll
        for (int r = 0; r < 4; r++) acc_o[n][r] *= fac[r];
#pragma unroll
      for (int ks = 0; ks < 2; ks++) {
        const bf16x8 ap = *(const bf16x8*)&p_l[wave][lr][ks * 32 + lk * 8];
        bf16x8 bv_[4];
#pragma unroll
        for (int nd = 0; nd < 4; nd++)
          bv_[nd] = *(const bf16x8*)&v_l[cur][nd * 16 + lr][ks * 32 + lk * 8];
#pragma unroll
        for (int nd = 0; nd < 4; nd++)
          acc_o[nd] = __builtin_amdgcn_mfma_f32_16x16x32_bf16(ap, bv_[nd], acc_o[nd], 0, 0, 0);
      }
    }
    __syncthreads();
    if (more) {
      ((int4*)&kp_l[cur ^ 1][krow][kcol])[0] = rk0;
      ((int4*)&kp_l[cur ^ 1][krow][kcol])[1] = rk1;
      *(int4*)&v_l[cur ^ 1][vrow][vcol] = rv;
    }
    __syncthreads();
  }
  float inv[4];
#pragma unroll
  for (int r = 0; r < 4; r++) inv[r] = 1.f / (__expf(-m_r[r]) + l_r[r]);
#pragma unroll
  for (int nd = 0; nd < 4; nd++) {
#pragma unroll
    for (int r = 0; r < 4; r++) {
      const int row = q0 + wave * 16 + lk * 4 + r;
      const int d = nd * 16 + lr;
      attn[(((size_t)b * NS + row) * NH + h) * NHD + d] = f2bf(acc_o[nd][r] * inv[r]);
    }
  }
}

// ============ LayerNorm: out = LN(A + R) * g + be ============
template<int ABF16, int OUTBF16>
__global__ __launch_bounds__(256) void k_ln(const void* __restrict__ Av,
    const float* __restrict__ R, const float* __restrict__ g,
    const float* __restrict__ be, void* __restrict__ out) {
  const int row = blockIdx.x, tid = threadIdx.x;
  float x0, x1, x2, x3;
  if (ABF16) {
    const short* A = (const short*)Av + (size_t)row * ND + tid * 4;
    short4 a = *(const short4*)A;
    x0 = bf2f((unsigned short)a.x); x1 = bf2f((unsigned short)a.y);
    x2 = bf2f((unsigned short)a.z); x3 = bf2f((unsigned short)a.w);
  } else {
    const float4 a = ((const float4*)((const float*)Av + (size_t)row * ND))[tid];
    x0 = a.x; x1 = a.y; x2 = a.z; x3 = a.w;
  }
  const float4 r = ((const float4*)(R + (size_t)row * ND))[tid];
  x0 += r.x; x1 += r.y; x2 += r.z; x3 += r.w;
  float s = x0 + x1 + x2 + x3;
  float sq = x0 * x0 + x1 * x1 + x2 * x2 + x3 * x3;
#pragma unroll
  for (int off = 32; off; off >>= 1) {
    s += __shfl_xor(s, off);
    sq += __shfl_xor(sq, off);
  }
  __shared__ float ss[4], ssq[4];
  const int wave = tid >> 6, lane = tid & 63;
  if (lane == 0) { ss[wave] = s; ssq[wave] = sq; }
  __syncthreads();
  s = ss[0] + ss[1] + ss[2] + ss[3];
  sq = ssq[0] + ssq[1] + ssq[2] + ssq[3];
  const float mu = s * (1.f / (float)ND);
  const float var = sq * (1.f / (float)ND) - mu * mu;
  const float rstd = rsqrtf(var + 1e-5f);
  const float4 gg = ((const float4*)g)[tid];
  const float4 bb = ((const float4*)be)[tid];
  const float o0 = (x0 - mu) * rstd * gg.x + bb.x;
  const float o1 = (x1 - mu) * rstd * gg.y + bb.y;
  const float o2 = (x2 - mu) * rstd * gg.z + bb.z;
  const float o3 = (x3 - mu) * rstd * gg.w + bb.w;
  if (OUTBF16) {
    short4 ov = { f2bf(o0), f2bf(o1), f2bf(o2), f2bf(o3) };
    *(short4*)((short*)out + (size_t)row * ND + tid * 4) = ov;
  } else {
    float4 ov = { o0, o1, o2, o3 };
    ((float4*)((float*)out + (size_t)row * ND))[tid] = ov;
  }
}

extern "C" void kernel_launch(void* const* d_in, const int* in_sizes, int n_in,
                              void* d_out, int out_size, void* d_ws, size_t ws_size,
                              hipStream_t stream) {
  const float* x   = (const float*)d_in[0];
  const int*   pos = (const int*)d_in[1];
  const float* wq  = (const float*)d_in[2];
  const float* bq  = (const float*)d_in[3];
  const float* wk  = (const float*)d_in[4];
  const float* bk  = (const float*)d_in[5];
  const float* wv  = (const float*)d_in[6];
  const float* bv  = (const float*)d_in[7];
  const float* wo  = (const float*)d_in[8];
  const float* bo  = (const float*)d_in[9];
  const float* phb = (const float*)d_in[10];
  const float* w1  = (const float*)d_in[11];
  const float* b1  = (const float*)d_in[12];
  const float* w2  = (const float*)d_in[13];
  const float* b2  = (const float*)d_in[14];
  const float* g1  = (const float*)d_in[15];
  const float* be1 = (const float*)d_in[16];
  const float* g2  = (const float*)d_in[17];
  const float* be2 = (const float*)d_in[18];

  char* ws = (char*)d_ws;
  const size_t MB = 1024 * 1024;
  if (ws_size < 112 * MB) return;
  short* qp    = (short*)(ws + 0 * MB);    // 16MB [bh][s][128]
  short* kp    = (short*)(ws + 16 * MB);   // 16MB
  short* vt    = (short*)(ws + 32 * MB);   // 8MB [bh][d][s]
  short* xb    = (short*)(ws + 48 * MB);   // 8MB
  short* attnb = (short*)(ws + 56 * MB);   // 8MB
  float* attnC = (float*)(ws + 64 * MB);   // 16MB
  short* hb    = (short*)(ws + 80 * MB);   // 8MB
  short* ffh   = (short*)(ws + 0 * MB);    // 32MB (reuse qp+kp after attn)
  float* ffC   = (float*)(ws + 40 * MB);   // 16MB (reuse vt+xb after attn)
  short* wqT   = (short*)(ws + 88 * MB);   // 2MB
  short* wkT   = (short*)(ws + 90 * MB);   // 2MB
  short* wvT   = (short*)(ws + 92 * MB);   // 2MB
  short* woT   = (short*)(ws + 94 * MB);   // 2MB
  short* w1T   = (short*)(ws + 96 * MB);   // 8MB [DFF][D]
  short* w2T   = (short*)(ws + 104 * MB);  // 8MB [D][DFF] -> ends 112MB

  dim3 blk(256);
  // prep: weight transposes + x conversion
  k_wt<<<dim3(16, 16), blk, 0, stream>>>(wq, wqT, ND, ND);
  k_wt<<<dim3(16, 16), blk, 0, stream>>>(wk, wkT, ND, ND);
  k_wt<<<dim3(16, 16), blk, 0, stream>>>(wv, wvT, ND, ND);
  k_wt<<<dim3(16, 16), blk, 0, stream>>>(wo, woT, ND, ND);
  k_wt<<<dim3(64, 16), blk, 0, stream>>>(w1, w1T, ND, NDFF);
  k_wt<<<dim3(16, 64), blk, 0, stream>>>(w2, w2T, NDFF, ND);
  k_xb<<<dim3((NB * NS * ND / 8 + 255) / 256), blk, 0, stream>>>(x, xb, NB * NS * ND / 8);
  // QKV + fused PoPE (writes qp, kp, vt directly, coalesced)
  k_qkv_pope<<<dim3(ND / 128, (NB * NS) / 128, 3), blk, 0, stream>>>(
      xb, wqT, bq, wkT, bk, wvT, bv, pos, phb, qp, kp, vt);
  // attention
  k_attn2<<<dim3(NS / 128, NB * NH), dim3(512), 0, stream>>>(qp, kp, vt, attnb);
  // wo projection
  k_gemm<0, 0><<<dim3(ND / 128, (NB * NS) / 128), blk, 0, stream>>>(
      attnb, woT, bo, attnC, NB * NS, ND, ND);
  // ln1 -> hb (bf16)
  k_ln<0, 1><<<dim3(NB * NS), blk, 0, stream>>>(x, attnC, g1, be1, hb);
  // ffn
  k_gemm<1, 1><<<dim3(NDFF / 128, (NB * NS) / 128), blk, 0, stream>>>(
      hb, w1T, b1, ffh, NB * NS, NDFF, ND);
  k_gemm<0, 0><<<dim3(ND / 128, (NB * NS) / 128), blk, 0, stream>>>(
      ffh, w2T, b2, ffC, NB * NS, ND, NDFF);
  // ln2 -> out (f32)
  k_ln<1, 0><<<dim3(NB * NS), blk, 0, stream>>>(hb, ffC, g2, be2, (float*)d_out);
}

// Round 5
// 487.126 us; speedup vs baseline: 5.8553x; 1.2843x over previous
//
#include <hip/hip_runtime.h>
#include <hip/hip_bf16.h>
#include <math.h>

#define NB 2
#define NS 2048
#define ND 1024
#define NH 16
#define NHD 64
#define NDFF 4096

typedef __attribute__((ext_vector_type(4))) float f32x4;
typedef __attribute__((ext_vector_type(8))) short bf16x8;

__device__ __forceinline__ short f2bf(float f) {
  union { float f; unsigned u; } v; v.f = f;
  unsigned r = v.u + 0x7fffu + ((v.u >> 16) & 1u);
  return (short)(r >> 16);
}
__device__ __forceinline__ float bf2f(unsigned short u) {
  union { unsigned u; float f; } v; v.u = ((unsigned)u) << 16; return v.f;
}
__device__ __forceinline__ float softplus_f(float x) {
  return fmaxf(x, 0.f) + log1pf(__expf(-fabsf(x)));
}

// ============ prep kernels ============
// W [K][N] f32 -> Wt [N][K] bf16 (transpose + convert)
__global__ __launch_bounds__(256) void k_wt(const float* __restrict__ W,
    short* __restrict__ Wt, int K, int N) {
  __shared__ float t[64][65];
  const int k0 = blockIdx.y * 64, n0 = blockIdx.x * 64;
  for (int i = threadIdx.x; i < 4096; i += 256) {
    const int r = i >> 6, c = i & 63;
    t[r][c] = W[(size_t)(k0 + r) * N + n0 + c];
  }
  __syncthreads();
  for (int i = threadIdx.x; i < 4096; i += 256) {
    const int r = i >> 6, c = i & 63;
    Wt[(size_t)(n0 + r) * K + k0 + c] = f2bf(t[c][r]);
  }
}

// x f32 -> bf16 (8 elems/thread)
__global__ __launch_bounds__(256) void k_xb(const float* __restrict__ x,
    short* __restrict__ xb, int n8) {
  const int i = blockIdx.x * 256 + threadIdx.x;
  if (i >= n8) return;
  const float4 a = ((const float4*)x)[i * 2];
  const float4 b = ((const float4*)x)[i * 2 + 1];
  short tmp[8] = { f2bf(a.x), f2bf(a.y), f2bf(a.z), f2bf(a.w),
                   f2bf(b.x), f2bf(b.y), f2bf(b.z), f2bf(b.w) };
  *(int4*)&xb[(size_t)i * 8] = *(const int4*)tmp;
}

// vb bf16 [b][s][h*64+d] -> vt bf16 [bh][d][s]  (verified round-3 path)
__global__ __launch_bounds__(256) void k_prep_v(const short* __restrict__ vb,
    short* __restrict__ vt) {
  __shared__ short t[64][72];
  const int bh = blockIdx.y, b = bh >> 4, h = bh & 15;
  const int s0 = blockIdx.x * 64;
  for (int i = threadIdx.x; i < 512; i += 256) {
    const int sl = i >> 3, d8 = (i & 7) * 8;
    int4 vv = *(const int4*)&vb[((size_t)(b * NS + s0 + sl) * NH + h) * NHD + d8];
    const short* sp = (const short*)&vv;
#pragma unroll
    for (int j = 0; j < 8; j++) t[d8 + j][sl] = sp[j];
  }
  __syncthreads();
  for (int i = threadIdx.x; i < 512; i += 256) {
    const int d = i >> 3, c8 = (i & 7) * 8;
    *(int4*)&vt[((size_t)bh * 64 + d) * NS + s0 + c8] = *(const int4*)&t[d][c8];
  }
}

// PoPE elementwise: qb/kb bf16 [b][s][h*64+d] -> qp/kp bf16 [bh][s][128]
__global__ __launch_bounds__(256) void k_pope(const short* __restrict__ qb,
    const short* __restrict__ kb, const int* __restrict__ positions,
    const float* __restrict__ phb, short* __restrict__ qp,
    short* __restrict__ kp) {
  const size_t i8 = ((size_t)blockIdx.x * 256 + threadIdx.x) * 8;
  const int d0 = (int)(i8 & 63);
  const int h  = (int)((i8 >> 6) & 15);
  const int s  = (int)((i8 >> 10) & 2047);
  const int b  = (int)(i8 >> 21);
  const float posf = (float)positions[s];
  int4 qv = *(const int4*)&qb[i8];
  int4 kv = *(const int4*)&kb[i8];
  const short* qs = (const short*)&qv;
  const short* ks = (const short*)&kv;
  short qc[8], qsn[8], kc[8], ksn[8];
#pragma unroll
  for (int j = 0; j < 8; j++) {
    const int d = d0 + j;
    const float freq = __expf(-(float)d * (float)(9.210340371976184 / 64.0));
    const float muq = softplus_f(bf2f((unsigned short)qs[j]));
    const float muk = softplus_f(bf2f((unsigned short)ks[j]));
    float cb = phb[h * 64 + d];
    cb = fminf(fmaxf(cb, -6.283185307179586f), 0.f);
    float snq, csq, snk, csk;
    __sincosf(posf * freq, &snq, &csq);
    __sincosf(posf * freq + cb, &snk, &csk);
    qc[j] = f2bf(muq * csq); qsn[j] = f2bf(muq * snq);
    kc[j] = f2bf(muk * csk); ksn[j] = f2bf(muk * snk);
  }
  const size_t o = (((size_t)(b * 16 + h) * NS + s) * 128) + d0;
  *(int4*)&qp[o] = *(const int4*)qc;
  *(int4*)&qp[o + 64] = *(const int4*)qsn;
  *(int4*)&kp[o] = *(const int4*)kc;
  *(int4*)&kp[o + 64] = *(const int4*)ksn;
}

// ============ GEMM core: A bf16 [M][K] @ Wt bf16 [N][K] -> acc f32 ============
#define BKK 32
#define LDK 40  // padded LDS row stride in shorts

__device__ __forceinline__ void gemm_core(const short* __restrict__ A,
    const short* __restrict__ Wt, const int K, const int row0, const int col0,
    short (*lsA)[LDK], short (*lsB)[LDK], f32x4 acc[4][4]) {
  const int tid = threadIdx.x;
  const int lane = tid & 63, wave = tid >> 6;
  const int lr = lane & 15, lk8 = (lane >> 4) << 3;
  const int wr = wave >> 1, wc = wave & 1;
  const int arow = tid >> 1, akb = (tid & 1) << 4;
#pragma unroll
  for (int m = 0; m < 4; m++)
#pragma unroll
    for (int n = 0; n < 4; n++) acc[m][n] = 0.f;
  for (int k0 = 0; k0 < K; k0 += BKK) {
    const short* sa = &A[(size_t)(row0 + arow) * K + k0 + akb];
    const short* sb = &Wt[(size_t)(col0 + arow) * K + k0 + akb];
    const int4 a0 = ((const int4*)sa)[0], a1 = ((const int4*)sa)[1];
    const int4 b0 = ((const int4*)sb)[0], b1 = ((const int4*)sb)[1];
    ((int4*)&lsA[arow][akb])[0] = a0;
    ((int4*)&lsA[arow][akb])[1] = a1;
    ((int4*)&lsB[arow][akb])[0] = b0;
    ((int4*)&lsB[arow][akb])[1] = b1;
    __syncthreads();
    bf16x8 af[4], bf_[4];
#pragma unroll
    for (int m = 0; m < 4; m++)
      af[m] = *(const bf16x8*)&lsA[wr * 64 + m * 16 + lr][lk8];
#pragma unroll
    for (int n = 0; n < 4; n++)
      bf_[n] = *(const bf16x8*)&lsB[wc * 64 + n * 16 + lr][lk8];
#pragma unroll
    for (int m = 0; m < 4; m++)
#pragma unroll
      for (int n = 0; n < 4; n++)
        acc[m][n] = __builtin_amdgcn_mfma_f32_16x16x32_bf16(af[m], bf_[n], acc[m][n], 0, 0, 0);
    __syncthreads();
  }
}

template<int RELU, int OUTBF16>
__global__ __launch_bounds__(256) void k_gemm(const short* __restrict__ A,
    const short* __restrict__ Wt, const float* __restrict__ bias,
    void* __restrict__ C, int M, int N, int K) {
  __shared__ short lsA[128][LDK], lsB[128][LDK];
  f32x4 acc[4][4];
  const int row0 = blockIdx.y * 128, col0 = blockIdx.x * 128;
  gemm_core(A, Wt, K, row0, col0, lsA, lsB, acc);
  const int lane = threadIdx.x & 63, wave = threadIdx.x >> 6;
  const int lr = lane & 15, r4 = (lane >> 4) << 2;
  const int wr = wave >> 1, wc = wave & 1;
#pragma unroll
  for (int m = 0; m < 4; m++) {
#pragma unroll
    for (int n = 0; n < 4; n++) {
      const int col = col0 + wc * 64 + n * 16 + lr;
      const float bv = bias[col];
#pragma unroll
      for (int r = 0; r < 4; r++) {
        const int row = row0 + wr * 64 + m * 16 + r4 + r;
        float val = acc[m][n][r] + bv;
        if (RELU) val = fmaxf(val, 0.f);
        if (OUTBF16) ((short*)C)[(size_t)row * N + col] = f2bf(val);
        else ((float*)C)[(size_t)row * N + col] = val;
      }
    }
  }
}

// ============ Attention (causal, softmax1), MFMA flash ============
// 512 threads = 8 waves; q-tile 128 rows (16/wave); 64-key chunks, double-buffered.
__global__ __launch_bounds__(512) void k_attn2(
    const short* __restrict__ qp, const short* __restrict__ kp,
    const short* __restrict__ vt, short* __restrict__ attn) {
  __shared__ short kp_l[2][64][136];
  __shared__ short v_l[2][64][72];
  __shared__ short p_l[8][16][72];
  const int bh = blockIdx.y, b = bh >> 4, h = bh & 15;
  const int q0 = (int)(gridDim.x - 1 - blockIdx.x) * 128;  // heavy tiles first
  const int tid = threadIdx.x, wave = tid >> 6, lane = tid & 63;
  const int lr = lane & 15, lk = lane >> 4;

  bf16x8 aq[4];
  {
    const short* qrow = qp + ((size_t)bh * NS + q0 + wave * 16 + lr) * 128;
#pragma unroll
    for (int ks = 0; ks < 4; ks++)
      aq[ks] = *(const bf16x8*)&qrow[ks * 32 + lk * 8];
  }

  f32x4 acc_o[4];
  float m_r[4], l_r[4];
#pragma unroll
  for (int r = 0; r < 4; r++) { m_r[r] = -INFINITY; l_r[r] = 0.f; }
#pragma unroll
  for (int n = 0; n < 4; n++) acc_o[n] = 0.f;

  const short* kpb = kp + (size_t)bh * NS * 128;
  const short* vtb = vt + (size_t)bh * 64 * NS;
  const int nch = q0 / 64 + 2;

  const int krow = tid >> 3, kcol = (tid & 7) * 16;  // kp staging: 2 int4/thread
  const int vrow = tid >> 3, vcol = (tid & 7) * 8;   // v staging: 1 int4/thread

  int4 rk0, rk1, rv;
  {
    const short* s = &kpb[(size_t)krow * 128 + kcol];
    rk0 = ((const int4*)s)[0]; rk1 = ((const int4*)s)[1];
    rv = *(const int4*)&vtb[(size_t)vrow * NS + vcol];
  }
  ((int4*)&kp_l[0][krow][kcol])[0] = rk0;
  ((int4*)&kp_l[0][krow][kcol])[1] = rk1;
  *(int4*)&v_l[0][vrow][vcol] = rv;
  __syncthreads();

  for (int c = 0; c < nch; c++) {
    const int kb = c * 64;
    const int cur = c & 1;
    const bool more = (c + 1) < nch;
    if (more) {
      const int kb2 = kb + 64;
      const short* s = &kpb[(size_t)(kb2 + krow) * 128 + kcol];
      rk0 = ((const int4*)s)[0]; rk1 = ((const int4*)s)[1];
      rv = *(const int4*)&vtb[(size_t)vrow * NS + kb2 + vcol];
    }
    if (q0 + wave * 16 + 15 >= kb) {  // wave has unmasked rows in this chunk
      f32x4 s_acc[4];
#pragma unroll
      for (int n = 0; n < 4; n++) s_acc[n] = 0.f;
#pragma unroll
      for (int ks = 0; ks < 4; ks++) {
        bf16x8 bk_[4];
#pragma unroll
        for (int n = 0; n < 4; n++)
          bk_[n] = *(const bf16x8*)&kp_l[cur][n * 16 + lr][ks * 32 + lk * 8];
#pragma unroll
        for (int n = 0; n < 4; n++)
          s_acc[n] = __builtin_amdgcn_mfma_f32_16x16x32_bf16(aq[ks], bk_[n], s_acc[n], 0, 0, 0);
      }
      const float scale = 0.08838834764831845f;
      float pmax[4];
#pragma unroll
      for (int r = 0; r < 4; r++) pmax[r] = -INFINITY;
#pragma unroll
      for (int n = 0; n < 4; n++) {
#pragma unroll
        for (int r = 0; r < 4; r++) {
          const int rel = q0 + wave * 16 + lk * 4 + r - kb;  // >=0 for active wave
          float sv = s_acc[n][r] * scale;
          sv = (n * 16 + lr <= rel) ? sv : -INFINITY;
          s_acc[n][r] = sv;
          pmax[r] = fmaxf(pmax[r], sv);
        }
      }
#pragma unroll
      for (int off = 8; off; off >>= 1)
#pragma unroll
        for (int r = 0; r < 4; r++) pmax[r] = fmaxf(pmax[r], __shfl_xor(pmax[r], off));
      float fac[4], rs[4];
#pragma unroll
      for (int r = 0; r < 4; r++) {
        const float nm = fmaxf(m_r[r], pmax[r]);
        fac[r] = __expf(m_r[r] - nm);
        m_r[r] = nm;
        rs[r] = 0.f;
      }
#pragma unroll
      for (int n = 0; n < 4; n++) {
#pragma unroll
        for (int r = 0; r < 4; r++) {
          const float p = __expf(s_acc[n][r] - m_r[r]);
          s_acc[n][r] = p;
          rs[r] += p;
        }
      }
#pragma unroll
      for (int off = 8; off; off >>= 1)
#pragma unroll
        for (int r = 0; r < 4; r++) rs[r] += __shfl_xor(rs[r], off);
#pragma unroll
      for (int r = 0; r < 4; r++) l_r[r] = l_r[r] * fac[r] + rs[r];
      // P -> wave-private LDS strip (same-wave RAW, no barrier)
#pragma unroll
      for (int n = 0; n < 4; n++)
#pragma unroll
        for (int r = 0; r < 4; r++)
          p_l[wave][lk * 4 + r][n * 16 + lr] = f2bf(s_acc[n][r]);
#pragma unroll
      for (int n = 0; n < 4; n++)
#pragma unroll
        for (int r = 0; r < 4; r++) acc_o[n][r] *= fac[r];
#pragma unroll
      for (int ks = 0; ks < 2; ks++) {
        const bf16x8 ap = *(const bf16x8*)&p_l[wave][lr][ks * 32 + lk * 8];
        bf16x8 bv_[4];
#pragma unroll
        for (int nd = 0; nd < 4; nd++)
          bv_[nd] = *(const bf16x8*)&v_l[cur][nd * 16 + lr][ks * 32 + lk * 8];
#pragma unroll
        for (int nd = 0; nd < 4; nd++)
          acc_o[nd] = __builtin_amdgcn_mfma_f32_16x16x32_bf16(ap, bv_[nd], acc_o[nd], 0, 0, 0);
      }
    }
    __syncthreads();
    if (more) {
      ((int4*)&kp_l[cur ^ 1][krow][kcol])[0] = rk0;
      ((int4*)&kp_l[cur ^ 1][krow][kcol])[1] = rk1;
      *(int4*)&v_l[cur ^ 1][vrow][vcol] = rv;
    }
    __syncthreads();
  }
  float inv[4];
#pragma unroll
  for (int r = 0; r < 4; r++) inv[r] = 1.f / (__expf(-m_r[r]) + l_r[r]);
#pragma unroll
  for (int nd = 0; nd < 4; nd++) {
#pragma unroll
    for (int r = 0; r < 4; r++) {
      const int row = q0 + wave * 16 + lk * 4 + r;
      const int d = nd * 16 + lr;
      attn[(((size_t)b * NS + row) * NH + h) * NHD + d] = f2bf(acc_o[nd][r] * inv[r]);
    }
  }
}

// ============ LayerNorm: out = LN(A + R) * g + be ============
template<int ABF16, int OUTBF16>
__global__ __launch_bounds__(256) void k_ln(const void* __restrict__ Av,
    const float* __restrict__ R, const float* __restrict__ g,
    const float* __restrict__ be, void* __restrict__ out) {
  const int row = blockIdx.x, tid = threadIdx.x;
  float x0, x1, x2, x3;
  if (ABF16) {
    const short* A = (const short*)Av + (size_t)row * ND + tid * 4;
    short4 a = *(const short4*)A;
    x0 = bf2f((unsigned short)a.x); x1 = bf2f((unsigned short)a.y);
    x2 = bf2f((unsigned short)a.z); x3 = bf2f((unsigned short)a.w);
  } else {
    const float4 a = ((const float4*)((const float*)Av + (size_t)row * ND))[tid];
    x0 = a.x; x1 = a.y; x2 = a.z; x3 = a.w;
  }
  const float4 r = ((const float4*)(R + (size_t)row * ND))[tid];
  x0 += r.x; x1 += r.y; x2 += r.z; x3 += r.w;
  float s = x0 + x1 + x2 + x3;
  float sq = x0 * x0 + x1 * x1 + x2 * x2 + x3 * x3;
#pragma unroll
  for (int off = 32; off; off >>= 1) {
    s += __shfl_xor(s, off);
    sq += __shfl_xor(sq, off);
  }
  __shared__ float ss[4], ssq[4];
  const int wave = tid >> 6, lane = tid & 63;
  if (lane == 0) { ss[wave] = s; ssq[wave] = sq; }
  __syncthreads();
  s = ss[0] + ss[1] + ss[2] + ss[3];
  sq = ssq[0] + ssq[1] + ssq[2] + ssq[3];
  const float mu = s * (1.f / (float)ND);
  const float var = sq * (1.f / (float)ND) - mu * mu;
  const float rstd = rsqrtf(var + 1e-5f);
  const float4 gg = ((const float4*)g)[tid];
  const float4 bb = ((const float4*)be)[tid];
  const float o0 = (x0 - mu) * rstd * gg.x + bb.x;
  const float o1 = (x1 - mu) * rstd * gg.y + bb.y;
  const float o2 = (x2 - mu) * rstd * gg.z + bb.z;
  const float o3 = (x3 - mu) * rstd * gg.w + bb.w;
  if (OUTBF16) {
    short4 ov = { f2bf(o0), f2bf(o1), f2bf(o2), f2bf(o3) };
    *(short4*)((short*)out + (size_t)row * ND + tid * 4) = ov;
  } else {
    float4 ov = { o0, o1, o2, o3 };
    ((float4*)((float*)out + (size_t)row * ND))[tid] = ov;
  }
}

extern "C" void kernel_launch(void* const* d_in, const int* in_sizes, int n_in,
                              void* d_out, int out_size, void* d_ws, size_t ws_size,
                              hipStream_t stream) {
  const float* x   = (const float*)d_in[0];
  const int*   pos = (const int*)d_in[1];
  const float* wq  = (const float*)d_in[2];
  const float* bq  = (const float*)d_in[3];
  const float* wk  = (const float*)d_in[4];
  const float* bk  = (const float*)d_in[5];
  const float* wv  = (const float*)d_in[6];
  const float* bv  = (const float*)d_in[7];
  const float* wo  = (const float*)d_in[8];
  const float* bo  = (const float*)d_in[9];
  const float* phb = (const float*)d_in[10];
  const float* w1  = (const float*)d_in[11];
  const float* b1  = (const float*)d_in[12];
  const float* w2  = (const float*)d_in[13];
  const float* b2  = (const float*)d_in[14];
  const float* g1  = (const float*)d_in[15];
  const float* be1 = (const float*)d_in[16];
  const float* g2  = (const float*)d_in[17];
  const float* be2 = (const float*)d_in[18];

  char* ws = (char*)d_ws;
  const size_t MB = 1024 * 1024;
  if (ws_size < 112 * MB) return;
  short* qb    = (short*)(ws + 0 * MB);    // 8MB bf16 [b][s][1024]
  short* kb    = (short*)(ws + 8 * MB);    // 8MB
  short* vb    = (short*)(ws + 16 * MB);   // 8MB
  short* qp    = (short*)(ws + 24 * MB);   // 16MB [bh][s][128]
  short* kp    = (short*)(ws + 40 * MB);   // 16MB
  short* vt    = (short*)(ws + 56 * MB);   // 8MB [bh][d][s]
  short* xb    = (short*)(ws + 64 * MB);   // 8MB
  short* attnb = (short*)(ws + 72 * MB);   // 8MB
  float* attnC = (float*)(ws + 0 * MB);    // 16MB (reuse qb+kb after pope)
  short* hb    = (short*)(ws + 16 * MB);   // 8MB (reuse vb after prep_v)
  short* ffh   = (short*)(ws + 24 * MB);   // 32MB (reuse qp+kp after attn)
  float* ffC   = (float*)(ws + 56 * MB);   // 16MB (reuse vt+xb after attn)
  short* wqT   = (short*)(ws + 88 * MB);   // 2MB
  short* wkT   = (short*)(ws + 90 * MB);   // 2MB
  short* wvT   = (short*)(ws + 92 * MB);   // 2MB
  short* woT   = (short*)(ws + 94 * MB);   // 2MB
  short* w1T   = (short*)(ws + 96 * MB);   // 8MB [DFF][D]
  short* w2T   = (short*)(ws + 104 * MB);  // 8MB [D][DFF] -> ends 112MB

  dim3 blk(256);
  // prep: weight transposes + x conversion
  k_wt<<<dim3(16, 16), blk, 0, stream>>>(wq, wqT, ND, ND);
  k_wt<<<dim3(16, 16), blk, 0, stream>>>(wk, wkT, ND, ND);
  k_wt<<<dim3(16, 16), blk, 0, stream>>>(wv, wvT, ND, ND);
  k_wt<<<dim3(16, 16), blk, 0, stream>>>(wo, woT, ND, ND);
  k_wt<<<dim3(64, 16), blk, 0, stream>>>(w1, w1T, ND, NDFF);
  k_wt<<<dim3(16, 64), blk, 0, stream>>>(w2, w2T, NDFF, ND);
  k_xb<<<dim3((NB * NS * ND / 8 + 255) / 256), blk, 0, stream>>>(x, xb, NB * NS * ND / 8);
  // QKV projections (plain GEMMs, bf16 out)
  k_gemm<0, 1><<<dim3(ND / 128, (NB * NS) / 128), blk, 0, stream>>>(
      xb, wqT, bq, qb, NB * NS, ND, ND);
  k_gemm<0, 1><<<dim3(ND / 128, (NB * NS) / 128), blk, 0, stream>>>(
      xb, wkT, bk, kb, NB * NS, ND, ND);
  k_gemm<0, 1><<<dim3(ND / 128, (NB * NS) / 128), blk, 0, stream>>>(
      xb, wvT, bv, vb, NB * NS, ND, ND);
  // PoPE (elementwise) + V transpose
  k_pope<<<dim3(NB * NS * ND / 8 / 256), blk, 0, stream>>>(qb, kb, pos, phb, qp, kp);
  k_prep_v<<<dim3(NS / 64, NB * NH), blk, 0, stream>>>(vb, vt);
  // attention
  k_attn2<<<dim3(NS / 128, NB * NH), dim3(512), 0, stream>>>(qp, kp, vt, attnb);
  // wo projection
  k_gemm<0, 0><<<dim3(ND / 128, (NB * NS) / 128), blk, 0, stream>>>(
      attnb, woT, bo, attnC, NB * NS, ND, ND);
  // ln1 -> hb (bf16)
  k_ln<0, 1><<<dim3(NB * NS), blk, 0, stream>>>(x, attnC, g1, be1, hb);
  // ffn
  k_gemm<1, 1><<<dim3(NDFF / 128, (NB * NS) / 128), blk, 0, stream>>>(
      hb, w1T, b1, ffh, NB * NS, NDFF, ND);
  k_gemm<0, 0><<<dim3(ND / 128, (NB * NS) / 128), blk, 0, stream>>>(
      ffh, w2T, b2, ffC, NB * NS, ND, NDFF);
  // ln2 -> out (f32)
  k_ln<1, 0><<<dim3(NB * NS), blk, 0, stream>>>(hb, ffC, g2, be2, (float*)d_out);
}

// Round 6
// 429.293 us; speedup vs baseline: 6.6441x; 1.1347x over previous
//
#include <hip/hip_runtime.h>
#include <hip/hip_bf16.h>
#include <math.h>

#define NB 2
#define NS 2048
#define ND 1024
#define NH 16
#define NHD 64
#define NDFF 4096

typedef __attribute__((ext_vector_type(4))) float f32x4;
typedef __attribute__((ext_vector_type(8))) short bf16x8;

__device__ __forceinline__ short f2bf(float f) {
  union { float f; unsigned u; } v; v.f = f;
  unsigned r = v.u + 0x7fffu + ((v.u >> 16) & 1u);
  return (short)(r >> 16);
}
__device__ __forceinline__ float bf2f(unsigned short u) {
  union { unsigned u; float f; } v; v.u = ((unsigned)u) << 16; return v.f;
}
__device__ __forceinline__ float softplus_f(float x) {
  return fmaxf(x, 0.f) + log1pf(__expf(-fabsf(x)));
}
// async global->LDS, 16B per lane; lptr must be wave-uniform (HW adds lane*16)
__device__ __forceinline__ void gl16(const short* g, short* l) {
  __builtin_amdgcn_global_load_lds(
      (const __attribute__((address_space(1))) void*)g,
      (__attribute__((address_space(3))) void*)l, 16, 0, 0);
}

// ============ prep kernels ============
__global__ __launch_bounds__(256) void k_wt(const float* __restrict__ W,
    short* __restrict__ Wt, int K, int N) {
  __shared__ float t[64][65];
  const int k0 = blockIdx.y * 64, n0 = blockIdx.x * 64;
  for (int i = threadIdx.x; i < 4096; i += 256) {
    const int r = i >> 6, c = i & 63;
    t[r][c] = W[(size_t)(k0 + r) * N + n0 + c];
  }
  __syncthreads();
  for (int i = threadIdx.x; i < 4096; i += 256) {
    const int r = i >> 6, c = i & 63;
    Wt[(size_t)(n0 + r) * K + k0 + c] = f2bf(t[c][r]);
  }
}

__global__ __launch_bounds__(256) void k_xb(const float* __restrict__ x,
    short* __restrict__ xb, int n8) {
  const int i = blockIdx.x * 256 + threadIdx.x;
  if (i >= n8) return;
  const float4 a = ((const float4*)x)[i * 2];
  const float4 b = ((const float4*)x)[i * 2 + 1];
  short tmp[8] = { f2bf(a.x), f2bf(a.y), f2bf(a.z), f2bf(a.w),
                   f2bf(b.x), f2bf(b.y), f2bf(b.z), f2bf(b.w) };
  *(int4*)&xb[(size_t)i * 8] = *(const int4*)tmp;
}

__global__ __launch_bounds__(256) void k_prep_v(const short* __restrict__ vb,
    short* __restrict__ vt) {
  __shared__ short t[64][72];
  const int bh = blockIdx.y, b = bh >> 4, h = bh & 15;
  const int s0 = blockIdx.x * 64;
  for (int i = threadIdx.x; i < 512; i += 256) {
    const int sl = i >> 3, d8 = (i & 7) * 8;
    int4 vv = *(const int4*)&vb[((size_t)(b * NS + s0 + sl) * NH + h) * NHD + d8];
    const short* sp = (const short*)&vv;
#pragma unroll
    for (int j = 0; j < 8; j++) t[d8 + j][sl] = sp[j];
  }
  __syncthreads();
  for (int i = threadIdx.x; i < 512; i += 256) {
    const int d = i >> 3, c8 = (i & 7) * 8;
    *(int4*)&vt[((size_t)bh * 64 + d) * NS + s0 + c8] = *(const int4*)&t[d][c8];
  }
}

__global__ __launch_bounds__(256) void k_pope(const short* __restrict__ qb,
    const short* __restrict__ kb, const int* __restrict__ positions,
    const float* __restrict__ phb, short* __restrict__ qp,
    short* __restrict__ kp) {
  const size_t i8 = ((size_t)blockIdx.x * 256 + threadIdx.x) * 8;
  const int d0 = (int)(i8 & 63);
  const int h  = (int)((i8 >> 6) & 15);
  const int s  = (int)((i8 >> 10) & 2047);
  const int b  = (int)(i8 >> 21);
  const float posf = (float)positions[s];
  int4 qv = *(const int4*)&qb[i8];
  int4 kv = *(const int4*)&kb[i8];
  const short* qs = (const short*)&qv;
  const short* ks = (const short*)&kv;
  short qc[8], qsn[8], kc[8], ksn[8];
#pragma unroll
  for (int j = 0; j < 8; j++) {
    const int d = d0 + j;
    const float freq = __expf(-(float)d * (float)(9.210340371976184 / 64.0));
    const float muq = softplus_f(bf2f((unsigned short)qs[j]));
    const float muk = softplus_f(bf2f((unsigned short)ks[j]));
    float cb = phb[h * 64 + d];
    cb = fminf(fmaxf(cb, -6.283185307179586f), 0.f);
    float snq, csq, snk, csk;
    __sincosf(posf * freq, &snq, &csq);
    __sincosf(posf * freq + cb, &snk, &csk);
    qc[j] = f2bf(muq * csq); qsn[j] = f2bf(muq * snq);
    kc[j] = f2bf(muk * csk); ksn[j] = f2bf(muk * snk);
  }
  const size_t o = (((size_t)(b * 16 + h) * NS + s) * 128) + d0;
  *(int4*)&qp[o] = *(const int4*)qc;
  *(int4*)&qp[o + 64] = *(const int4*)qsn;
  *(int4*)&kp[o] = *(const int4*)kc;
  *(int4*)&kp[o + 64] = *(const int4*)ksn;
}

// ============ GEMM core (m97 pattern): global_load_lds into linear LDS ============
#define BKK 32

__device__ __forceinline__ void gemm_core(const short* __restrict__ A,
    const short* __restrict__ Wt, const int K, const int row0, const int col0,
    short* lsA, short* lsB, f32x4 acc[4][4]) {
  const int tid = threadIdx.x;
  const int lane = tid & 63, wave = tid >> 6;
  const int lr = lane & 15, lk8 = (lane >> 4) << 3;
  const int wr = wave >> 1, wc = wave & 1;
  const int srow = lane >> 2, scol = (lane & 3) << 3;  // lane -> (row, col8)
  const int wbase = wave * 32;                          // wave's 32-row strip
#pragma unroll
  for (int m = 0; m < 4; m++)
#pragma unroll
    for (int n = 0; n < 4; n++) acc[m][n] = 0.f;
  const short* gA0 = &A[(size_t)(row0 + wbase + srow) * K + scol];
  const short* gA1 = &A[(size_t)(row0 + wbase + 16 + srow) * K + scol];
  const short* gB0 = &Wt[(size_t)(col0 + wbase + srow) * K + scol];
  const short* gB1 = &Wt[(size_t)(col0 + wbase + 16 + srow) * K + scol];
  short* lA0 = &lsA[wbase * 32];
  short* lA1 = &lsA[(wbase + 16) * 32];
  short* lB0 = &lsB[wbase * 32];
  short* lB1 = &lsB[(wbase + 16) * 32];
  for (int k0 = 0; k0 < K; k0 += BKK) {
    gl16(gA0 + k0, lA0);
    gl16(gA1 + k0, lA1);
    gl16(gB0 + k0, lB0);
    gl16(gB1 + k0, lB1);
    __syncthreads();  // compiler emits vmcnt(0) before barrier
    bf16x8 af[4], bf_[4];
#pragma unroll
    for (int m = 0; m < 4; m++)
      af[m] = *(const bf16x8*)&lsA[(wr * 64 + m * 16 + lr) * 32 + lk8];
#pragma unroll
    for (int n = 0; n < 4; n++)
      bf_[n] = *(const bf16x8*)&lsB[(wc * 64 + n * 16 + lr) * 32 + lk8];
#pragma unroll
    for (int m = 0; m < 4; m++)
#pragma unroll
      for (int n = 0; n < 4; n++)
        acc[m][n] = __builtin_amdgcn_mfma_f32_16x16x32_bf16(af[m], bf_[n], acc[m][n], 0, 0, 0);
    __syncthreads();
  }
}

template<int RELU, int OUTBF16>
__global__ __launch_bounds__(256) void k_gemm(const short* __restrict__ A,
    const short* __restrict__ Wt, const float* __restrict__ bias,
    void* __restrict__ C, int M, int N, int K) {
  __shared__ short lsA[128 * 32], lsB[128 * 32];
  f32x4 acc[4][4];
  const int row0 = blockIdx.y * 128, col0 = blockIdx.x * 128;
  gemm_core(A, Wt, K, row0, col0, lsA, lsB, acc);
  const int lane = threadIdx.x & 63, wave = threadIdx.x >> 6;
  const int lr = lane & 15, r4 = (lane >> 4) << 2;
  const int wr = wave >> 1, wc = wave & 1;
#pragma unroll
  for (int m = 0; m < 4; m++) {
#pragma unroll
    for (int n = 0; n < 4; n++) {
      const int col = col0 + wc * 64 + n * 16 + lr;
      const float bv = bias[col];
#pragma unroll
      for (int r = 0; r < 4; r++) {
        const int row = row0 + wr * 64 + m * 16 + r4 + r;
        float val = acc[m][n][r] + bv;
        if (RELU) val = fmaxf(val, 0.f);
        if (OUTBF16) ((short*)C)[(size_t)row * N + col] = f2bf(val);
        else ((float*)C)[(size_t)row * N + col] = val;
      }
    }
  }
}

// ============ Attention (causal, softmax1), MFMA flash, paired tiles ============
// grid (8, 32): block handles tiles tL=bx and tH=15-bx jointly (equal work: 34 chunks).
__device__ __forceinline__ void attn_proc(bf16x8 aq[4], f32x4 acc_o[4],
    float m_r[4], float l_r[4], const int rowb, const int kb,
    const short (*kpl)[136], const short (*vl)[72], short (*pl)[72],
    const int lr, const int lk) {
  f32x4 s_acc[4];
#pragma unroll
  for (int n = 0; n < 4; n++) s_acc[n] = 0.f;
#pragma unroll
  for (int ks = 0; ks < 4; ks++) {
    bf16x8 bk_[4];
#pragma unroll
    for (int n = 0; n < 4; n++)
      bk_[n] = *(const bf16x8*)&kpl[n * 16 + lr][ks * 32 + lk * 8];
#pragma unroll
    for (int n = 0; n < 4; n++)
      s_acc[n] = __builtin_amdgcn_mfma_f32_16x16x32_bf16(aq[ks], bk_[n], s_acc[n], 0, 0, 0);
  }
  const float scale = 0.08838834764831845f;
  float pmax[4];
#pragma unroll
  for (int r = 0; r < 4; r++) pmax[r] = -INFINITY;
#pragma unroll
  for (int n = 0; n < 4; n++) {
#pragma unroll
    for (int r = 0; r < 4; r++) {
      const int rel = rowb + lk * 4 + r - kb;
      float sv = s_acc[n][r] * scale;
      sv = (n * 16 + lr <= rel) ? sv : -INFINITY;
      s_acc[n][r] = sv;
      pmax[r] = fmaxf(pmax[r], sv);
    }
  }
#pragma unroll
  for (int off = 8; off; off >>= 1)
#pragma unroll
    for (int r = 0; r < 4; r++) pmax[r] = fmaxf(pmax[r], __shfl_xor(pmax[r], off));
  float fac[4], rs[4];
#pragma unroll
  for (int r = 0; r < 4; r++) {
    const float nm = fmaxf(m_r[r], pmax[r]);
    fac[r] = __expf(m_r[r] - nm);
    m_r[r] = nm;
    rs[r] = 0.f;
  }
#pragma unroll
  for (int n = 0; n < 4; n++) {
#pragma unroll
    for (int r = 0; r < 4; r++) {
      const float p = __expf(s_acc[n][r] - m_r[r]);
      s_acc[n][r] = p;
      rs[r] += p;
    }
  }
#pragma unroll
  for (int off = 8; off; off >>= 1)
#pragma unroll
    for (int r = 0; r < 4; r++) rs[r] += __shfl_xor(rs[r], off);
#pragma unroll
  for (int r = 0; r < 4; r++) l_r[r] = l_r[r] * fac[r] + rs[r];
  // P -> wave-private LDS strip (same-wave RAW, no barrier)
#pragma unroll
  for (int n = 0; n < 4; n++)
#pragma unroll
    for (int r = 0; r < 4; r++)
      pl[lk * 4 + r][n * 16 + lr] = f2bf(s_acc[n][r]);
#pragma unroll
  for (int n = 0; n < 4; n++)
#pragma unroll
    for (int r = 0; r < 4; r++) acc_o[n][r] *= fac[r];
#pragma unroll
  for (int ks = 0; ks < 2; ks++) {
    const bf16x8 ap = *(const bf16x8*)&pl[lr][ks * 32 + lk * 8];
    bf16x8 bv_[4];
#pragma unroll
    for (int nd = 0; nd < 4; nd++)
      bv_[nd] = *(const bf16x8*)&vl[nd * 16 + lr][ks * 32 + lk * 8];
#pragma unroll
    for (int nd = 0; nd < 4; nd++)
      acc_o[nd] = __builtin_amdgcn_mfma_f32_16x16x32_bf16(ap, bv_[nd], acc_o[nd], 0, 0, 0);
  }
}

__global__ __launch_bounds__(512) void k_attn2(
    const short* __restrict__ qp, const short* __restrict__ kp,
    const short* __restrict__ vt, short* __restrict__ attn) {
  __shared__ short kp_l[2][64][136];
  __shared__ short v_l[2][64][72];
  __shared__ short p_l[8][16][72];
  const int bh = blockIdx.y, b = bh >> 4, h = bh & 15;
  const int tL = blockIdx.x, tH = 15 - tL;
  const int q0L = tL * 128, q0H = tH * 128;
  const int tid = threadIdx.x, wave = tid >> 6, lane = tid & 63;
  const int lr = lane & 15, lk = lane >> 4;

  bf16x8 aqH[4], aqL[4];
  {
    const short* qrH = qp + ((size_t)bh * NS + q0H + wave * 16 + lr) * 128;
    const short* qrL = qp + ((size_t)bh * NS + q0L + wave * 16 + lr) * 128;
#pragma unroll
    for (int ks = 0; ks < 4; ks++) {
      aqH[ks] = *(const bf16x8*)&qrH[ks * 32 + lk * 8];
      aqL[ks] = *(const bf16x8*)&qrL[ks * 32 + lk * 8];
    }
  }
  f32x4 accH[4], accL[4];
  float mH[4], lH[4], mL[4], lL[4];
#pragma unroll
  for (int r = 0; r < 4; r++) { mH[r] = -INFINITY; lH[r] = 0.f; mL[r] = -INFINITY; lL[r] = 0.f; }
#pragma unroll
  for (int n = 0; n < 4; n++) { accH[n] = 0.f; accL[n] = 0.f; }

  const short* kpb = kp + (size_t)bh * NS * 128;
  const short* vtb = vt + (size_t)bh * 64 * NS;
  const int nch = q0H / 64 + 2;
  const int rowbH = q0H + wave * 16, rowbL = q0L + wave * 16;

  const int krow = tid >> 3, kcol = (tid & 7) * 16;
  const int vrow = tid >> 3, vcol = (tid & 7) * 8;

  int4 rk0, rk1, rv;
  {
    const short* s = &kpb[(size_t)krow * 128 + kcol];
    rk0 = ((const int4*)s)[0]; rk1 = ((const int4*)s)[1];
    rv = *(const int4*)&vtb[(size_t)vrow * NS + vcol];
  }
  ((int4*)&kp_l[0][krow][kcol])[0] = rk0;
  ((int4*)&kp_l[0][krow][kcol])[1] = rk1;
  *(int4*)&v_l[0][vrow][vcol] = rv;
  __syncthreads();

  for (int c = 0; c < nch; c++) {
    const int kb = c * 64;
    const int cur = c & 1;
    const bool more = (c + 1) < nch;
    if (more) {
      const int kb2 = kb + 64;
      const short* s = &kpb[(size_t)(kb2 + krow) * 128 + kcol];
      rk0 = ((const int4*)s)[0]; rk1 = ((const int4*)s)[1];
      rv = *(const int4*)&vtb[(size_t)vrow * NS + kb2 + vcol];
    }
    if (rowbH + 15 >= kb)
      attn_proc(aqH, accH, mH, lH, rowbH, kb, kp_l[cur], v_l[cur], p_l[wave], lr, lk);
    if (rowbL + 15 >= kb)
      attn_proc(aqL, accL, mL, lL, rowbL, kb, kp_l[cur], v_l[cur], p_l[wave], lr, lk);
    __syncthreads();
    if (more) {
      ((int4*)&kp_l[cur ^ 1][krow][kcol])[0] = rk0;
      ((int4*)&kp_l[cur ^ 1][krow][kcol])[1] = rk1;
      *(int4*)&v_l[cur ^ 1][vrow][vcol] = rv;
    }
    __syncthreads();
  }
#pragma unroll
  for (int r = 0; r < 4; r++) {
    lH[r] = 1.f / (__expf(-mH[r]) + lH[r]);
    lL[r] = 1.f / (__expf(-mL[r]) + lL[r]);
  }
#pragma unroll
  for (int nd = 0; nd < 4; nd++) {
#pragma unroll
    for (int r = 0; r < 4; r++) {
      const int d = nd * 16 + lr;
      const int rowH = q0H + wave * 16 + lk * 4 + r;
      const int rowL = q0L + wave * 16 + lk * 4 + r;
      attn[(((size_t)b * NS + rowH) * NH + h) * NHD + d] = f2bf(accH[nd][r] * lH[r]);
      attn[(((size_t)b * NS + rowL) * NH + h) * NHD + d] = f2bf(accL[nd][r] * lL[r]);
    }
  }
}

// ============ LayerNorm: out = LN(A + R) * g + be ============
template<int ABF16, int OUTBF16>
__global__ __launch_bounds__(256) void k_ln(const void* __restrict__ Av,
    const float* __restrict__ R, const float* __restrict__ g,
    const float* __restrict__ be, void* __restrict__ out) {
  const int row = blockIdx.x, tid = threadIdx.x;
  float x0, x1, x2, x3;
  if (ABF16) {
    const short* A = (const short*)Av + (size_t)row * ND + tid * 4;
    short4 a = *(const short4*)A;
    x0 = bf2f((unsigned short)a.x); x1 = bf2f((unsigned short)a.y);
    x2 = bf2f((unsigned short)a.z); x3 = bf2f((unsigned short)a.w);
  } else {
    const float4 a = ((const float4*)((const float*)Av + (size_t)row * ND))[tid];
    x0 = a.x; x1 = a.y; x2 = a.z; x3 = a.w;
  }
  const float4 r = ((const float4*)(R + (size_t)row * ND))[tid];
  x0 += r.x; x1 += r.y; x2 += r.z; x3 += r.w;
  float s = x0 + x1 + x2 + x3;
  float sq = x0 * x0 + x1 * x1 + x2 * x2 + x3 * x3;
#pragma unroll
  for (int off = 32; off; off >>= 1) {
    s += __shfl_xor(s, off);
    sq += __shfl_xor(sq, off);
  }
  __shared__ float ss[4], ssq[4];
  const int wave = tid >> 6, lane = tid & 63;
  if (lane == 0) { ss[wave] = s; ssq[wave] = sq; }
  __syncthreads();
  s = ss[0] + ss[1] + ss[2] + ss[3];
  sq = ssq[0] + ssq[1] + ssq[2] + ssq[3];
  const float mu = s * (1.f / (float)ND);
  const float var = sq * (1.f / (float)ND) - mu * mu;
  const float rstd = rsqrtf(var + 1e-5f);
  const float4 gg = ((const float4*)g)[tid];
  const float4 bb = ((const float4*)be)[tid];
  const float o0 = (x0 - mu) * rstd * gg.x + bb.x;
  const float o1 = (x1 - mu) * rstd * gg.y + bb.y;
  const float o2 = (x2 - mu) * rstd * gg.z + bb.z;
  const float o3 = (x3 - mu) * rstd * gg.w + bb.w;
  if (OUTBF16) {
    short4 ov = { f2bf(o0), f2bf(o1), f2bf(o2), f2bf(o3) };
    *(short4*)((short*)out + (size_t)row * ND + tid * 4) = ov;
  } else {
    float4 ov = { o0, o1, o2, o3 };
    ((float4*)((float*)out + (size_t)row * ND))[tid] = ov;
  }
}

extern "C" void kernel_launch(void* const* d_in, const int* in_sizes, int n_in,
                              void* d_out, int out_size, void* d_ws, size_t ws_size,
                              hipStream_t stream) {
  const float* x   = (const float*)d_in[0];
  const int*   pos = (const int*)d_in[1];
  const float* wq  = (const float*)d_in[2];
  const float* bq  = (const float*)d_in[3];
  const float* wk  = (const float*)d_in[4];
  const float* bk  = (const float*)d_in[5];
  const float* wv  = (const float*)d_in[6];
  const float* bv  = (const float*)d_in[7];
  const float* wo  = (const float*)d_in[8];
  const float* bo  = (const float*)d_in[9];
  const float* phb = (const float*)d_in[10];
  const float* w1  = (const float*)d_in[11];
  const float* b1  = (const float*)d_in[12];
  const float* w2  = (const float*)d_in[13];
  const float* b2  = (const float*)d_in[14];
  const float* g1  = (const float*)d_in[15];
  const float* be1 = (const float*)d_in[16];
  const float* g2  = (const float*)d_in[17];
  const float* be2 = (const float*)d_in[18];

  char* ws = (char*)d_ws;
  const size_t MB = 1024 * 1024;
  if (ws_size < 112 * MB) return;
  short* qb    = (short*)(ws + 0 * MB);    // 8MB bf16 [b][s][1024]
  short* kb    = (short*)(ws + 8 * MB);    // 8MB
  short* vb    = (short*)(ws + 16 * MB);   // 8MB
  short* qp    = (short*)(ws + 24 * MB);   // 16MB [bh][s][128]
  short* kp    = (short*)(ws + 40 * MB);   // 16MB
  short* vt    = (short*)(ws + 56 * MB);   // 8MB [bh][d][s]
  short* xb    = (short*)(ws + 64 * MB);   // 8MB
  short* attnb = (short*)(ws + 72 * MB);   // 8MB
  float* attnC = (float*)(ws + 0 * MB);    // 16MB (reuse qb+kb after pope)
  short* hb    = (short*)(ws + 16 * MB);   // 8MB (reuse vb after prep_v)
  short* ffh   = (short*)(ws + 24 * MB);   // 32MB (reuse qp+kp after attn)
  float* ffC   = (float*)(ws + 56 * MB);   // 16MB (reuse vt+xb after attn)
  short* wqT   = (short*)(ws + 88 * MB);   // 2MB
  short* wkT   = (short*)(ws + 90 * MB);   // 2MB
  short* wvT   = (short*)(ws + 92 * MB);   // 2MB
  short* woT   = (short*)(ws + 94 * MB);   // 2MB
  short* w1T   = (short*)(ws + 96 * MB);   // 8MB [DFF][D]
  short* w2T   = (short*)(ws + 104 * MB);  // 8MB [D][DFF] -> ends 112MB

  dim3 blk(256);
  // prep: weight transposes + x conversion
  k_wt<<<dim3(16, 16), blk, 0, stream>>>(wq, wqT, ND, ND);
  k_wt<<<dim3(16, 16), blk, 0, stream>>>(wk, wkT, ND, ND);
  k_wt<<<dim3(16, 16), blk, 0, stream>>>(wv, wvT, ND, ND);
  k_wt<<<dim3(16, 16), blk, 0, stream>>>(wo, woT, ND, ND);
  k_wt<<<dim3(64, 16), blk, 0, stream>>>(w1, w1T, ND, NDFF);
  k_wt<<<dim3(16, 64), blk, 0, stream>>>(w2, w2T, NDFF, ND);
  k_xb<<<dim3((NB * NS * ND / 8 + 255) / 256), blk, 0, stream>>>(x, xb, NB * NS * ND / 8);
  // QKV projections (plain GEMMs, bf16 out)
  k_gemm<0, 1><<<dim3(ND / 128, (NB * NS) / 128), blk, 0, stream>>>(
      xb, wqT, bq, qb, NB * NS, ND, ND);
  k_gemm<0, 1><<<dim3(ND / 128, (NB * NS) / 128), blk, 0, stream>>>(
      xb, wkT, bk, kb, NB * NS, ND, ND);
  k_gemm<0, 1><<<dim3(ND / 128, (NB * NS) / 128), blk, 0, stream>>>(
      xb, wvT, bv, vb, NB * NS, ND, ND);
  // PoPE (elementwise) + V transpose
  k_pope<<<dim3(NB * NS * ND / 8 / 256), blk, 0, stream>>>(qb, kb, pos, phb, qp, kp);
  k_prep_v<<<dim3(NS / 64, NB * NH), blk, 0, stream>>>(vb, vt);
  // attention (paired tiles, balanced)
  k_attn2<<<dim3(8, NB * NH), dim3(512), 0, stream>>>(qp, kp, vt, attnb);
  // wo projection
  k_gemm<0, 0><<<dim3(ND / 128, (NB * NS) / 128), blk, 0, stream>>>(
      attnb, woT, bo, attnC, NB * NS, ND, ND);
  // ln1 -> hb (bf16)
  k_ln<0, 1><<<dim3(NB * NS), blk, 0, stream>>>(x, attnC, g1, be1, hb);
  // ffn
  k_gemm<1, 1><<<dim3(NDFF / 128, (NB * NS) / 128), blk, 0, stream>>>(
      hb, w1T, b1, ffh, NB * NS, NDFF, ND);
  k_gemm<0, 0><<<dim3(ND / 128, (NB * NS) / 128), blk, 0, stream>>>(
      ffh, w2T, b2, ffC, NB * NS, ND, NDFF);
  // ln2 -> out (f32)
  k_ln<1, 0><<<dim3(NB * NS), blk, 0, stream>>>(hb, ffC, g2, be2, (float*)d_out);
}

// Round 7
// 322.756 us; speedup vs baseline: 8.8372x; 1.3301x over previous
//
#include <hip/hip_runtime.h>
#include <hip/hip_bf16.h>
#include <math.h>

#define NB 2
#define NS 2048
#define ND 1024
#define NH 16
#define NHD 64
#define NDFF 4096

typedef __attribute__((ext_vector_type(4))) float f32x4;
typedef __attribute__((ext_vector_type(8))) short bf16x8;

__device__ __forceinline__ short f2bf(float f) {
  union { float f; unsigned u; } v; v.f = f;
  unsigned r = v.u + 0x7fffu + ((v.u >> 16) & 1u);
  return (short)(r >> 16);
}
__device__ __forceinline__ float bf2f(unsigned short u) {
  union { unsigned u; float f; } v; v.u = ((unsigned)u) << 16; return v.f;
}
__device__ __forceinline__ float softplus_f(float x) {
  return fmaxf(x, 0.f) + log1pf(__expf(-fabsf(x)));
}
// async global->LDS, 16B per lane; LDS dest wave-uniform (HW adds lane*16)
__device__ __forceinline__ void gl16(const short* g, short* l) {
  __builtin_amdgcn_global_load_lds(
      (const __attribute__((address_space(1))) void*)g,
      (__attribute__((address_space(3))) void*)l, 16, 0, 0);
}

// ============ prep kernels ============
__global__ __launch_bounds__(256) void k_wt(const float* __restrict__ W,
    short* __restrict__ Wt, int K, int N) {
  __shared__ float t[64][65];
  const int k0 = blockIdx.y * 64, n0 = blockIdx.x * 64;
  for (int i = threadIdx.x; i < 4096; i += 256) {
    const int r = i >> 6, c = i & 63;
    t[r][c] = W[(size_t)(k0 + r) * N + n0 + c];
  }
  __syncthreads();
  for (int i = threadIdx.x; i < 4096; i += 256) {
    const int r = i >> 6, c = i & 63;
    Wt[(size_t)(n0 + r) * K + k0 + c] = f2bf(t[c][r]);
  }
}

__global__ __launch_bounds__(256) void k_xb(const float* __restrict__ x,
    short* __restrict__ xb, int n8) {
  const int i = blockIdx.x * 256 + threadIdx.x;
  if (i >= n8) return;
  const float4 a = ((const float4*)x)[i * 2];
  const float4 b = ((const float4*)x)[i * 2 + 1];
  short tmp[8] = { f2bf(a.x), f2bf(a.y), f2bf(a.z), f2bf(a.w),
                   f2bf(b.x), f2bf(b.y), f2bf(b.z), f2bf(b.w) };
  *(int4*)&xb[(size_t)i * 8] = *(const int4*)tmp;
}

__global__ __launch_bounds__(256) void k_prep_v(const short* __restrict__ vb,
    short* __restrict__ vt) {
  __shared__ short t[64][72];
  const int bh = blockIdx.y, b = bh >> 4, h = bh & 15;
  const int s0 = blockIdx.x * 64;
  for (int i = threadIdx.x; i < 512; i += 256) {
    const int sl = i >> 3, d8 = (i & 7) * 8;
    int4 vv = *(const int4*)&vb[((size_t)(b * NS + s0 + sl) * NH + h) * NHD + d8];
    const short* sp = (const short*)&vv;
#pragma unroll
    for (int j = 0; j < 8; j++) t[d8 + j][sl] = sp[j];
  }
  __syncthreads();
  for (int i = threadIdx.x; i < 512; i += 256) {
    const int d = i >> 3, c8 = (i & 7) * 8;
    *(int4*)&vt[((size_t)bh * 64 + d) * NS + s0 + c8] = *(const int4*)&t[d][c8];
  }
}

__global__ __launch_bounds__(256) void k_pope(const short* __restrict__ qb,
    const short* __restrict__ kb, const int* __restrict__ positions,
    const float* __restrict__ phb, short* __restrict__ qp,
    short* __restrict__ kp) {
  const size_t i8 = ((size_t)blockIdx.x * 256 + threadIdx.x) * 8;
  const int d0 = (int)(i8 & 63);
  const int h  = (int)((i8 >> 6) & 15);
  const int s  = (int)((i8 >> 10) & 2047);
  const int b  = (int)(i8 >> 21);
  const float posf = (float)positions[s];
  int4 qv = *(const int4*)&qb[i8];
  int4 kv = *(const int4*)&kb[i8];
  const short* qs = (const short*)&qv;
  const short* ks = (const short*)&kv;
  short qc[8], qsn[8], kc[8], ksn[8];
#pragma unroll
  for (int j = 0; j < 8; j++) {
    const int d = d0 + j;
    const float freq = __expf(-(float)d * (float)(9.210340371976184 / 64.0));
    const float muq = softplus_f(bf2f((unsigned short)qs[j]));
    const float muk = softplus_f(bf2f((unsigned short)ks[j]));
    float cb = phb[h * 64 + d];
    cb = fminf(fmaxf(cb, -6.283185307179586f), 0.f);
    float snq, csq, snk, csk;
    __sincosf(posf * freq, &snq, &csq);
    __sincosf(posf * freq + cb, &snk, &csk);
    qc[j] = f2bf(muq * csq); qsn[j] = f2bf(muq * snq);
    kc[j] = f2bf(muk * csk); ksn[j] = f2bf(muk * snk);
  }
  const size_t o = (((size_t)(b * 16 + h) * NS + s) * 128) + d0;
  *(int4*)&qp[o] = *(const int4*)qc;
  *(int4*)&qp[o + 64] = *(const int4*)qsn;
  *(int4*)&kp[o] = *(const int4*)kc;
  *(int4*)&kp[o + 64] = *(const int4*)ksn;
}

// ==== GEMM core: 2-phase double-buffered, global_load_lds, prefetch-first ====
#define BKK 32

__device__ __forceinline__ void gemm_core(const short* __restrict__ A,
    const short* __restrict__ Wt, const int K, const int kbeg, const int kend,
    const int row0, const int col0, short* lsA, short* lsB, f32x4 acc[4][4]) {
  const int tid = threadIdx.x;
  const int lane = tid & 63, wave = tid >> 6;
  const int lr = lane & 15, lk8 = (lane >> 4) << 3;
  const int wr = wave >> 1, wc = wave & 1;
  const int srow = lane >> 2, scol = (lane & 3) << 3;
  const int wbase = wave * 32;
#pragma unroll
  for (int m = 0; m < 4; m++)
#pragma unroll
    for (int n = 0; n < 4; n++) acc[m][n] = 0.f;
  const short* gA0 = &A[(size_t)(row0 + wbase + srow) * K + scol];
  const short* gA1 = gA0 + (size_t)16 * K;
  const short* gB0 = &Wt[(size_t)(col0 + wbase + srow) * K + scol];
  const short* gB1 = gB0 + (size_t)16 * K;
  short* const lA0 = lsA + wbase * 32;
  short* const lB0 = lsB + wbase * 32;
  auto stage = [&](int buf, int kk) {
    const int o = buf * 4096;
    gl16(gA0 + kk, lA0 + o);
    gl16(gA1 + kk, lA0 + o + 512);
    gl16(gB0 + kk, lB0 + o);
    gl16(gB1 + kk, lB0 + o + 512);
  };
  stage(0, kbeg);
  __syncthreads();
  int cur = 0;
  for (int k0 = kbeg; k0 < kend; k0 += BKK) {
    if (k0 + BKK < kend) stage(cur ^ 1, k0 + BKK);  // issue-early: overlaps compute
    const short* la = lsA + cur * 4096;
    const short* lb = lsB + cur * 4096;
    bf16x8 af[4], bf_[4];
#pragma unroll
    for (int m = 0; m < 4; m++)
      af[m] = *(const bf16x8*)&la[(wr * 64 + m * 16 + lr) * 32 + lk8];
#pragma unroll
    for (int n = 0; n < 4; n++)
      bf_[n] = *(const bf16x8*)&lb[(wc * 64 + n * 16 + lr) * 32 + lk8];
#pragma unroll
    for (int m = 0; m < 4; m++)
#pragma unroll
      for (int n = 0; n < 4; n++)
        acc[m][n] = __builtin_amdgcn_mfma_f32_16x16x32_bf16(af[m], bf_[n], acc[m][n], 0, 0, 0);
    __syncthreads();  // drains this iter's prefetch (vmcnt) + read-done (lgkm)
    cur ^= 1;
  }
}

template<int RELU, int OUTBF16>
__global__ __launch_bounds__(256) void k_gemm(const short* __restrict__ A,
    const short* __restrict__ Wt, const float* __restrict__ bias,
    void* __restrict__ C, int M, int N, int K) {
  __shared__ short lsA[2 * 4096], lsB[2 * 4096];
  f32x4 acc[4][4];
  const int row0 = blockIdx.y * 128, col0 = blockIdx.x * 128;
  gemm_core(A, Wt, K, 0, K, row0, col0, lsA, lsB, acc);
  const int lane = threadIdx.x & 63, wave = threadIdx.x >> 6;
  const int lr = lane & 15, r4 = (lane >> 4) << 2;
  const int wr = wave >> 1, wc = wave & 1;
#pragma unroll
  for (int m = 0; m < 4; m++) {
#pragma unroll
    for (int n = 0; n < 4; n++) {
      const int col = col0 + wc * 64 + n * 16 + lr;
      const float bv = bias[col];
#pragma unroll
      for (int r = 0; r < 4; r++) {
        const int row = row0 + wr * 64 + m * 16 + r4 + r;
        float val = acc[m][n][r] + bv;
        if (RELU) val = fmaxf(val, 0.f);
        if (OUTBF16) ((short*)C)[(size_t)row * N + col] = f2bf(val);
        else ((float*)C)[(size_t)row * N + col] = val;
      }
    }
  }
}

// QKV merged: grid.z picks weight/bias/output. bf16 out.
__global__ __launch_bounds__(256) void k_gemm3(const short* __restrict__ xb,
    const short* __restrict__ wqT, const short* __restrict__ wkT,
    const short* __restrict__ wvT, const float* __restrict__ bq,
    const float* __restrict__ bk, const float* __restrict__ bv,
    short* __restrict__ qb, short* __restrict__ kb, short* __restrict__ vb) {
  __shared__ short lsA[2 * 4096], lsB[2 * 4096];
  const int z = blockIdx.z;
  const short* Wt = (z == 0) ? wqT : (z == 1) ? wkT : wvT;
  const float* bias = (z == 0) ? bq : (z == 1) ? bk : bv;
  short* C = (z == 0) ? qb : (z == 1) ? kb : vb;
  f32x4 acc[4][4];
  const int row0 = blockIdx.y * 128, col0 = blockIdx.x * 128;
  gemm_core(xb, Wt, ND, 0, ND, row0, col0, lsA, lsB, acc);
  const int lane = threadIdx.x & 63, wave = threadIdx.x >> 6;
  const int lr = lane & 15, r4 = (lane >> 4) << 2;
  const int wr = wave >> 1, wc = wave & 1;
#pragma unroll
  for (int m = 0; m < 4; m++) {
#pragma unroll
    for (int n = 0; n < 4; n++) {
      const int col = col0 + wc * 64 + n * 16 + lr;
      const float bvs = bias[col];
#pragma unroll
      for (int r = 0; r < 4; r++) {
        const int row = row0 + wr * 64 + m * 16 + r4 + r;
        C[(size_t)row * ND + col] = f2bf(acc[m][n][r] + bvs);
      }
    }
  }
}

// Split-K GEMM: grid.z=2 halves of K; writes unbiased f32 partials to C0/C1.
__global__ __launch_bounds__(256) void k_gemm_sk(const short* __restrict__ A,
    const short* __restrict__ Wt, float* __restrict__ C0, float* __restrict__ C1,
    int M, int N, int K) {
  __shared__ short lsA[2 * 4096], lsB[2 * 4096];
  f32x4 acc[4][4];
  const int z = blockIdx.z;
  const int khalf = K >> 1, kbeg = z * khalf, kend = kbeg + khalf;
  const int row0 = blockIdx.y * 128, col0 = blockIdx.x * 128;
  gemm_core(A, Wt, K, kbeg, kend, row0, col0, lsA, lsB, acc);
  float* C = z ? C1 : C0;
  const int lane = threadIdx.x & 63, wave = threadIdx.x >> 6;
  const int lr = lane & 15, r4 = (lane >> 4) << 2;
  const int wr = wave >> 1, wc = wave & 1;
#pragma unroll
  for (int m = 0; m < 4; m++) {
#pragma unroll
    for (int n = 0; n < 4; n++) {
      const int col = col0 + wc * 64 + n * 16 + lr;
#pragma unroll
      for (int r = 0; r < 4; r++) {
        const int row = row0 + wr * 64 + m * 16 + r4 + r;
        C[(size_t)row * N + col] = acc[m][n][r];
      }
    }
  }
}

// ============ Attention (causal, softmax1), MFMA flash, paired tiles ============
__device__ __forceinline__ void attn_proc(bf16x8 aq[4], f32x4 acc_o[4],
    float m_r[4], float l_r[4], const int rowb, const int kb,
    const short (*kpl)[136], const short (*vl)[72], short (*pl)[72],
    const int lr, const int lk) {
  f32x4 s_acc[4];
#pragma unroll
  for (int n = 0; n < 4; n++) s_acc[n] = 0.f;
#pragma unroll
  for (int ks = 0; ks < 4; ks++) {
    bf16x8 bk_[4];
#pragma unroll
    for (int n = 0; n < 4; n++)
      bk_[n] = *(const bf16x8*)&kpl[n * 16 + lr][ks * 32 + lk * 8];
#pragma unroll
    for (int n = 0; n < 4; n++)
      s_acc[n] = __builtin_amdgcn_mfma_f32_16x16x32_bf16(aq[ks], bk_[n], s_acc[n], 0, 0, 0);
  }
  const float scale = 0.08838834764831845f;
  float pmax[4];
#pragma unroll
  for (int r = 0; r < 4; r++) pmax[r] = -INFINITY;
#pragma unroll
  for (int n = 0; n < 4; n++) {
#pragma unroll
    for (int r = 0; r < 4; r++) {
      const int rel = rowb + lk * 4 + r - kb;
      float sv = s_acc[n][r] * scale;
      sv = (n * 16 + lr <= rel) ? sv : -INFINITY;
      s_acc[n][r] = sv;
      pmax[r] = fmaxf(pmax[r], sv);
    }
  }
#pragma unroll
  for (int off = 8; off; off >>= 1)
#pragma unroll
    for (int r = 0; r < 4; r++) pmax[r] = fmaxf(pmax[r], __shfl_xor(pmax[r], off));
  float fac[4], rs[4];
#pragma unroll
  for (int r = 0; r < 4; r++) {
    const float nm = fmaxf(m_r[r], pmax[r]);
    fac[r] = __expf(m_r[r] - nm);
    m_r[r] = nm;
    rs[r] = 0.f;
  }
#pragma unroll
  for (int n = 0; n < 4; n++) {
#pragma unroll
    for (int r = 0; r < 4; r++) {
      const float p = __expf(s_acc[n][r] - m_r[r]);
      s_acc[n][r] = p;
      rs[r] += p;
    }
  }
#pragma unroll
  for (int off = 8; off; off >>= 1)
#pragma unroll
    for (int r = 0; r < 4; r++) rs[r] += __shfl_xor(rs[r], off);
#pragma unroll
  for (int r = 0; r < 4; r++) l_r[r] = l_r[r] * fac[r] + rs[r];
#pragma unroll
  for (int n = 0; n < 4; n++)
#pragma unroll
    for (int r = 0; r < 4; r++)
      pl[lk * 4 + r][n * 16 + lr] = f2bf(s_acc[n][r]);
#pragma unroll
  for (int n = 0; n < 4; n++)
#pragma unroll
    for (int r = 0; r < 4; r++) acc_o[n][r] *= fac[r];
#pragma unroll
  for (int ks = 0; ks < 2; ks++) {
    const bf16x8 ap = *(const bf16x8*)&pl[lr][ks * 32 + lk * 8];
    bf16x8 bv_[4];
#pragma unroll
    for (int nd = 0; nd < 4; nd++)
      bv_[nd] = *(const bf16x8*)&vl[nd * 16 + lr][ks * 32 + lk * 8];
#pragma unroll
    for (int nd = 0; nd < 4; nd++)
      acc_o[nd] = __builtin_amdgcn_mfma_f32_16x16x32_bf16(ap, bv_[nd], acc_o[nd], 0, 0, 0);
  }
}

__global__ __launch_bounds__(512) void k_attn2(
    const short* __restrict__ qp, const short* __restrict__ kp,
    const short* __restrict__ vt, short* __restrict__ attn) {
  __shared__ short kp_l[2][64][136];
  __shared__ short v_l[2][64][72];
  __shared__ short p_l[8][16][72];
  const int bh = blockIdx.y, b = bh >> 4, h = bh & 15;
  const int tL = blockIdx.x, tH = 15 - tL;
  const int q0L = tL * 128, q0H = tH * 128;
  const int tid = threadIdx.x, wave = tid >> 6, lane = tid & 63;
  const int lr = lane & 15, lk = lane >> 4;

  bf16x8 aqH[4], aqL[4];
  {
    const short* qrH = qp + ((size_t)bh * NS + q0H + wave * 16 + lr) * 128;
    const short* qrL = qp + ((size_t)bh * NS + q0L + wave * 16 + lr) * 128;
#pragma unroll
    for (int ks = 0; ks < 4; ks++) {
      aqH[ks] = *(const bf16x8*)&qrH[ks * 32 + lk * 8];
      aqL[ks] = *(const bf16x8*)&qrL[ks * 32 + lk * 8];
    }
  }
  f32x4 accH[4], accL[4];
  float mH[4], lH[4], mL[4], lL[4];
#pragma unroll
  for (int r = 0; r < 4; r++) { mH[r] = -INFINITY; lH[r] = 0.f; mL[r] = -INFINITY; lL[r] = 0.f; }
#pragma unroll
  for (int n = 0; n < 4; n++) { accH[n] = 0.f; accL[n] = 0.f; }

  const short* kpb = kp + (size_t)bh * NS * 128;
  const short* vtb = vt + (size_t)bh * 64 * NS;
  const int nch = q0H / 64 + 2;
  const int rowbH = q0H + wave * 16, rowbL = q0L + wave * 16;

  const int krow = tid >> 3, kcol = (tid & 7) * 16;
  const int vrow = tid >> 3, vcol = (tid & 7) * 8;

  int4 rk0, rk1, rv;
  {
    const short* s = &kpb[(size_t)krow * 128 + kcol];
    rk0 = ((const int4*)s)[0]; rk1 = ((const int4*)s)[1];
    rv = *(const int4*)&vtb[(size_t)vrow * NS + vcol];
  }
  ((int4*)&kp_l[0][krow][kcol])[0] = rk0;
  ((int4*)&kp_l[0][krow][kcol])[1] = rk1;
  *(int4*)&v_l[0][vrow][vcol] = rv;
  __syncthreads();

  for (int c = 0; c < nch; c++) {
    const int kb = c * 64;
    const int cur = c & 1;
    const bool more = (c + 1) < nch;
    if (more) {
      const int kb2 = kb + 64;
      const short* s = &kpb[(size_t)(kb2 + krow) * 128 + kcol];
      rk0 = ((const int4*)s)[0]; rk1 = ((const int4*)s)[1];
      rv = *(const int4*)&vtb[(size_t)vrow * NS + kb2 + vcol];
    }
    if (rowbH + 15 >= kb)
      attn_proc(aqH, accH, mH, lH, rowbH, kb, kp_l[cur], v_l[cur], p_l[wave], lr, lk);
    if (rowbL + 15 >= kb)
      attn_proc(aqL, accL, mL, lL, rowbL, kb, kp_l[cur], v_l[cur], p_l[wave], lr, lk);
    __syncthreads();
    if (more) {
      ((int4*)&kp_l[cur ^ 1][krow][kcol])[0] = rk0;
      ((int4*)&kp_l[cur ^ 1][krow][kcol])[1] = rk1;
      *(int4*)&v_l[cur ^ 1][vrow][vcol] = rv;
    }
    __syncthreads();
  }
#pragma unroll
  for (int r = 0; r < 4; r++) {
    lH[r] = 1.f / (__expf(-mH[r]) + lH[r]);
    lL[r] = 1.f / (__expf(-mL[r]) + lL[r]);
  }
#pragma unroll
  for (int nd = 0; nd < 4; nd++) {
#pragma unroll
    for (int r = 0; r < 4; r++) {
      const int d = nd * 16 + lr;
      const int rowH = q0H + wave * 16 + lk * 4 + r;
      const int rowL = q0L + wave * 16 + lk * 4 + r;
      attn[(((size_t)b * NS + rowH) * NH + h) * NHD + d] = f2bf(accH[nd][r] * lH[r]);
      attn[(((size_t)b * NS + rowL) * NH + h) * NHD + d] = f2bf(accL[nd][r] * lL[r]);
    }
  }
}

// ==== LayerNorm with fused partial-sum + bias: x = A0 + A1 + badd + R ====
template<int RBF16, int OUTBF16>
__global__ __launch_bounds__(256) void k_ln3(const float* __restrict__ A0,
    const float* __restrict__ A1, const float* __restrict__ badd,
    const void* __restrict__ Rv, const float* __restrict__ g,
    const float* __restrict__ be, void* __restrict__ out) {
  const int row = blockIdx.x, tid = threadIdx.x;
  const float4 a0 = ((const float4*)(A0 + (size_t)row * ND))[tid];
  const float4 a1 = ((const float4*)(A1 + (size_t)row * ND))[tid];
  const float4 bd = ((const float4*)badd)[tid];
  float r0, r1, r2, r3;
  if (RBF16) {
    short4 rr = *(const short4*)((const short*)Rv + (size_t)row * ND + tid * 4);
    r0 = bf2f((unsigned short)rr.x); r1 = bf2f((unsigned short)rr.y);
    r2 = bf2f((unsigned short)rr.z); r3 = bf2f((unsigned short)rr.w);
  } else {
    const float4 rr = ((const float4*)((const float*)Rv + (size_t)row * ND))[tid];
    r0 = rr.x; r1 = rr.y; r2 = rr.z; r3 = rr.w;
  }
  const float x0 = a0.x + a1.x + bd.x + r0;
  const float x1 = a0.y + a1.y + bd.y + r1;
  const float x2 = a0.z + a1.z + bd.z + r2;
  const float x3 = a0.w + a1.w + bd.w + r3;
  float s = x0 + x1 + x2 + x3;
  float sq = x0 * x0 + x1 * x1 + x2 * x2 + x3 * x3;
#pragma unroll
  for (int off = 32; off; off >>= 1) {
    s += __shfl_xor(s, off);
    sq += __shfl_xor(sq, off);
  }
  __shared__ float ss[4], ssq[4];
  const int wave = tid >> 6, lane = tid & 63;
  if (lane == 0) { ss[wave] = s; ssq[wave] = sq; }
  __syncthreads();
  s = ss[0] + ss[1] + ss[2] + ss[3];
  sq = ssq[0] + ssq[1] + ssq[2] + ssq[3];
  const float mu = s * (1.f / (float)ND);
  const float var = sq * (1.f / (float)ND) - mu * mu;
  const float rstd = rsqrtf(var + 1e-5f);
  const float4 gg = ((const float4*)g)[tid];
  const float4 bb = ((const float4*)be)[tid];
  const float o0 = (x0 - mu) * rstd * gg.x + bb.x;
  const float o1 = (x1 - mu) * rstd * gg.y + bb.y;
  const float o2 = (x2 - mu) * rstd * gg.z + bb.z;
  const float o3 = (x3 - mu) * rstd * gg.w + bb.w;
  if (OUTBF16) {
    short4 ov = { f2bf(o0), f2bf(o1), f2bf(o2), f2bf(o3) };
    *(short4*)((short*)out + (size_t)row * ND + tid * 4) = ov;
  } else {
    float4 ov = { o0, o1, o2, o3 };
    ((float4*)((float*)out + (size_t)row * ND))[tid] = ov;
  }
}

extern "C" void kernel_launch(void* const* d_in, const int* in_sizes, int n_in,
                              void* d_out, int out_size, void* d_ws, size_t ws_size,
                              hipStream_t stream) {
  const float* x   = (const float*)d_in[0];
  const int*   pos = (const int*)d_in[1];
  const float* wq  = (const float*)d_in[2];
  const float* bq  = (const float*)d_in[3];
  const float* wk  = (const float*)d_in[4];
  const float* bk  = (const float*)d_in[5];
  const float* wv  = (const float*)d_in[6];
  const float* bv  = (const float*)d_in[7];
  const float* wo  = (const float*)d_in[8];
  const float* bo  = (const float*)d_in[9];
  const float* phb = (const float*)d_in[10];
  const float* w1  = (const float*)d_in[11];
  const float* b1  = (const float*)d_in[12];
  const float* w2  = (const float*)d_in[13];
  const float* b2  = (const float*)d_in[14];
  const float* g1  = (const float*)d_in[15];
  const float* be1 = (const float*)d_in[16];
  const float* g2  = (const float*)d_in[17];
  const float* be2 = (const float*)d_in[18];

  char* ws = (char*)d_ws;
  const size_t MB = 1024 * 1024;
  if (ws_size < 112 * MB) return;
  short* qb     = (short*)(ws + 0 * MB);    // 8MB
  short* kb     = (short*)(ws + 8 * MB);    // 8MB
  short* vb     = (short*)(ws + 16 * MB);   // 8MB
  short* qp     = (short*)(ws + 24 * MB);   // 16MB
  short* kp     = (short*)(ws + 40 * MB);   // 16MB
  short* vt     = (short*)(ws + 56 * MB);   // 8MB
  short* xb     = (short*)(ws + 64 * MB);   // 8MB
  short* attnb  = (short*)(ws + 72 * MB);   // 8MB
  float* attnC0 = (float*)(ws + 0 * MB);    // 16MB (over qb+kb, dead after pope)
  float* attnC1 = (float*)(ws + 24 * MB);   // 16MB (over qp, dead after attn)
  short* hb     = (short*)(ws + 16 * MB);   // 8MB (over vb, dead after prep_v)
  short* ffh    = (short*)(ws + 40 * MB);   // 32MB (over kp+vt+xb, dead)
  float* ffC0   = (float*)(ws + 72 * MB);   // 16MB (over attnb, dead after wo)
  float* ffC1   = (float*)(ws + 0 * MB);    // 16MB (over attnC0, dead after ln1)
  short* wqT    = (short*)(ws + 88 * MB);
  short* wkT    = (short*)(ws + 90 * MB);
  short* wvT    = (short*)(ws + 92 * MB);
  short* woT    = (short*)(ws + 94 * MB);
  short* w1T    = (short*)(ws + 96 * MB);   // 8MB [DFF][D]
  short* w2T    = (short*)(ws + 104 * MB);  // 8MB [D][DFF]

  dim3 blk(256);
  k_wt<<<dim3(16, 16), blk, 0, stream>>>(wq, wqT, ND, ND);
  k_wt<<<dim3(16, 16), blk, 0, stream>>>(wk, wkT, ND, ND);
  k_wt<<<dim3(16, 16), blk, 0, stream>>>(wv, wvT, ND, ND);
  k_wt<<<dim3(16, 16), blk, 0, stream>>>(wo, woT, ND, ND);
  k_wt<<<dim3(64, 16), blk, 0, stream>>>(w1, w1T, ND, NDFF);
  k_wt<<<dim3(16, 64), blk, 0, stream>>>(w2, w2T, NDFF, ND);
  k_xb<<<dim3((NB * NS * ND / 8 + 255) / 256), blk, 0, stream>>>(x, xb, NB * NS * ND / 8);
  // QKV: one merged launch, 768 blocks co-resident
  k_gemm3<<<dim3(ND / 128, (NB * NS) / 128, 3), blk, 0, stream>>>(
      xb, wqT, wkT, wvT, bq, bk, bv, qb, kb, vb);
  k_pope<<<dim3(NB * NS * ND / 8 / 256), blk, 0, stream>>>(qb, kb, pos, phb, qp, kp);
  k_prep_v<<<dim3(NS / 64, NB * NH), blk, 0, stream>>>(vb, vt);
  k_attn2<<<dim3(8, NB * NH), dim3(512), 0, stream>>>(qp, kp, vt, attnb);
  // wo: split-K (z=2), partials summed in ln1
  k_gemm_sk<<<dim3(ND / 128, (NB * NS) / 128, 2), blk, 0, stream>>>(
      attnb, woT, attnC0, attnC1, NB * NS, ND, ND);
  k_ln3<0, 1><<<dim3(NB * NS), blk, 0, stream>>>(attnC0, attnC1, bo, x, g1, be1, hb);
  // ffn1: full-K (grid 1024 blocks already)
  k_gemm<1, 1><<<dim3(NDFF / 128, (NB * NS) / 128), blk, 0, stream>>>(
      hb, w1T, b1, ffh, NB * NS, NDFF, ND);
  // ffn2: split-K (z=2), partials + b2 summed in ln2
  k_gemm_sk<<<dim3(ND / 128, (NB * NS) / 128, 2), blk, 0, stream>>>(
      ffh, w2T, ffC0, ffC1, NB * NS, ND, NDFF);
  k_ln3<1, 0><<<dim3(NB * NS), blk, 0, stream>>>(ffC0, ffC1, b2, hb, g2, be2, (float*)d_out);
}

// Round 8
// 295.639 us; speedup vs baseline: 9.6478x; 1.0917x over previous
//
#include <hip/hip_runtime.h>
#include <hip/hip_bf16.h>
#include <math.h>

#define NB 2
#define NS 2048
#define ND 1024
#define NH 16
#define NHD 64
#define NDFF 4096

typedef __attribute__((ext_vector_type(4))) float f32x4;
typedef __attribute__((ext_vector_type(8))) short bf16x8;

__device__ __forceinline__ short f2bf(float f) {
  union { float f; unsigned u; } v; v.f = f;
  unsigned r = v.u + 0x7fffu + ((v.u >> 16) & 1u);
  return (short)(r >> 16);
}
__device__ __forceinline__ float bf2f(unsigned short u) {
  union { unsigned u; float f; } v; v.u = ((unsigned)u) << 16; return v.f;
}
__device__ __forceinline__ float softplus_f(float x) {
  return fmaxf(x, 0.f) + log1pf(__expf(-fabsf(x)));
}
// async global->LDS, 16B per lane; LDS dest wave-uniform (HW adds lane*16)
__device__ __forceinline__ void gl16(const short* g, short* l) {
  __builtin_amdgcn_global_load_lds(
      (const __attribute__((address_space(1))) void*)g,
      (__attribute__((address_space(3))) void*)l, 16, 0, 0);
}
// XCD-chunked bijective block remap: each XCD owns a contiguous row-slab x all cols.
// Requires gridDim.y % 8 == 0 (always 32 here). Blocks sharing an A row-panel land
// on ONE XCD's L2 instead of eight.
__device__ __forceinline__ void xcd_map(int& row0, int& col0) {
  const int gx = gridDim.x, gy = gridDim.y;
  const int bid = blockIdx.y * gx + blockIdx.x;
  const int rows_px = gy >> 3;
  const int xcd = bid & 7, l = bid >> 3;
  row0 = (xcd * rows_px + (l % rows_px)) * 128;
  col0 = (l / rows_px) * 128;
}

// ============ prep kernels ============
__global__ __launch_bounds__(256) void k_wt(const float* __restrict__ W,
    short* __restrict__ Wt, int K, int N) {
  __shared__ float t[64][65];
  const int k0 = blockIdx.y * 64, n0 = blockIdx.x * 64;
  for (int i = threadIdx.x; i < 4096; i += 256) {
    const int r = i >> 6, c = i & 63;
    t[r][c] = W[(size_t)(k0 + r) * N + n0 + c];
  }
  __syncthreads();
  for (int i = threadIdx.x; i < 4096; i += 256) {
    const int r = i >> 6, c = i & 63;
    Wt[(size_t)(n0 + r) * K + k0 + c] = f2bf(t[c][r]);
  }
}

__global__ __launch_bounds__(256) void k_xb(const float* __restrict__ x,
    short* __restrict__ xb, int n8) {
  const int i = blockIdx.x * 256 + threadIdx.x;
  if (i >= n8) return;
  const float4 a = ((const float4*)x)[i * 2];
  const float4 b = ((const float4*)x)[i * 2 + 1];
  short tmp[8] = { f2bf(a.x), f2bf(a.y), f2bf(a.z), f2bf(a.w),
                   f2bf(b.x), f2bf(b.y), f2bf(b.z), f2bf(b.w) };
  *(int4*)&xb[(size_t)i * 8] = *(const int4*)tmp;
}

__global__ __launch_bounds__(256) void k_prep_v(const short* __restrict__ vb,
    short* __restrict__ vt) {
  __shared__ short t[64][72];
  const int bh = blockIdx.y, b = bh >> 4, h = bh & 15;
  const int s0 = blockIdx.x * 64;
  for (int i = threadIdx.x; i < 512; i += 256) {
    const int sl = i >> 3, d8 = (i & 7) * 8;
    int4 vv = *(const int4*)&vb[((size_t)(b * NS + s0 + sl) * NH + h) * NHD + d8];
    const short* sp = (const short*)&vv;
#pragma unroll
    for (int j = 0; j < 8; j++) t[d8 + j][sl] = sp[j];
  }
  __syncthreads();
  for (int i = threadIdx.x; i < 512; i += 256) {
    const int d = i >> 3, c8 = (i & 7) * 8;
    *(int4*)&vt[((size_t)bh * 64 + d) * NS + s0 + c8] = *(const int4*)&t[d][c8];
  }
}

__global__ __launch_bounds__(256) void k_pope(const short* __restrict__ qb,
    const short* __restrict__ kb, const int* __restrict__ positions,
    const float* __restrict__ phb, short* __restrict__ qp,
    short* __restrict__ kp) {
  const size_t i8 = ((size_t)blockIdx.x * 256 + threadIdx.x) * 8;
  const int d0 = (int)(i8 & 63);
  const int h  = (int)((i8 >> 6) & 15);
  const int s  = (int)((i8 >> 10) & 2047);
  const int b  = (int)(i8 >> 21);
  const float posf = (float)positions[s];
  int4 qv = *(const int4*)&qb[i8];
  int4 kv = *(const int4*)&kb[i8];
  const short* qs = (const short*)&qv;
  const short* ks = (const short*)&kv;
  short qc[8], qsn[8], kc[8], ksn[8];
#pragma unroll
  for (int j = 0; j < 8; j++) {
    const int d = d0 + j;
    const float freq = __expf(-(float)d * (float)(9.210340371976184 / 64.0));
    const float muq = softplus_f(bf2f((unsigned short)qs[j]));
    const float muk = softplus_f(bf2f((unsigned short)ks[j]));
    float cb = phb[h * 64 + d];
    cb = fminf(fmaxf(cb, -6.283185307179586f), 0.f);
    float snq, csq, snk, csk;
    __sincosf(posf * freq, &snq, &csq);
    __sincosf(posf * freq + cb, &snk, &csk);
    qc[j] = f2bf(muq * csq); qsn[j] = f2bf(muq * snq);
    kc[j] = f2bf(muk * csk); ksn[j] = f2bf(muk * snk);
  }
  const size_t o = (((size_t)(b * 16 + h) * NS + s) * 128) + d0;
  *(int4*)&qp[o] = *(const int4*)qc;
  *(int4*)&qp[o + 64] = *(const int4*)qsn;
  *(int4*)&kp[o] = *(const int4*)kc;
  *(int4*)&kp[o + 64] = *(const int4*)ksn;
}

// ==== GEMM core: 2-phase double-buffered, global_load_lds, prefetch-first ====
#define BKK 32

__device__ __forceinline__ void gemm_core(const short* __restrict__ A,
    const short* __restrict__ Wt, const int K, const int kbeg, const int kend,
    const int row0, const int col0, short* lsA, short* lsB, f32x4 acc[4][4]) {
  const int tid = threadIdx.x;
  const int lane = tid & 63, wave = tid >> 6;
  const int lr = lane & 15, lk8 = (lane >> 4) << 3;
  const int wr = wave >> 1, wc = wave & 1;
  const int srow = lane >> 2, scol = (lane & 3) << 3;
  const int wbase = wave * 32;
#pragma unroll
  for (int m = 0; m < 4; m++)
#pragma unroll
    for (int n = 0; n < 4; n++) acc[m][n] = 0.f;
  const short* gA0 = &A[(size_t)(row0 + wbase + srow) * K + scol];
  const short* gA1 = gA0 + (size_t)16 * K;
  const short* gB0 = &Wt[(size_t)(col0 + wbase + srow) * K + scol];
  const short* gB1 = gB0 + (size_t)16 * K;
  short* const lA0 = lsA + wbase * 32;
  short* const lB0 = lsB + wbase * 32;
  auto stage = [&](int buf, int kk) {
    const int o = buf * 4096;
    gl16(gA0 + kk, lA0 + o);
    gl16(gA1 + kk, lA0 + o + 512);
    gl16(gB0 + kk, lB0 + o);
    gl16(gB1 + kk, lB0 + o + 512);
  };
  stage(0, kbeg);
  __syncthreads();
  int cur = 0;
  for (int k0 = kbeg; k0 < kend; k0 += BKK) {
    if (k0 + BKK < kend) stage(cur ^ 1, k0 + BKK);  // issue-early: overlaps compute
    const short* la = lsA + cur * 4096;
    const short* lb = lsB + cur * 4096;
    bf16x8 af[4], bf_[4];
#pragma unroll
    for (int m = 0; m < 4; m++)
      af[m] = *(const bf16x8*)&la[(wr * 64 + m * 16 + lr) * 32 + lk8];
#pragma unroll
    for (int n = 0; n < 4; n++)
      bf_[n] = *(const bf16x8*)&lb[(wc * 64 + n * 16 + lr) * 32 + lk8];
#pragma unroll
    for (int m = 0; m < 4; m++)
#pragma unroll
      for (int n = 0; n < 4; n++)
        acc[m][n] = __builtin_amdgcn_mfma_f32_16x16x32_bf16(af[m], bf_[n], acc[m][n], 0, 0, 0);
    __syncthreads();  // drains this iter's prefetch (vmcnt) + read-done (lgkm)
    cur ^= 1;
  }
}

template<int RELU, int OUTBF16>
__global__ __launch_bounds__(256) void k_gemm(const short* __restrict__ A,
    const short* __restrict__ Wt, const float* __restrict__ bias,
    void* __restrict__ C, int M, int N, int K) {
  __shared__ short lsA[2 * 4096], lsB[2 * 4096];
  f32x4 acc[4][4];
  int row0, col0;
  xcd_map(row0, col0);
  gemm_core(A, Wt, K, 0, K, row0, col0, lsA, lsB, acc);
  const int lane = threadIdx.x & 63, wave = threadIdx.x >> 6;
  const int lr = lane & 15, r4 = (lane >> 4) << 2;
  const int wr = wave >> 1, wc = wave & 1;
#pragma unroll
  for (int m = 0; m < 4; m++) {
#pragma unroll
    for (int n = 0; n < 4; n++) {
      const int col = col0 + wc * 64 + n * 16 + lr;
      const float bv = bias[col];
#pragma unroll
      for (int r = 0; r < 4; r++) {
        const int row = row0 + wr * 64 + m * 16 + r4 + r;
        float val = acc[m][n][r] + bv;
        if (RELU) val = fmaxf(val, 0.f);
        if (OUTBF16) ((short*)C)[(size_t)row * N + col] = f2bf(val);
        else ((float*)C)[(size_t)row * N + col] = val;
      }
    }
  }
}

// QKV merged: grid.z picks weight/bias/output. bf16 out.
__global__ __launch_bounds__(256) void k_gemm3(const short* __restrict__ xb,
    const short* __restrict__ wqT, const short* __restrict__ wkT,
    const short* __restrict__ wvT, const float* __restrict__ bq,
    const float* __restrict__ bk, const float* __restrict__ bv,
    short* __restrict__ qb, short* __restrict__ kb, short* __restrict__ vb) {
  __shared__ short lsA[2 * 4096], lsB[2 * 4096];
  const int z = blockIdx.z;
  const short* Wt = (z == 0) ? wqT : (z == 1) ? wkT : wvT;
  const float* bias = (z == 0) ? bq : (z == 1) ? bk : bv;
  short* C = (z == 0) ? qb : (z == 1) ? kb : vb;
  f32x4 acc[4][4];
  int row0, col0;
  xcd_map(row0, col0);
  gemm_core(xb, Wt, ND, 0, ND, row0, col0, lsA, lsB, acc);
  const int lane = threadIdx.x & 63, wave = threadIdx.x >> 6;
  const int lr = lane & 15, r4 = (lane >> 4) << 2;
  const int wr = wave >> 1, wc = wave & 1;
#pragma unroll
  for (int m = 0; m < 4; m++) {
#pragma unroll
    for (int n = 0; n < 4; n++) {
      const int col = col0 + wc * 64 + n * 16 + lr;
      const float bvs = bias[col];
#pragma unroll
      for (int r = 0; r < 4; r++) {
        const int row = row0 + wr * 64 + m * 16 + r4 + r;
        C[(size_t)row * ND + col] = f2bf(acc[m][n][r] + bvs);
      }
    }
  }
}

// Split-K GEMM: grid.z=2 halves of K; writes unbiased f32 partials to C0/C1.
__global__ __launch_bounds__(256) void k_gemm_sk(const short* __restrict__ A,
    const short* __restrict__ Wt, float* __restrict__ C0, float* __restrict__ C1,
    int M, int N, int K) {
  __shared__ short lsA[2 * 4096], lsB[2 * 4096];
  f32x4 acc[4][4];
  const int z = blockIdx.z;
  const int khalf = K >> 1, kbeg = z * khalf, kend = kbeg + khalf;
  int row0, col0;
  xcd_map(row0, col0);
  gemm_core(A, Wt, K, kbeg, kend, row0, col0, lsA, lsB, acc);
  float* C = z ? C1 : C0;
  const int lane = threadIdx.x & 63, wave = threadIdx.x >> 6;
  const int lr = lane & 15, r4 = (lane >> 4) << 2;
  const int wr = wave >> 1, wc = wave & 1;
#pragma unroll
  for (int m = 0; m < 4; m++) {
#pragma unroll
    for (int n = 0; n < 4; n++) {
      const int col = col0 + wc * 64 + n * 16 + lr;
#pragma unroll
      for (int r = 0; r < 4; r++) {
        const int row = row0 + wr * 64 + m * 16 + r4 + r;
        C[(size_t)row * N + col] = acc[m][n][r];
      }
    }
  }
}

// ============ Attention (causal, softmax1), MFMA flash, paired tiles ============
// m=0 fixed (softmax1 is shift-invariant; scores provably < ~6, no overflow):
// no max tracking, no rescale. Per-lane partial row-sums, reduced once at epilogue.
__device__ __forceinline__ void attn_proc(const bf16x8 aq[4], f32x4 acc_o[4],
    float l_p[4], const int rowb, const int kb,
    const short (*kpl)[136], const short (*vl)[72], short (*pl)[72],
    const int lr, const int lk) {
  f32x4 s_acc[4];
#pragma unroll
  for (int n = 0; n < 4; n++) s_acc[n] = 0.f;
#pragma unroll
  for (int ks = 0; ks < 4; ks++) {
    bf16x8 bk_[4];
#pragma unroll
    for (int n = 0; n < 4; n++)
      bk_[n] = *(const bf16x8*)&kpl[n * 16 + lr][ks * 32 + lk * 8];
#pragma unroll
    for (int n = 0; n < 4; n++)
      s_acc[n] = __builtin_amdgcn_mfma_f32_16x16x32_bf16(aq[ks], bk_[n], s_acc[n], 0, 0, 0);
  }
  const float scale = 0.08838834764831845f;
  const bool domask = (kb + 63 > rowb);  // wave-uniform: diagonal-crossing chunk
#pragma unroll
  for (int n = 0; n < 4; n++) {
#pragma unroll
    for (int r = 0; r < 4; r++) {
      const float sv = s_acc[n][r] * scale;
      float p;
      if (domask) {
        const int rel = rowb + lk * 4 + r - kb;
        p = (n * 16 + lr <= rel) ? __expf(sv) : 0.f;
      } else {
        p = __expf(sv);
      }
      s_acc[n][r] = p;
      l_p[r] += p;  // per-lane partial; cross-lane reduce deferred to epilogue
    }
  }
  // P -> wave-private LDS strip (same-wave RAW, no barrier)
#pragma unroll
  for (int n = 0; n < 4; n++)
#pragma unroll
    for (int r = 0; r < 4; r++)
      pl[lk * 4 + r][n * 16 + lr] = f2bf(s_acc[n][r]);
#pragma unroll
  for (int ks = 0; ks < 2; ks++) {
    const bf16x8 ap = *(const bf16x8*)&pl[lr][ks * 32 + lk * 8];
    bf16x8 bv_[4];
#pragma unroll
    for (int nd = 0; nd < 4; nd++)
      bv_[nd] = *(const bf16x8*)&vl[nd * 16 + lr][ks * 32 + lk * 8];
#pragma unroll
    for (int nd = 0; nd < 4; nd++)
      acc_o[nd] = __builtin_amdgcn_mfma_f32_16x16x32_bf16(ap, bv_[nd], acc_o[nd], 0, 0, 0);
  }
}

__global__ __launch_bounds__(512) void k_attn2(
    const short* __restrict__ qp, const short* __restrict__ kp,
    const short* __restrict__ vt, short* __restrict__ attn) {
  __shared__ short kp_l[2][64][136];
  __shared__ short v_l[2][64][72];
  __shared__ short p_l[8][16][72];
  const int bh = blockIdx.y, b = bh >> 4, h = bh & 15;
  const int tL = blockIdx.x, tH = 15 - tL;
  const int q0L = tL * 128, q0H = tH * 128;
  const int tid = threadIdx.x, wave = tid >> 6, lane = tid & 63;
  const int lr = lane & 15, lk = lane >> 4;

  bf16x8 aqH[4], aqL[4];
  {
    const short* qrH = qp + ((size_t)bh * NS + q0H + wave * 16 + lr) * 128;
    const short* qrL = qp + ((size_t)bh * NS + q0L + wave * 16 + lr) * 128;
#pragma unroll
    for (int ks = 0; ks < 4; ks++) {
      aqH[ks] = *(const bf16x8*)&qrH[ks * 32 + lk * 8];
      aqL[ks] = *(const bf16x8*)&qrL[ks * 32 + lk * 8];
    }
  }
  f32x4 accH[4], accL[4];
  float lH[4], lL[4];
#pragma unroll
  for (int r = 0; r < 4; r++) { lH[r] = 0.f; lL[r] = 0.f; }
#pragma unroll
  for (int n = 0; n < 4; n++) { accH[n] = 0.f; accL[n] = 0.f; }

  const short* kpb = kp + (size_t)bh * NS * 128;
  const short* vtb = vt + (size_t)bh * 64 * NS;
  const int nch = q0H / 64 + 2;
  const int rowbH = q0H + wave * 16, rowbL = q0L + wave * 16;

  const int krow = tid >> 3, kcol = (tid & 7) * 16;
  const int vrow = tid >> 3, vcol = (tid & 7) * 8;

  int4 rk0, rk1, rv;
  {
    const short* s = &kpb[(size_t)krow * 128 + kcol];
    rk0 = ((const int4*)s)[0]; rk1 = ((const int4*)s)[1];
    rv = *(const int4*)&vtb[(size_t)vrow * NS + vcol];
  }
  ((int4*)&kp_l[0][krow][kcol])[0] = rk0;
  ((int4*)&kp_l[0][krow][kcol])[1] = rk1;
  *(int4*)&v_l[0][vrow][vcol] = rv;
  __syncthreads();

  for (int c = 0; c < nch; c++) {
    const int kb = c * 64;
    const int cur = c & 1;
    const bool more = (c + 1) < nch;
    if (more) {
      const int kb2 = kb + 64;
      const short* s = &kpb[(size_t)(kb2 + krow) * 128 + kcol];
      rk0 = ((const int4*)s)[0]; rk1 = ((const int4*)s)[1];
      rv = *(const int4*)&vtb[(size_t)vrow * NS + kb2 + vcol];
    }
    if (rowbH + 15 >= kb)
      attn_proc(aqH, accH, lH, rowbH, kb, kp_l[cur], v_l[cur], p_l[wave], lr, lk);
    if (rowbL + 15 >= kb)
      attn_proc(aqL, accL, lL, rowbL, kb, kp_l[cur], v_l[cur], p_l[wave], lr, lk);
    if (more) {
      // writes target buffer cur^1 (nobody reads it this iteration); the single
      // barrier below both publishes these writes and closes the read phase.
      ((int4*)&kp_l[cur ^ 1][krow][kcol])[0] = rk0;
      ((int4*)&kp_l[cur ^ 1][krow][kcol])[1] = rk1;
      *(int4*)&v_l[cur ^ 1][vrow][vcol] = rv;
    }
    __syncthreads();
  }
  // epilogue: single cross-lane reduce of the deferred row sums (lane bits 0-3)
#pragma unroll
  for (int r = 0; r < 4; r++) {
    float sH = lH[r], sL = lL[r];
#pragma unroll
    for (int off = 8; off; off >>= 1) {
      sH += __shfl_xor(sH, off);
      sL += __shfl_xor(sL, off);
    }
    lH[r] = 1.f / (1.f + sH);   // softmax1 with m=0: denom = 1 + sum
    lL[r] = 1.f / (1.f + sL);
  }
#pragma unroll
  for (int nd = 0; nd < 4; nd++) {
#pragma unroll
    for (int r = 0; r < 4; r++) {
      const int d = nd * 16 + lr;
      const int rowH = q0H + wave * 16 + lk * 4 + r;
      const int rowL = q0L + wave * 16 + lk * 4 + r;
      attn[(((size_t)b * NS + rowH) * NH + h) * NHD + d] = f2bf(accH[nd][r] * lH[r]);
      attn[(((size_t)b * NS + rowL) * NH + h) * NHD + d] = f2bf(accL[nd][r] * lL[r]);
    }
  }
}

// ==== LayerNorm with fused partial-sum + bias: x = A0 + A1 + badd + R ====
template<int RBF16, int OUTBF16>
__global__ __launch_bounds__(256) void k_ln3(const float* __restrict__ A0,
    const float* __restrict__ A1, const float* __restrict__ badd,
    const void* __restrict__ Rv, const float* __restrict__ g,
    const float* __restrict__ be, void* __restrict__ out) {
  const int row = blockIdx.x, tid = threadIdx.x;
  const float4 a0 = ((const float4*)(A0 + (size_t)row * ND))[tid];
  const float4 a1 = ((const float4*)(A1 + (size_t)row * ND))[tid];
  const float4 bd = ((const float4*)badd)[tid];
  float r0, r1, r2, r3;
  if (RBF16) {
    short4 rr = *(const short4*)((const short*)Rv + (size_t)row * ND + tid * 4);
    r0 = bf2f((unsigned short)rr.x); r1 = bf2f((unsigned short)rr.y);
    r2 = bf2f((unsigned short)rr.z); r3 = bf2f((unsigned short)rr.w);
  } else {
    const float4 rr = ((const float4*)((const float*)Rv + (size_t)row * ND))[tid];
    r0 = rr.x; r1 = rr.y; r2 = rr.z; r3 = rr.w;
  }
  const float x0 = a0.x + a1.x + bd.x + r0;
  const float x1 = a0.y + a1.y + bd.y + r1;
  const float x2 = a0.z + a1.z + bd.z + r2;
  const float x3 = a0.w + a1.w + bd.w + r3;
  float s = x0 + x1 + x2 + x3;
  float sq = x0 * x0 + x1 * x1 + x2 * x2 + x3 * x3;
#pragma unroll
  for (int off = 32; off; off >>= 1) {
    s += __shfl_xor(s, off);
    sq += __shfl_xor(sq, off);
  }
  __shared__ float ss[4], ssq[4];
  const int wave = tid >> 6, lane = tid & 63;
  if (lane == 0) { ss[wave] = s; ssq[wave] = sq; }
  __syncthreads();
  s = ss[0] + ss[1] + ss[2] + ss[3];
  sq = ssq[0] + ssq[1] + ssq[2] + ssq[3];
  const float mu = s * (1.f / (float)ND);
  const float var = sq * (1.f / (float)ND) - mu * mu;
  const float rstd = rsqrtf(var + 1e-5f);
  const float4 gg = ((const float4*)g)[tid];
  const float4 bb = ((const float4*)be)[tid];
  const float o0 = (x0 - mu) * rstd * gg.x + bb.x;
  const float o1 = (x1 - mu) * rstd * gg.y + bb.y;
  const float o2 = (x2 - mu) * rstd * gg.z + bb.z;
  const float o3 = (x3 - mu) * rstd * gg.w + bb.w;
  if (OUTBF16) {
    short4 ov = { f2bf(o0), f2bf(o1), f2bf(o2), f2bf(o3) };
    *(short4*)((short*)out + (size_t)row * ND + tid * 4) = ov;
  } else {
    float4 ov = { o0, o1, o2, o3 };
    ((float4*)((float*)out + (size_t)row * ND))[tid] = ov;
  }
}

extern "C" void kernel_launch(void* const* d_in, const int* in_sizes, int n_in,
                              void* d_out, int out_size, void* d_ws, size_t ws_size,
                              hipStream_t stream) {
  const float* x   = (const float*)d_in[0];
  const int*   pos = (const int*)d_in[1];
  const float* wq  = (const float*)d_in[2];
  const float* bq  = (const float*)d_in[3];
  const float* wk  = (const float*)d_in[4];
  const float* bk  = (const float*)d_in[5];
  const float* wv  = (const float*)d_in[6];
  const float* bv  = (const float*)d_in[7];
  const float* wo  = (const float*)d_in[8];
  const float* bo  = (const float*)d_in[9];
  const float* phb = (const float*)d_in[10];
  const float* w1  = (const float*)d_in[11];
  const float* b1  = (const float*)d_in[12];
  const float* w2  = (const float*)d_in[13];
  const float* b2  = (const float*)d_in[14];
  const float* g1  = (const float*)d_in[15];
  const float* be1 = (const float*)d_in[16];
  const float* g2  = (const float*)d_in[17];
  const float* be2 = (const float*)d_in[18];

  char* ws = (char*)d_ws;
  const size_t MB = 1024 * 1024;
  if (ws_size < 112 * MB) return;
  short* qb     = (short*)(ws + 0 * MB);    // 8MB
  short* kb     = (short*)(ws + 8 * MB);    // 8MB
  short* vb     = (short*)(ws + 16 * MB);   // 8MB
  short* qp     = (short*)(ws + 24 * MB);   // 16MB
  short* kp     = (short*)(ws + 40 * MB);   // 16MB
  short* vt     = (short*)(ws + 56 * MB);   // 8MB
  short* xb     = (short*)(ws + 64 * MB);   // 8MB
  short* attnb  = (short*)(ws + 72 * MB);   // 8MB
  float* attnC0 = (float*)(ws + 0 * MB);    // 16MB (over qb+kb, dead after pope)
  float* attnC1 = (float*)(ws + 24 * MB);   // 16MB (over qp, dead after attn)
  short* hb     = (short*)(ws + 16 * MB);   // 8MB (over vb, dead after prep_v)
  short* ffh    = (short*)(ws + 40 * MB);   // 32MB (over kp+vt+xb, dead)
  float* ffC0   = (float*)(ws + 72 * MB);   // 16MB (over attnb, dead after wo)
  float* ffC1   = (float*)(ws + 0 * MB);    // 16MB (over attnC0, dead after ln1)
  short* wqT    = (short*)(ws + 88 * MB);
  short* wkT    = (short*)(ws + 90 * MB);
  short* wvT    = (short*)(ws + 92 * MB);
  short* woT    = (short*)(ws + 94 * MB);
  short* w1T    = (short*)(ws + 96 * MB);   // 8MB [DFF][D]
  short* w2T    = (short*)(ws + 104 * MB);  // 8MB [D][DFF]

  dim3 blk(256);
  k_wt<<<dim3(16, 16), blk, 0, stream>>>(wq, wqT, ND, ND);
  k_wt<<<dim3(16, 16), blk, 0, stream>>>(wk, wkT, ND, ND);
  k_wt<<<dim3(16, 16), blk, 0, stream>>>(wv, wvT, ND, ND);
  k_wt<<<dim3(16, 16), blk, 0, stream>>>(wo, woT, ND, ND);
  k_wt<<<dim3(64, 16), blk, 0, stream>>>(w1, w1T, ND, NDFF);
  k_wt<<<dim3(16, 64), blk, 0, stream>>>(w2, w2T, NDFF, ND);
  k_xb<<<dim3((NB * NS * ND / 8 + 255) / 256), blk, 0, stream>>>(x, xb, NB * NS * ND / 8);
  // QKV: one merged launch, 768 blocks co-resident
  k_gemm3<<<dim3(ND / 128, (NB * NS) / 128, 3), blk, 0, stream>>>(
      xb, wqT, wkT, wvT, bq, bk, bv, qb, kb, vb);
  k_pope<<<dim3(NB * NS * ND / 8 / 256), blk, 0, stream>>>(qb, kb, pos, phb, qp, kp);
  k_prep_v<<<dim3(NS / 64, NB * NH), blk, 0, stream>>>(vb, vt);
  k_attn2<<<dim3(8, NB * NH), dim3(512), 0, stream>>>(qp, kp, vt, attnb);
  // wo: split-K (z=2), partials summed in ln1
  k_gemm_sk<<<dim3(ND / 128, (NB * NS) / 128, 2), blk, 0, stream>>>(
      attnb, woT, attnC0, attnC1, NB * NS, ND, ND);
  k_ln3<0, 1><<<dim3(NB * NS), blk, 0, stream>>>(attnC0, attnC1, bo, x, g1, be1, hb);
  // ffn1: full-K (grid 1024 blocks already)
  k_gemm<1, 1><<<dim3(NDFF / 128, (NB * NS) / 128), blk, 0, stream>>>(
      hb, w1T, b1, ffh, NB * NS, NDFF, ND);
  // ffn2: split-K (z=2), partials + b2 summed in ln2
  k_gemm_sk<<<dim3(ND / 128, (NB * NS) / 128, 2), blk, 0, stream>>>(
      ffh, w2T, ffC0, ffC1, NB * NS, ND, NDFF);
  k_ln3<1, 0><<<dim3(NB * NS), blk, 0, stream>>>(ffC0, ffC1, b2, hb, g2, be2, (float*)d_out);
}

// Round 9
// 278.649 us; speedup vs baseline: 10.2360x; 1.0610x over previous
//
#include <hip/hip_runtime.h>
#include <hip/hip_bf16.h>
#include <math.h>

#define NB 2
#define NS 2048
#define ND 1024
#define NH 16
#define NHD 64
#define NDFF 4096

typedef __attribute__((ext_vector_type(4))) float f32x4;
typedef __attribute__((ext_vector_type(8))) short bf16x8;

__device__ __forceinline__ short f2bf(float f) {
  union { float f; unsigned u; } v; v.f = f;
  unsigned r = v.u + 0x7fffu + ((v.u >> 16) & 1u);
  return (short)(r >> 16);
}
__device__ __forceinline__ float bf2f(unsigned short u) {
  union { unsigned u; float f; } v; v.u = ((unsigned)u) << 16; return v.f;
}
__device__ __forceinline__ float softplus_f(float x) {
  return fmaxf(x, 0.f) + log1pf(__expf(-fabsf(x)));
}
// async global->LDS, 16B per lane; LDS dest wave-uniform (HW adds lane*16)
__device__ __forceinline__ void gl16(const short* g, short* l) {
  __builtin_amdgcn_global_load_lds(
      (const __attribute__((address_space(1))) void*)g,
      (__attribute__((address_space(3))) void*)l, 16, 0, 0);
}
// XCD-chunked bijective block remap (T1): each XCD owns a contiguous row-slab.
__device__ __forceinline__ void xcd_map(int& row0, int& col0) {
  const int gx = gridDim.x, gy = gridDim.y;
  const int bid = blockIdx.y * gx + blockIdx.x;
  const int rows_px = gy >> 3;
  const int xcd = bid & 7, l = bid >> 3;
  row0 = (xcd * rows_px + (l % rows_px)) * 128;
  col0 = (l / rows_px) * 128;
}

// ============ prep kernels ============
// All six weight transposes in ONE dispatch. Block ranges:
// [0,1024): wq/wk/wv/wo (256 each, K=N=1024); [1024,2048): w1 (K=1024,N=4096);
// [2048,3072): w2 (K=4096,N=1024).
__global__ __launch_bounds__(256) void k_wt6(
    const float* __restrict__ wq, const float* __restrict__ wk,
    const float* __restrict__ wv, const float* __restrict__ wo,
    const float* __restrict__ w1, const float* __restrict__ w2,
    short* __restrict__ wqT, short* __restrict__ wkT, short* __restrict__ wvT,
    short* __restrict__ woT, short* __restrict__ w1T, short* __restrict__ w2T) {
  __shared__ float t[64][65];
  const int bid = blockIdx.x;
  const float* W; short* Wt; int K, N, local;
  if (bid < 1024) {
    const int wsel = bid >> 8; local = bid & 255;
    W  = wsel == 0 ? wq  : wsel == 1 ? wk  : wsel == 2 ? wv  : wo;
    Wt = wsel == 0 ? wqT : wsel == 1 ? wkT : wsel == 2 ? wvT : woT;
    K = ND; N = ND;
  } else if (bid < 2048) {
    local = bid - 1024; W = w1; Wt = w1T; K = ND; N = NDFF;
  } else {
    local = bid - 2048; W = w2; Wt = w2T; K = NDFF; N = ND;
  }
  const int nx = N >> 6;
  const int n0 = (local % nx) * 64, k0 = (local / nx) * 64;
  for (int i = threadIdx.x; i < 4096; i += 256) {
    const int r = i >> 6, c = i & 63;
    t[r][c] = W[(size_t)(k0 + r) * N + n0 + c];
  }
  __syncthreads();
  for (int i = threadIdx.x; i < 4096; i += 256) {
    const int r = i >> 6, c = i & 63;
    Wt[(size_t)(n0 + r) * K + k0 + c] = f2bf(t[c][r]);
  }
}

__global__ __launch_bounds__(256) void k_xb(const float* __restrict__ x,
    short* __restrict__ xb, int n8) {
  const int i = blockIdx.x * 256 + threadIdx.x;
  if (i >= n8) return;
  const float4 a = ((const float4*)x)[i * 2];
  const float4 b = ((const float4*)x)[i * 2 + 1];
  short tmp[8] = { f2bf(a.x), f2bf(a.y), f2bf(a.z), f2bf(a.w),
                   f2bf(b.x), f2bf(b.y), f2bf(b.z), f2bf(b.w) };
  *(int4*)&xb[(size_t)i * 8] = *(const int4*)tmp;
}

__global__ __launch_bounds__(256) void k_prep_v(const short* __restrict__ vb,
    short* __restrict__ vt) {
  __shared__ short t[64][72];
  const int bh = blockIdx.y, b = bh >> 4, h = bh & 15;
  const int s0 = blockIdx.x * 64;
  for (int i = threadIdx.x; i < 512; i += 256) {
    const int sl = i >> 3, d8 = (i & 7) * 8;
    int4 vv = *(const int4*)&vb[((size_t)(b * NS + s0 + sl) * NH + h) * NHD + d8];
    const short* sp = (const short*)&vv;
#pragma unroll
    for (int j = 0; j < 8; j++) t[d8 + j][sl] = sp[j];
  }
  __syncthreads();
  for (int i = threadIdx.x; i < 512; i += 256) {
    const int d = i >> 3, c8 = (i & 7) * 8;
    *(int4*)&vt[((size_t)bh * 64 + d) * NS + s0 + c8] = *(const int4*)&t[d][c8];
  }
}

__global__ __launch_bounds__(256) void k_pope(const short* __restrict__ qb,
    const short* __restrict__ kb, const int* __restrict__ positions,
    const float* __restrict__ phb, short* __restrict__ qp,
    short* __restrict__ kp) {
  const size_t i8 = ((size_t)blockIdx.x * 256 + threadIdx.x) * 8;
  const int d0 = (int)(i8 & 63);
  const int h  = (int)((i8 >> 6) & 15);
  const int s  = (int)((i8 >> 10) & 2047);
  const int b  = (int)(i8 >> 21);
  const float posf = (float)positions[s];
  int4 qv = *(const int4*)&qb[i8];
  int4 kv = *(const int4*)&kb[i8];
  const short* qs = (const short*)&qv;
  const short* ks = (const short*)&kv;
  short qc[8], qsn[8], kc[8], ksn[8];
#pragma unroll
  for (int j = 0; j < 8; j++) {
    const int d = d0 + j;
    const float freq = __expf(-(float)d * (float)(9.210340371976184 / 64.0));
    const float muq = softplus_f(bf2f((unsigned short)qs[j]));
    const float muk = softplus_f(bf2f((unsigned short)ks[j]));
    float cb = phb[h * 64 + d];
    cb = fminf(fmaxf(cb, -6.283185307179586f), 0.f);
    float snq, csq, snk, csk;
    __sincosf(posf * freq, &snq, &csq);
    __sincosf(posf * freq + cb, &snk, &csk);
    qc[j] = f2bf(muq * csq); qsn[j] = f2bf(muq * snq);
    kc[j] = f2bf(muk * csk); ksn[j] = f2bf(muk * snk);
  }
  const size_t o = (((size_t)(b * 16 + h) * NS + s) * 128) + d0;
  *(int4*)&qp[o] = *(const int4*)qc;
  *(int4*)&qp[o + 64] = *(const int4*)qsn;
  *(int4*)&kp[o] = *(const int4*)kc;
  *(int4*)&kp[o + 64] = *(const int4*)ksn;
}

// ==== GEMM core: 2-phase double-buffered, global_load_lds, prefetch-first ====
#define BKK 32

__device__ __forceinline__ void gemm_core(const short* __restrict__ A,
    const short* __restrict__ Wt, const int K, const int kbeg, const int kend,
    const int row0, const int col0, short* lsA, short* lsB, f32x4 acc[4][4]) {
  const int tid = threadIdx.x;
  const int lane = tid & 63, wave = tid >> 6;
  const int lr = lane & 15, lk8 = (lane >> 4) << 3;
  const int wr = wave >> 1, wc = wave & 1;
  const int srow = lane >> 2, scol = (lane & 3) << 3;
  const int wbase = wave * 32;
#pragma unroll
  for (int m = 0; m < 4; m++)
#pragma unroll
    for (int n = 0; n < 4; n++) acc[m][n] = 0.f;
  const short* gA0 = &A[(size_t)(row0 + wbase + srow) * K + scol];
  const short* gA1 = gA0 + (size_t)16 * K;
  const short* gB0 = &Wt[(size_t)(col0 + wbase + srow) * K + scol];
  const short* gB1 = gB0 + (size_t)16 * K;
  short* const lA0 = lsA + wbase * 32;
  short* const lB0 = lsB + wbase * 32;
  auto stage = [&](int buf, int kk) {
    const int o = buf * 4096;
    gl16(gA0 + kk, lA0 + o);
    gl16(gA1 + kk, lA0 + o + 512);
    gl16(gB0 + kk, lB0 + o);
    gl16(gB1 + kk, lB0 + o + 512);
  };
  stage(0, kbeg);
  __syncthreads();
  int cur = 0;
  for (int k0 = kbeg; k0 < kend; k0 += BKK) {
    if (k0 + BKK < kend) stage(cur ^ 1, k0 + BKK);  // issue-early: overlaps compute
    const short* la = lsA + cur * 4096;
    const short* lb = lsB + cur * 4096;
    bf16x8 af[4], bf_[4];
#pragma unroll
    for (int m = 0; m < 4; m++)
      af[m] = *(const bf16x8*)&la[(wr * 64 + m * 16 + lr) * 32 + lk8];
#pragma unroll
    for (int n = 0; n < 4; n++)
      bf_[n] = *(const bf16x8*)&lb[(wc * 64 + n * 16 + lr) * 32 + lk8];
#pragma unroll
    for (int m = 0; m < 4; m++)
#pragma unroll
      for (int n = 0; n < 4; n++)
        acc[m][n] = __builtin_amdgcn_mfma_f32_16x16x32_bf16(af[m], bf_[n], acc[m][n], 0, 0, 0);
    __syncthreads();  // drains this iter's prefetch (vmcnt) + read-done (lgkm)
    cur ^= 1;
  }
}

template<int RELU, int OUTBF16>
__global__ __launch_bounds__(256) void k_gemm(const short* __restrict__ A,
    const short* __restrict__ Wt, const float* __restrict__ bias,
    void* __restrict__ C, int M, int N, int K) {
  __shared__ short lsA[2 * 4096], lsB[2 * 4096];
  f32x4 acc[4][4];
  int row0, col0;
  xcd_map(row0, col0);
  gemm_core(A, Wt, K, 0, K, row0, col0, lsA, lsB, acc);
  const int lane = threadIdx.x & 63, wave = threadIdx.x >> 6;
  const int lr = lane & 15, r4 = (lane >> 4) << 2;
  const int wr = wave >> 1, wc = wave & 1;
#pragma unroll
  for (int m = 0; m < 4; m++) {
#pragma unroll
    for (int n = 0; n < 4; n++) {
      const int col = col0 + wc * 64 + n * 16 + lr;
      const float bv = bias[col];
#pragma unroll
      for (int r = 0; r < 4; r++) {
        const int row = row0 + wr * 64 + m * 16 + r4 + r;
        float val = acc[m][n][r] + bv;
        if (RELU) val = fmaxf(val, 0.f);
        if (OUTBF16) ((short*)C)[(size_t)row * N + col] = f2bf(val);
        else ((float*)C)[(size_t)row * N + col] = val;
      }
    }
  }
}

// QKV merged: grid.z picks weight/bias/output. bf16 out.
__global__ __launch_bounds__(256) void k_gemm3(const short* __restrict__ xb,
    const short* __restrict__ wqT, const short* __restrict__ wkT,
    const short* __restrict__ wvT, const float* __restrict__ bq,
    const float* __restrict__ bk, const float* __restrict__ bv,
    short* __restrict__ qb, short* __restrict__ kb, short* __restrict__ vb) {
  __shared__ short lsA[2 * 4096], lsB[2 * 4096];
  const int z = blockIdx.z;
  const short* Wt = (z == 0) ? wqT : (z == 1) ? wkT : wvT;
  const float* bias = (z == 0) ? bq : (z == 1) ? bk : bv;
  short* C = (z == 0) ? qb : (z == 1) ? kb : vb;
  f32x4 acc[4][4];
  int row0, col0;
  xcd_map(row0, col0);
  gemm_core(xb, Wt, ND, 0, ND, row0, col0, lsA, lsB, acc);
  const int lane = threadIdx.x & 63, wave = threadIdx.x >> 6;
  const int lr = lane & 15, r4 = (lane >> 4) << 2;
  const int wr = wave >> 1, wc = wave & 1;
#pragma unroll
  for (int m = 0; m < 4; m++) {
#pragma unroll
    for (int n = 0; n < 4; n++) {
      const int col = col0 + wc * 64 + n * 16 + lr;
      const float bvs = bias[col];
#pragma unroll
      for (int r = 0; r < 4; r++) {
        const int row = row0 + wr * 64 + m * 16 + r4 + r;
        C[(size_t)row * ND + col] = f2bf(acc[m][n][r] + bvs);
      }
    }
  }
}

// Split-K GEMM: grid.z=2 halves of K; writes unbiased f32 partials to C0/C1.
__global__ __launch_bounds__(256) void k_gemm_sk(const short* __restrict__ A,
    const short* __restrict__ Wt, float* __restrict__ C0, float* __restrict__ C1,
    int M, int N, int K) {
  __shared__ short lsA[2 * 4096], lsB[2 * 4096];
  f32x4 acc[4][4];
  const int z = blockIdx.z;
  const int khalf = K >> 1, kbeg = z * khalf, kend = kbeg + khalf;
  int row0, col0;
  xcd_map(row0, col0);
  gemm_core(A, Wt, K, kbeg, kend, row0, col0, lsA, lsB, acc);
  float* C = z ? C1 : C0;
  const int lane = threadIdx.x & 63, wave = threadIdx.x >> 6;
  const int lr = lane & 15, r4 = (lane >> 4) << 2;
  const int wr = wave >> 1, wc = wave & 1;
#pragma unroll
  for (int m = 0; m < 4; m++) {
#pragma unroll
    for (int n = 0; n < 4; n++) {
      const int col = col0 + wc * 64 + n * 16 + lr;
#pragma unroll
      for (int r = 0; r < 4; r++) {
        const int row = row0 + wr * 64 + m * 16 + r4 + r;
        C[(size_t)row * N + col] = acc[m][n][r];
      }
    }
  }
}

// ============ Attention (causal, softmax1), MFMA flash ============
// m=0 fixed (softmax1 is shift-invariant; scores provably < ~6, no overflow).
__device__ __forceinline__ void attn_proc(const bf16x8 aq[4], f32x4 acc_o[4],
    float l_p[4], const int rowb, const int kb,
    const short (*kpl)[136], const short (*vl)[72], short (*pl)[72],
    const int lr, const int lk) {
  f32x4 s_acc[4];
#pragma unroll
  for (int n = 0; n < 4; n++) s_acc[n] = 0.f;
#pragma unroll
  for (int ks = 0; ks < 4; ks++) {
    bf16x8 bk_[4];
#pragma unroll
    for (int n = 0; n < 4; n++)
      bk_[n] = *(const bf16x8*)&kpl[n * 16 + lr][ks * 32 + lk * 8];
#pragma unroll
    for (int n = 0; n < 4; n++)
      s_acc[n] = __builtin_amdgcn_mfma_f32_16x16x32_bf16(aq[ks], bk_[n], s_acc[n], 0, 0, 0);
  }
  const float scale = 0.08838834764831845f;
  const bool domask = (kb + 63 > rowb);  // wave-uniform: diagonal-crossing chunk
#pragma unroll
  for (int n = 0; n < 4; n++) {
#pragma unroll
    for (int r = 0; r < 4; r++) {
      const float sv = s_acc[n][r] * scale;
      float p;
      if (domask) {
        const int rel = rowb + lk * 4 + r - kb;
        p = (n * 16 + lr <= rel) ? __expf(sv) : 0.f;
      } else {
        p = __expf(sv);
      }
      s_acc[n][r] = p;
      l_p[r] += p;  // per-lane partial; cross-lane reduce deferred to epilogue
    }
  }
  // P -> wave-private LDS strip (same-wave RAW, no barrier)
#pragma unroll
  for (int n = 0; n < 4; n++)
#pragma unroll
    for (int r = 0; r < 4; r++)
      pl[lk * 4 + r][n * 16 + lr] = f2bf(s_acc[n][r]);
#pragma unroll
  for (int ks = 0; ks < 2; ks++) {
    const bf16x8 ap = *(const bf16x8*)&pl[lr][ks * 32 + lk * 8];
    bf16x8 bv_[4];
#pragma unroll
    for (int nd = 0; nd < 4; nd++)
      bv_[nd] = *(const bf16x8*)&vl[nd * 16 + lr][ks * 32 + lk * 8];
#pragma unroll
    for (int nd = 0; nd < 4; nd++)
      acc_o[nd] = __builtin_amdgcn_mfma_f32_16x16x32_bf16(ap, bv_[nd], acc_o[nd], 0, 0, 0);
  }
}

// grid (16, 32), 512 threads, 2 blocks/CU. Block bx: waves 0-3 own 64-row tile
// tH=31-bx, waves 4-7 own tile tB=bx. One shared K/V sweep over chunks 0..tH;
// a wave procs only while its tile is live. Per-block proc work = 33 units (balanced).
__global__ __launch_bounds__(512) void k_attn3(
    const short* __restrict__ qp, const short* __restrict__ kp,
    const short* __restrict__ vt, short* __restrict__ attn) {
  __shared__ short kp_l[2][64][136];
  __shared__ short v_l[2][64][72];
  __shared__ short p_l[8][16][72];
  const int bh = blockIdx.y, b = bh >> 4, h = bh & 15;
  const int bx = blockIdx.x;
  const int tid = threadIdx.x, wave = tid >> 6, lane = tid & 63;
  const int lr = lane & 15, lk = lane >> 4;
  const int tHeavy = 31 - bx;
  const int myTile = (wave < 4) ? tHeavy : bx;
  const int rowb = myTile * 64 + (wave & 3) * 16;
  const int nch = tHeavy + 1;

  bf16x8 aq[4];
  {
    const short* qrow = qp + ((size_t)bh * NS + rowb + lr) * 128;
#pragma unroll
    for (int ks = 0; ks < 4; ks++)
      aq[ks] = *(const bf16x8*)&qrow[ks * 32 + lk * 8];
  }
  f32x4 acc[4];
  float lsum[4];
#pragma unroll
  for (int r = 0; r < 4; r++) lsum[r] = 0.f;
#pragma unroll
  for (int n = 0; n < 4; n++) acc[n] = 0.f;

  const short* kpb = kp + (size_t)bh * NS * 128;
  const short* vtb = vt + (size_t)bh * 64 * NS;
  const int krow = tid >> 3, kcol = (tid & 7) * 16;
  const int vrow = tid >> 3, vcol = (tid & 7) * 8;

  int4 rk0, rk1, rv;
  {
    const short* s = &kpb[(size_t)krow * 128 + kcol];
    rk0 = ((const int4*)s)[0]; rk1 = ((const int4*)s)[1];
    rv = *(const int4*)&vtb[(size_t)vrow * NS + vcol];
  }
  ((int4*)&kp_l[0][krow][kcol])[0] = rk0;
  ((int4*)&kp_l[0][krow][kcol])[1] = rk1;
  *(int4*)&v_l[0][vrow][vcol] = rv;
  __syncthreads();

  for (int c = 0; c < nch; c++) {
    const int kb = c * 64;
    const int cur = c & 1;
    const bool more = (c + 1) < nch;
    if (more) {
      const int kb2 = kb + 64;
      const short* s = &kpb[(size_t)(kb2 + krow) * 128 + kcol];
      rk0 = ((const int4*)s)[0]; rk1 = ((const int4*)s)[1];
      rv = *(const int4*)&vtb[(size_t)vrow * NS + kb2 + vcol];
    }
    if (rowb + 15 >= kb)
      attn_proc(aq, acc, lsum, rowb, kb, kp_l[cur], v_l[cur], p_l[wave], lr, lk);
    if (more) {
      // writes target buffer cur^1 (nobody reads it this iteration); the single
      // barrier below both publishes these writes and closes the read phase.
      ((int4*)&kp_l[cur ^ 1][krow][kcol])[0] = rk0;
      ((int4*)&kp_l[cur ^ 1][krow][kcol])[1] = rk1;
      *(int4*)&v_l[cur ^ 1][vrow][vcol] = rv;
    }
    __syncthreads();
  }
  // epilogue: single cross-lane reduce of the deferred row sums (lane bits 0-3)
#pragma unroll
  for (int r = 0; r < 4; r++) {
    float s = lsum[r];
#pragma unroll
    for (int off = 8; off; off >>= 1) s += __shfl_xor(s, off);
    lsum[r] = 1.f / (1.f + s);   // softmax1 with m=0: denom = 1 + sum
  }
#pragma unroll
  for (int nd = 0; nd < 4; nd++) {
#pragma unroll
    for (int r = 0; r < 4; r++) {
      const int d = nd * 16 + lr;
      const int row = rowb + lk * 4 + r;
      attn[(((size_t)b * NS + row) * NH + h) * NHD + d] = f2bf(acc[nd][r] * lsum[r]);
    }
  }
}

// ==== LayerNorm with fused partial-sum + bias: x = A0 + A1 + badd + R ====
template<int RBF16, int OUTBF16>
__global__ __launch_bounds__(256) void k_ln3(const float* __restrict__ A0,
    const float* __restrict__ A1, const float* __restrict__ badd,
    const void* __restrict__ Rv, const float* __restrict__ g,
    const float* __restrict__ be, void* __restrict__ out) {
  const int row = blockIdx.x, tid = threadIdx.x;
  const float4 a0 = ((const float4*)(A0 + (size_t)row * ND))[tid];
  const float4 a1 = ((const float4*)(A1 + (size_t)row * ND))[tid];
  const float4 bd = ((const float4*)badd)[tid];
  float r0, r1, r2, r3;
  if (RBF16) {
    short4 rr = *(const short4*)((const short*)Rv + (size_t)row * ND + tid * 4);
    r0 = bf2f((unsigned short)rr.x); r1 = bf2f((unsigned short)rr.y);
    r2 = bf2f((unsigned short)rr.z); r3 = bf2f((unsigned short)rr.w);
  } else {
    const float4 rr = ((const float4*)((const float*)Rv + (size_t)row * ND))[tid];
    r0 = rr.x; r1 = rr.y; r2 = rr.z; r3 = rr.w;
  }
  const float x0 = a0.x + a1.x + bd.x + r0;
  const float x1 = a0.y + a1.y + bd.y + r1;
  const float x2 = a0.z + a1.z + bd.z + r2;
  const float x3 = a0.w + a1.w + bd.w + r3;
  float s = x0 + x1 + x2 + x3;
  float sq = x0 * x0 + x1 * x1 + x2 * x2 + x3 * x3;
#pragma unroll
  for (int off = 32; off; off >>= 1) {
    s += __shfl_xor(s, off);
    sq += __shfl_xor(sq, off);
  }
  __shared__ float ss[4], ssq[4];
  const int wave = tid >> 6, lane = tid & 63;
  if (lane == 0) { ss[wave] = s; ssq[wave] = sq; }
  __syncthreads();
  s = ss[0] + ss[1] + ss[2] + ss[3];
  sq = ssq[0] + ssq[1] + ssq[2] + ssq[3];
  const float mu = s * (1.f / (float)ND);
  const float var = sq * (1.f / (float)ND) - mu * mu;
  const float rstd = rsqrtf(var + 1e-5f);
  const float4 gg = ((const float4*)g)[tid];
  const float4 bb = ((const float4*)be)[tid];
  const float o0 = (x0 - mu) * rstd * gg.x + bb.x;
  const float o1 = (x1 - mu) * rstd * gg.y + bb.y;
  const float o2 = (x2 - mu) * rstd * gg.z + bb.z;
  const float o3 = (x3 - mu) * rstd * gg.w + bb.w;
  if (OUTBF16) {
    short4 ov = { f2bf(o0), f2bf(o1), f2bf(o2), f2bf(o3) };
    *(short4*)((short*)out + (size_t)row * ND + tid * 4) = ov;
  } else {
    float4 ov = { o0, o1, o2, o3 };
    ((float4*)((float*)out + (size_t)row * ND))[tid] = ov;
  }
}

extern "C" void kernel_launch(void* const* d_in, const int* in_sizes, int n_in,
                              void* d_out, int out_size, void* d_ws, size_t ws_size,
                              hipStream_t stream) {
  const float* x   = (const float*)d_in[0];
  const int*   pos = (const int*)d_in[1];
  const float* wq  = (const float*)d_in[2];
  const float* bq  = (const float*)d_in[3];
  const float* wk  = (const float*)d_in[4];
  const float* bk  = (const float*)d_in[5];
  const float* wv  = (const float*)d_in[6];
  const float* bv  = (const float*)d_in[7];
  const float* wo  = (const float*)d_in[8];
  const float* bo  = (const float*)d_in[9];
  const float* phb = (const float*)d_in[10];
  const float* w1  = (const float*)d_in[11];
  const float* b1  = (const float*)d_in[12];
  const float* w2  = (const float*)d_in[13];
  const float* b2  = (const float*)d_in[14];
  const float* g1  = (const float*)d_in[15];
  const float* be1 = (const float*)d_in[16];
  const float* g2  = (const float*)d_in[17];
  const float* be2 = (const float*)d_in[18];

  char* ws = (char*)d_ws;
  const size_t MB = 1024 * 1024;
  if (ws_size < 112 * MB) return;
  short* qb     = (short*)(ws + 0 * MB);    // 8MB
  short* kb     = (short*)(ws + 8 * MB);    // 8MB
  short* vb     = (short*)(ws + 16 * MB);   // 8MB
  short* qp     = (short*)(ws + 24 * MB);   // 16MB
  short* kp     = (short*)(ws + 40 * MB);   // 16MB
  short* vt     = (short*)(ws + 56 * MB);   // 8MB
  short* xb     = (short*)(ws + 64 * MB);   // 8MB
  short* attnb  = (short*)(ws + 72 * MB);   // 8MB
  float* attnC0 = (float*)(ws + 0 * MB);    // 16MB (over qb+kb, dead after pope)
  float* attnC1 = (float*)(ws + 24 * MB);   // 16MB (over qp, dead after attn)
  short* hb     = (short*)(ws + 16 * MB);   // 8MB (over vb, dead after prep_v)
  short* ffh    = (short*)(ws + 40 * MB);   // 32MB (over kp+vt+xb, dead)
  float* ffC0   = (float*)(ws + 72 * MB);   // 16MB (over attnb, dead after wo)
  float* ffC1   = (float*)(ws + 0 * MB);    // 16MB (over attnC0, dead after ln1)
  short* wqT    = (short*)(ws + 88 * MB);
  short* wkT    = (short*)(ws + 90 * MB);
  short* wvT    = (short*)(ws + 92 * MB);
  short* woT    = (short*)(ws + 94 * MB);
  short* w1T    = (short*)(ws + 96 * MB);   // 8MB [DFF][D]
  short* w2T    = (short*)(ws + 104 * MB);  // 8MB [D][DFF]

  dim3 blk(256);
  k_wt6<<<dim3(3072), blk, 0, stream>>>(wq, wk, wv, wo, w1, w2,
                                        wqT, wkT, wvT, woT, w1T, w2T);
  k_xb<<<dim3((NB * NS * ND / 8 + 255) / 256), blk, 0, stream>>>(x, xb, NB * NS * ND / 8);
  // QKV: one merged launch, 768 blocks co-resident
  k_gemm3<<<dim3(ND / 128, (NB * NS) / 128, 3), blk, 0, stream>>>(
      xb, wqT, wkT, wvT, bq, bk, bv, qb, kb, vb);
  k_pope<<<dim3(NB * NS * ND / 8 / 256), blk, 0, stream>>>(qb, kb, pos, phb, qp, kp);
  k_prep_v<<<dim3(NS / 64, NB * NH), blk, 0, stream>>>(vb, vt);
  // attention: 512 blocks, 2/CU
  k_attn3<<<dim3(16, NB * NH), dim3(512), 0, stream>>>(qp, kp, vt, attnb);
  // wo: split-K (z=2), partials summed in ln1
  k_gemm_sk<<<dim3(ND / 128, (NB * NS) / 128, 2), blk, 0, stream>>>(
      attnb, woT, attnC0, attnC1, NB * NS, ND, ND);
  k_ln3<0, 1><<<dim3(NB * NS), blk, 0, stream>>>(attnC0, attnC1, bo, x, g1, be1, hb);
  // ffn1: full-K (grid 1024 blocks already)
  k_gemm<1, 1><<<dim3(NDFF / 128, (NB * NS) / 128), blk, 0, stream>>>(
      hb, w1T, b1, ffh, NB * NS, NDFF, ND);
  // ffn2: split-K (z=2), partials + b2 summed in ln2
  k_gemm_sk<<<dim3(ND / 128, (NB * NS) / 128, 2), blk, 0, stream>>>(
      ffh, w2T, ffC0, ffC1, NB * NS, ND, NDFF);
  k_ln3<1, 0><<<dim3(NB * NS), blk, 0, stream>>>(ffC0, ffC1, b2, hb, g2, be2, (float*)d_out);
}

// Round 10
// 275.585 us; speedup vs baseline: 10.3498x; 1.0111x over previous
//
#include <hip/hip_runtime.h>
#include <hip/hip_bf16.h>
#include <math.h>

#define NB 2
#define NS 2048
#define ND 1024
#define NH 16
#define NHD 64
#define NDFF 4096

typedef __attribute__((ext_vector_type(4))) float f32x4;
typedef __attribute__((ext_vector_type(8))) short bf16x8;

__device__ __forceinline__ short f2bf(float f) {
  union { float f; unsigned u; } v; v.f = f;
  unsigned r = v.u + 0x7fffu + ((v.u >> 16) & 1u);
  return (short)(r >> 16);
}
__device__ __forceinline__ float bf2f(unsigned short u) {
  union { unsigned u; float f; } v; v.u = ((unsigned)u) << 16; return v.f;
}
__device__ __forceinline__ float softplus_f(float x) {
  return fmaxf(x, 0.f) + log1pf(__expf(-fabsf(x)));
}
// async global->LDS, 16B per lane; LDS dest wave-uniform (HW adds lane*16)
__device__ __forceinline__ void gl16(const short* g, short* l) {
  __builtin_amdgcn_global_load_lds(
      (const __attribute__((address_space(1))) void*)g,
      (__attribute__((address_space(3))) void*)l, 16, 0, 0);
}
// XCD-chunked bijective block remap (T1): each XCD owns a contiguous row-slab.
__device__ __forceinline__ void xcd_map(int& row0, int& col0) {
  const int gx = gridDim.x, gy = gridDim.y;
  const int bid = blockIdx.y * gx + blockIdx.x;
  const int rows_px = gy >> 3;
  const int xcd = bid & 7, l = bid >> 3;
  row0 = (xcd * rows_px + (l % rows_px)) * 128;
  col0 = (l / rows_px) * 128;
}

// ============ prep: all 6 weight transposes + x->bf16 in ONE dispatch ============
// [0,1024): wq/wk/wv/wo; [1024,2048): w1; [2048,3072): w2; [3072,5120): xb.
__global__ __launch_bounds__(256) void k_prep(
    const float* __restrict__ wq, const float* __restrict__ wk,
    const float* __restrict__ wv, const float* __restrict__ wo,
    const float* __restrict__ w1, const float* __restrict__ w2,
    const float* __restrict__ x,
    short* __restrict__ wqT, short* __restrict__ wkT, short* __restrict__ wvT,
    short* __restrict__ woT, short* __restrict__ w1T, short* __restrict__ w2T,
    short* __restrict__ xb) {
  __shared__ float t[64][65];
  const int bid = blockIdx.x;
  if (bid >= 3072) {
    const int i = (bid - 3072) * 256 + threadIdx.x;
    const float4 a = ((const float4*)x)[i * 2];
    const float4 b = ((const float4*)x)[i * 2 + 1];
    short tmp[8] = { f2bf(a.x), f2bf(a.y), f2bf(a.z), f2bf(a.w),
                     f2bf(b.x), f2bf(b.y), f2bf(b.z), f2bf(b.w) };
    *(int4*)&xb[(size_t)i * 8] = *(const int4*)tmp;
    return;
  }
  const float* W; short* Wt; int K, N, local;
  if (bid < 1024) {
    const int wsel = bid >> 8; local = bid & 255;
    W  = wsel == 0 ? wq  : wsel == 1 ? wk  : wsel == 2 ? wv  : wo;
    Wt = wsel == 0 ? wqT : wsel == 1 ? wkT : wsel == 2 ? wvT : woT;
    K = ND; N = ND;
  } else if (bid < 2048) {
    local = bid - 1024; W = w1; Wt = w1T; K = ND; N = NDFF;
  } else {
    local = bid - 2048; W = w2; Wt = w2T; K = NDFF; N = ND;
  }
  const int nx = N >> 6;
  const int n0 = (local % nx) * 64, k0 = (local / nx) * 64;
  for (int i = threadIdx.x; i < 4096; i += 256) {
    const int r = i >> 6, c = i & 63;
    t[r][c] = W[(size_t)(k0 + r) * N + n0 + c];
  }
  __syncthreads();
  for (int i = threadIdx.x; i < 4096; i += 256) {
    const int r = i >> 6, c = i & 63;
    Wt[(size_t)(n0 + r) * K + k0 + c] = f2bf(t[c][r]);
  }
}

// ============ PoPE + V-transpose in ONE dispatch ============
// [0,2048): pope elementwise; [2048,3072): prep_v tiles.
__global__ __launch_bounds__(256) void k_pope_pv(const short* __restrict__ qb,
    const short* __restrict__ kb, const short* __restrict__ vb,
    const int* __restrict__ positions, const float* __restrict__ phb,
    short* __restrict__ qp, short* __restrict__ kp, short* __restrict__ vt) {
  __shared__ short t[64][72];
  const int bid = blockIdx.x;
  if (bid < 2048) {
    const size_t i8 = ((size_t)bid * 256 + threadIdx.x) * 8;
    const int d0 = (int)(i8 & 63);
    const int h  = (int)((i8 >> 6) & 15);
    const int s  = (int)((i8 >> 10) & 2047);
    const int b  = (int)(i8 >> 21);
    const float posf = (float)positions[s];
    int4 qv = *(const int4*)&qb[i8];
    int4 kv = *(const int4*)&kb[i8];
    const short* qs = (const short*)&qv;
    const short* ks = (const short*)&kv;
    short qc[8], qsn[8], kc[8], ksn[8];
#pragma unroll
    for (int j = 0; j < 8; j++) {
      const int d = d0 + j;
      const float freq = __expf(-(float)d * (float)(9.210340371976184 / 64.0));
      const float muq = softplus_f(bf2f((unsigned short)qs[j]));
      const float muk = softplus_f(bf2f((unsigned short)ks[j]));
      float cb = phb[h * 64 + d];
      cb = fminf(fmaxf(cb, -6.283185307179586f), 0.f);
      float snq, csq, snk, csk;
      __sincosf(posf * freq, &snq, &csq);
      __sincosf(posf * freq + cb, &snk, &csk);
      qc[j] = f2bf(muq * csq); qsn[j] = f2bf(muq * snq);
      kc[j] = f2bf(muk * csk); ksn[j] = f2bf(muk * snk);
    }
    const size_t o = (((size_t)(b * 16 + h) * NS + s) * 128) + d0;
    *(int4*)&qp[o] = *(const int4*)qc;
    *(int4*)&qp[o + 64] = *(const int4*)qsn;
    *(int4*)&kp[o] = *(const int4*)kc;
    *(int4*)&kp[o + 64] = *(const int4*)ksn;
  } else {
    const int local = bid - 2048;
    const int bh = local >> 5, b = bh >> 4, h = bh & 15;
    const int s0 = (local & 31) * 64;
    for (int i = threadIdx.x; i < 512; i += 256) {
      const int sl = i >> 3, d8 = (i & 7) * 8;
      int4 vv = *(const int4*)&vb[((size_t)(b * NS + s0 + sl) * NH + h) * NHD + d8];
      const short* sp = (const short*)&vv;
#pragma unroll
      for (int j = 0; j < 8; j++) t[d8 + j][sl] = sp[j];
    }
    __syncthreads();
    for (int i = threadIdx.x; i < 512; i += 256) {
      const int d = i >> 3, c8 = (i & 7) * 8;
      *(int4*)&vt[((size_t)bh * 64 + d) * NS + s0 + c8] = *(const int4*)&t[d][c8];
    }
  }
}

// ==== GEMM core: 2-phase double-buffered, global_load_lds, prefetch-first ====
#define BKK 32

__device__ __forceinline__ void gemm_core(const short* __restrict__ A,
    const short* __restrict__ Wt, const int K, const int kbeg, const int kend,
    const int row0, const int col0, short* lsA, short* lsB, f32x4 acc[4][4]) {
  const int tid = threadIdx.x;
  const int lane = tid & 63, wave = tid >> 6;
  const int lr = lane & 15, lk8 = (lane >> 4) << 3;
  const int wr = wave >> 1, wc = wave & 1;
  const int srow = lane >> 2, scol = (lane & 3) << 3;
  const int wbase = wave * 32;
#pragma unroll
  for (int m = 0; m < 4; m++)
#pragma unroll
    for (int n = 0; n < 4; n++) acc[m][n] = 0.f;
  const short* gA0 = &A[(size_t)(row0 + wbase + srow) * K + scol];
  const short* gA1 = gA0 + (size_t)16 * K;
  const short* gB0 = &Wt[(size_t)(col0 + wbase + srow) * K + scol];
  const short* gB1 = gB0 + (size_t)16 * K;
  short* const lA0 = lsA + wbase * 32;
  short* const lB0 = lsB + wbase * 32;
  auto stage = [&](int buf, int kk) {
    const int o = buf * 4096;
    gl16(gA0 + kk, lA0 + o);
    gl16(gA1 + kk, lA0 + o + 512);
    gl16(gB0 + kk, lB0 + o);
    gl16(gB1 + kk, lB0 + o + 512);
  };
  stage(0, kbeg);
  __syncthreads();
  int cur = 0;
  for (int k0 = kbeg; k0 < kend; k0 += BKK) {
    if (k0 + BKK < kend) stage(cur ^ 1, k0 + BKK);  // issue-early: overlaps compute
    const short* la = lsA + cur * 4096;
    const short* lb = lsB + cur * 4096;
    bf16x8 af[4], bf_[4];
#pragma unroll
    for (int m = 0; m < 4; m++)
      af[m] = *(const bf16x8*)&la[(wr * 64 + m * 16 + lr) * 32 + lk8];
#pragma unroll
    for (int n = 0; n < 4; n++)
      bf_[n] = *(const bf16x8*)&lb[(wc * 64 + n * 16 + lr) * 32 + lk8];
#pragma unroll
    for (int m = 0; m < 4; m++)
#pragma unroll
      for (int n = 0; n < 4; n++)
        acc[m][n] = __builtin_amdgcn_mfma_f32_16x16x32_bf16(af[m], bf_[n], acc[m][n], 0, 0, 0);
    __syncthreads();  // drains this iter's prefetch (vmcnt) + read-done (lgkm)
    cur ^= 1;
  }
}

template<int RELU, int OUTBF16>
__global__ __launch_bounds__(256) void k_gemm(const short* __restrict__ A,
    const short* __restrict__ Wt, const float* __restrict__ bias,
    void* __restrict__ C, int M, int N, int K) {
  __shared__ short lsA[2 * 4096], lsB[2 * 4096];
  f32x4 acc[4][4];
  int row0, col0;
  xcd_map(row0, col0);
  gemm_core(A, Wt, K, 0, K, row0, col0, lsA, lsB, acc);
  const int lane = threadIdx.x & 63, wave = threadIdx.x >> 6;
  const int lr = lane & 15, r4 = (lane >> 4) << 2;
  const int wr = wave >> 1, wc = wave & 1;
#pragma unroll
  for (int m = 0; m < 4; m++) {
#pragma unroll
    for (int n = 0; n < 4; n++) {
      const int col = col0 + wc * 64 + n * 16 + lr;
      const float bv = bias[col];
#pragma unroll
      for (int r = 0; r < 4; r++) {
        const int row = row0 + wr * 64 + m * 16 + r4 + r;
        float val = acc[m][n][r] + bv;
        if (RELU) val = fmaxf(val, 0.f);
        if (OUTBF16) ((short*)C)[(size_t)row * N + col] = f2bf(val);
        else ((float*)C)[(size_t)row * N + col] = val;
      }
    }
  }
}

// QKV merged: grid.z picks weight/bias/output. bf16 out.
__global__ __launch_bounds__(256) void k_gemm3(const short* __restrict__ xb,
    const short* __restrict__ wqT, const short* __restrict__ wkT,
    const short* __restrict__ wvT, const float* __restrict__ bq,
    const float* __restrict__ bk, const float* __restrict__ bv,
    short* __restrict__ qb, short* __restrict__ kb, short* __restrict__ vb) {
  __shared__ short lsA[2 * 4096], lsB[2 * 4096];
  const int z = blockIdx.z;
  const short* Wt = (z == 0) ? wqT : (z == 1) ? wkT : wvT;
  const float* bias = (z == 0) ? bq : (z == 1) ? bk : bv;
  short* C = (z == 0) ? qb : (z == 1) ? kb : vb;
  f32x4 acc[4][4];
  int row0, col0;
  xcd_map(row0, col0);
  gemm_core(xb, Wt, ND, 0, ND, row0, col0, lsA, lsB, acc);
  const int lane = threadIdx.x & 63, wave = threadIdx.x >> 6;
  const int lr = lane & 15, r4 = (lane >> 4) << 2;
  const int wr = wave >> 1, wc = wave & 1;
#pragma unroll
  for (int m = 0; m < 4; m++) {
#pragma unroll
    for (int n = 0; n < 4; n++) {
      const int col = col0 + wc * 64 + n * 16 + lr;
      const float bvs = bias[col];
#pragma unroll
      for (int r = 0; r < 4; r++) {
        const int row = row0 + wr * 64 + m * 16 + r4 + r;
        C[(size_t)row * ND + col] = f2bf(acc[m][n][r] + bvs);
      }
    }
  }
}

// Split-K GEMM: grid.z=2 halves of K; writes unbiased f32 partials to C0/C1.
__global__ __launch_bounds__(256) void k_gemm_sk(const short* __restrict__ A,
    const short* __restrict__ Wt, float* __restrict__ C0, float* __restrict__ C1,
    int M, int N, int K) {
  __shared__ short lsA[2 * 4096], lsB[2 * 4096];
  f32x4 acc[4][4];
  const int z = blockIdx.z;
  const int khalf = K >> 1, kbeg = z * khalf, kend = kbeg + khalf;
  int row0, col0;
  xcd_map(row0, col0);
  gemm_core(A, Wt, K, kbeg, kend, row0, col0, lsA, lsB, acc);
  float* C = z ? C1 : C0;
  const int lane = threadIdx.x & 63, wave = threadIdx.x >> 6;
  const int lr = lane & 15, r4 = (lane >> 4) << 2;
  const int wr = wave >> 1, wc = wave & 1;
#pragma unroll
  for (int m = 0; m < 4; m++) {
#pragma unroll
    for (int n = 0; n < 4; n++) {
      const int col = col0 + wc * 64 + n * 16 + lr;
#pragma unroll
      for (int r = 0; r < 4; r++) {
        const int row = row0 + wr * 64 + m * 16 + r4 + r;
        C[(size_t)row * N + col] = acc[m][n][r];
      }
    }
  }
}

// ============ Attention (causal, softmax1), MFMA flash ============
// m=0 fixed (softmax1 is shift-invariant; scores provably < ~6, no overflow).
// Row-sums computed by MFMA with an all-ones B fragment (accS) — no VALU adds,
// no epilogue shuffles (C-layout makes accS[r] lane-uniform across cols).
__device__ __forceinline__ void attn_proc(const bf16x8 aq[4], f32x4 acc_o[4],
    f32x4& accS, const int rowb, const int kb,
    const short (*kpl)[136], const short (*vl)[72], short (*pl)[72],
    const int lr, const int lk) {
  f32x4 s_acc[4];
#pragma unroll
  for (int n = 0; n < 4; n++) s_acc[n] = 0.f;
#pragma unroll
  for (int ks = 0; ks < 4; ks++) {
    bf16x8 bk_[4];
#pragma unroll
    for (int n = 0; n < 4; n++)
      bk_[n] = *(const bf16x8*)&kpl[n * 16 + lr][ks * 32 + lk * 8];
#pragma unroll
    for (int n = 0; n < 4; n++)
      s_acc[n] = __builtin_amdgcn_mfma_f32_16x16x32_bf16(aq[ks], bk_[n], s_acc[n], 0, 0, 0);
  }
  // p = exp2(s * (1/sqrt(128) * log2 e)) == exp(s/sqrt(128)); single v_exp each.
  const float scale2 = 0.1275174333f;
  const bool domask = (kb + 63 > rowb);  // wave-uniform: diagonal-crossing chunk
#pragma unroll
  for (int n = 0; n < 4; n++) {
#pragma unroll
    for (int r = 0; r < 4; r++) {
      float p = exp2f(s_acc[n][r] * scale2);
      if (domask) {
        const int rel = rowb + lk * 4 + r - kb;
        p = (n * 16 + lr <= rel) ? p : 0.f;
      }
      s_acc[n][r] = p;
    }
  }
  // P -> wave-private LDS strip (same-wave RAW, no barrier)
#pragma unroll
  for (int n = 0; n < 4; n++)
#pragma unroll
    for (int r = 0; r < 4; r++)
      pl[lk * 4 + r][n * 16 + lr] = f2bf(s_acc[n][r]);
  bf16x8 bones;
#pragma unroll
  for (int i = 0; i < 8; i++) bones[i] = (short)0x3F80;  // bf16 1.0
#pragma unroll
  for (int ks = 0; ks < 2; ks++) {
    const bf16x8 ap = *(const bf16x8*)&pl[lr][ks * 32 + lk * 8];
    accS = __builtin_amdgcn_mfma_f32_16x16x32_bf16(ap, bones, accS, 0, 0, 0);
    bf16x8 bv_[4];
#pragma unroll
    for (int nd = 0; nd < 4; nd++)
      bv_[nd] = *(const bf16x8*)&vl[nd * 16 + lr][ks * 32 + lk * 8];
#pragma unroll
    for (int nd = 0; nd < 4; nd++)
      acc_o[nd] = __builtin_amdgcn_mfma_f32_16x16x32_bf16(ap, bv_[nd], acc_o[nd], 0, 0, 0);
  }
}

// grid (16, 32), 512 threads, 2 blocks/CU. Block bx: waves 0-3 own 64-row tile
// tH=31-bx, waves 4-7 own tile tB=bx. One shared K/V sweep over chunks 0..tH.
__global__ __launch_bounds__(512) void k_attn3(
    const short* __restrict__ qp, const short* __restrict__ kp,
    const short* __restrict__ vt, short* __restrict__ attn) {
  __shared__ short kp_l[2][64][136];
  __shared__ short v_l[2][64][72];
  __shared__ short p_l[8][16][72];
  const int bh = blockIdx.y, b = bh >> 4, h = bh & 15;
  const int bx = blockIdx.x;
  const int tid = threadIdx.x, wave = tid >> 6, lane = tid & 63;
  const int lr = lane & 15, lk = lane >> 4;
  const int tHeavy = 31 - bx;
  const int myTile = (wave < 4) ? tHeavy : bx;
  const int rowb = myTile * 64 + (wave & 3) * 16;
  const int nch = tHeavy + 1;

  bf16x8 aq[4];
  {
    const short* qrow = qp + ((size_t)bh * NS + rowb + lr) * 128;
#pragma unroll
    for (int ks = 0; ks < 4; ks++)
      aq[ks] = *(const bf16x8*)&qrow[ks * 32 + lk * 8];
  }
  f32x4 acc[4], accS;
  accS = 0.f;
#pragma unroll
  for (int n = 0; n < 4; n++) acc[n] = 0.f;

  const short* kpb = kp + (size_t)bh * NS * 128;
  const short* vtb = vt + (size_t)bh * 64 * NS;
  const int krow = tid >> 3, kcol = (tid & 7) * 16;
  const int vrow = tid >> 3, vcol = (tid & 7) * 8;

  int4 rk0, rk1, rv;
  {
    const short* s = &kpb[(size_t)krow * 128 + kcol];
    rk0 = ((const int4*)s)[0]; rk1 = ((const int4*)s)[1];
    rv = *(const int4*)&vtb[(size_t)vrow * NS + vcol];
  }
  ((int4*)&kp_l[0][krow][kcol])[0] = rk0;
  ((int4*)&kp_l[0][krow][kcol])[1] = rk1;
  *(int4*)&v_l[0][vrow][vcol] = rv;
  __syncthreads();

  for (int c = 0; c < nch; c++) {
    const int kb = c * 64;
    const int cur = c & 1;
    const bool more = (c + 1) < nch;
    if (more) {
      const int kb2 = kb + 64;
      const short* s = &kpb[(size_t)(kb2 + krow) * 128 + kcol];
      rk0 = ((const int4*)s)[0]; rk1 = ((const int4*)s)[1];
      rv = *(const int4*)&vtb[(size_t)vrow * NS + kb2 + vcol];
    }
    if (rowb + 15 >= kb)
      attn_proc(aq, acc, accS, rowb, kb, kp_l[cur], v_l[cur], p_l[wave], lr, lk);
    if (more) {
      // writes target buffer cur^1 (nobody reads it this iteration); the single
      // barrier below both publishes these writes and closes the read phase.
      ((int4*)&kp_l[cur ^ 1][krow][kcol])[0] = rk0;
      ((int4*)&kp_l[cur ^ 1][krow][kcol])[1] = rk1;
      *(int4*)&v_l[cur ^ 1][vrow][vcol] = rv;
    }
    __syncthreads();
  }
  // softmax1 with m=0: denom = 1 + rowsum; accS[r] is lane-uniform (every col
  // of the ones-MFMA holds the same row sum) -> no cross-lane reduce needed.
  float inv[4];
#pragma unroll
  for (int r = 0; r < 4; r++) inv[r] = 1.f / (1.f + accS[r]);
#pragma unroll
  for (int nd = 0; nd < 4; nd++) {
#pragma unroll
    for (int r = 0; r < 4; r++) {
      const int d = nd * 16 + lr;
      const int row = rowb + lk * 4 + r;
      attn[(((size_t)b * NS + row) * NH + h) * NHD + d] = f2bf(acc[nd][r] * inv[r]);
    }
  }
}

// ==== LayerNorm with fused partial-sum + bias: x = A0 + A1 + badd + R ====
template<int RBF16, int OUTBF16>
__global__ __launch_bounds__(256) void k_ln3(const float* __restrict__ A0,
    const float* __restrict__ A1, const float* __restrict__ badd,
    const void* __restrict__ Rv, const float* __restrict__ g,
    const float* __restrict__ be, void* __restrict__ out) {
  const int row = blockIdx.x, tid = threadIdx.x;
  const float4 a0 = ((const float4*)(A0 + (size_t)row * ND))[tid];
  const float4 a1 = ((const float4*)(A1 + (size_t)row * ND))[tid];
  const float4 bd = ((const float4*)badd)[tid];
  float r0, r1, r2, r3;
  if (RBF16) {
    short4 rr = *(const short4*)((const short*)Rv + (size_t)row * ND + tid * 4);
    r0 = bf2f((unsigned short)rr.x); r1 = bf2f((unsigned short)rr.y);
    r2 = bf2f((unsigned short)rr.z); r3 = bf2f((unsigned short)rr.w);
  } else {
    const float4 rr = ((const float4*)((const float*)Rv + (size_t)row * ND))[tid];
    r0 = rr.x; r1 = rr.y; r2 = rr.z; r3 = rr.w;
  }
  const float x0 = a0.x + a1.x + bd.x + r0;
  const float x1 = a0.y + a1.y + bd.y + r1;
  const float x2 = a0.z + a1.z + bd.z + r2;
  const float x3 = a0.w + a1.w + bd.w + r3;
  float s = x0 + x1 + x2 + x3;
  float sq = x0 * x0 + x1 * x1 + x2 * x2 + x3 * x3;
#pragma unroll
  for (int off = 32; off; off >>= 1) {
    s += __shfl_xor(s, off);
    sq += __shfl_xor(sq, off);
  }
  __shared__ float ss[4], ssq[4];
  const int wave = tid >> 6, lane = tid & 63;
  if (lane == 0) { ss[wave] = s; ssq[wave] = sq; }
  __syncthreads();
  s = ss[0] + ss[1] + ss[2] + ss[3];
  sq = ssq[0] + ssq[1] + ssq[2] + ssq[3];
  const float mu = s * (1.f / (float)ND);
  const float var = sq * (1.f / (float)ND) - mu * mu;
  const float rstd = rsqrtf(var + 1e-5f);
  const float4 gg = ((const float4*)g)[tid];
  const float4 bb = ((const float4*)be)[tid];
  const float o0 = (x0 - mu) * rstd * gg.x + bb.x;
  const float o1 = (x1 - mu) * rstd * gg.y + bb.y;
  const float o2 = (x2 - mu) * rstd * gg.z + bb.z;
  const float o3 = (x3 - mu) * rstd * gg.w + bb.w;
  if (OUTBF16) {
    short4 ov = { f2bf(o0), f2bf(o1), f2bf(o2), f2bf(o3) };
    *(short4*)((short*)out + (size_t)row * ND + tid * 4) = ov;
  } else {
    float4 ov = { o0, o1, o2, o3 };
    ((float4*)((float*)out + (size_t)row * ND))[tid] = ov;
  }
}

extern "C" void kernel_launch(void* const* d_in, const int* in_sizes, int n_in,
                              void* d_out, int out_size, void* d_ws, size_t ws_size,
                              hipStream_t stream) {
  const float* x   = (const float*)d_in[0];
  const int*   pos = (const int*)d_in[1];
  const float* wq  = (const float*)d_in[2];
  const float* bq  = (const float*)d_in[3];
  const float* wk  = (const float*)d_in[4];
  const float* bk  = (const float*)d_in[5];
  const float* wv  = (const float*)d_in[6];
  const float* bv  = (const float*)d_in[7];
  const float* wo  = (const float*)d_in[8];
  const float* bo  = (const float*)d_in[9];
  const float* phb = (const float*)d_in[10];
  const float* w1  = (const float*)d_in[11];
  const float* b1  = (const float*)d_in[12];
  const float* w2  = (const float*)d_in[13];
  const float* b2  = (const float*)d_in[14];
  const float* g1  = (const float*)d_in[15];
  const float* be1 = (const float*)d_in[16];
  const float* g2  = (const float*)d_in[17];
  const float* be2 = (const float*)d_in[18];

  char* ws = (char*)d_ws;
  const size_t MB = 1024 * 1024;
  if (ws_size < 112 * MB) return;
  short* qb     = (short*)(ws + 0 * MB);    // 8MB
  short* kb     = (short*)(ws + 8 * MB);    // 8MB
  short* vb     = (short*)(ws + 16 * MB);   // 8MB
  short* qp     = (short*)(ws + 24 * MB);   // 16MB
  short* kp     = (short*)(ws + 40 * MB);   // 16MB
  short* vt     = (short*)(ws + 56 * MB);   // 8MB
  short* xb     = (short*)(ws + 64 * MB);   // 8MB
  short* attnb  = (short*)(ws + 72 * MB);   // 8MB
  float* attnC0 = (float*)(ws + 0 * MB);    // 16MB (over qb+kb, dead after pope)
  float* attnC1 = (float*)(ws + 24 * MB);   // 16MB (over qp, dead after attn)
  short* hb     = (short*)(ws + 16 * MB);   // 8MB (over vb, dead after prep_v)
  short* ffh    = (short*)(ws + 40 * MB);   // 32MB (over kp+vt+xb, dead)
  float* ffC0   = (float*)(ws + 72 * MB);   // 16MB (over attnb, dead after wo)
  float* ffC1   = (float*)(ws + 0 * MB);    // 16MB (over attnC0, dead after ln1)
  short* wqT    = (short*)(ws + 88 * MB);
  short* wkT    = (short*)(ws + 90 * MB);
  short* wvT    = (short*)(ws + 92 * MB);
  short* woT    = (short*)(ws + 94 * MB);
  short* w1T    = (short*)(ws + 96 * MB);   // 8MB [DFF][D]
  short* w2T    = (short*)(ws + 104 * MB);  // 8MB [D][DFF]

  dim3 blk(256);
  // weight transposes + x->bf16, one dispatch
  k_prep<<<dim3(5120), blk, 0, stream>>>(wq, wk, wv, wo, w1, w2, x,
                                         wqT, wkT, wvT, woT, w1T, w2T, xb);
  // QKV: one merged launch, 768 blocks co-resident
  k_gemm3<<<dim3(ND / 128, (NB * NS) / 128, 3), blk, 0, stream>>>(
      xb, wqT, wkT, wvT, bq, bk, bv, qb, kb, vb);
  // PoPE + V transpose, one dispatch
  k_pope_pv<<<dim3(3072), blk, 0, stream>>>(qb, kb, vb, pos, phb, qp, kp, vt);
  // attention: 512 blocks, 2/CU
  k_attn3<<<dim3(16, NB * NH), dim3(512), 0, stream>>>(qp, kp, vt, attnb);
  // wo: split-K (z=2), partials summed in ln1
  k_gemm_sk<<<dim3(ND / 128, (NB * NS) / 128, 2), blk, 0, stream>>>(
      attnb, woT, attnC0, attnC1, NB * NS, ND, ND);
  k_ln3<0, 1><<<dim3(NB * NS), blk, 0, stream>>>(attnC0, attnC1, bo, x, g1, be1, hb);
  // ffn1: full-K (grid 1024 blocks already)
  k_gemm<1, 1><<<dim3(NDFF / 128, (NB * NS) / 128), blk, 0, stream>>>(
      hb, w1T, b1, ffh, NB * NS, NDFF, ND);
  // ffn2: split-K (z=2), partials + b2 summed in ln2
  k_gemm_sk<<<dim3(ND / 128, (NB * NS) / 128, 2), blk, 0, stream>>>(
      ffh, w2T, ffC0, ffC1, NB * NS, ND, NDFF);
  k_ln3<1, 0><<<dim3(NB * NS), blk, 0, stream>>>(ffC0, ffC1, b2, hb, g2, be2, (float*)d_out);
}

// Round 11
// 264.640 us; speedup vs baseline: 10.7779x; 1.0414x over previous
//
#include <hip/hip_runtime.h>
#include <hip/hip_bf16.h>
#include <math.h>

#define NB 2
#define NS 2048
#define ND 1024
#define NH 16
#define NHD 64
#define NDFF 4096

typedef __attribute__((ext_vector_type(4))) float f32x4;
typedef __attribute__((ext_vector_type(8))) short bf16x8;

__device__ __forceinline__ short f2bf(float f) {
  union { float f; unsigned u; } v; v.f = f;
  unsigned r = v.u + 0x7fffu + ((v.u >> 16) & 1u);
  return (short)(r >> 16);
}
__device__ __forceinline__ float bf2f(unsigned short u) {
  union { unsigned u; float f; } v; v.u = ((unsigned)u) << 16; return v.f;
}
__device__ __forceinline__ float softplus_f(float x) {
  return fmaxf(x, 0.f) + log1pf(__expf(-fabsf(x)));
}
// async global->LDS, 16B per lane; LDS dest wave-uniform (HW adds lane*16)
__device__ __forceinline__ void gl16(const short* g, short* l) {
  __builtin_amdgcn_global_load_lds(
      (const __attribute__((address_space(1))) void*)g,
      (__attribute__((address_space(3))) void*)l, 16, 0, 0);
}
// XCD-chunked bijective block remap (T1): each XCD owns a contiguous row-slab.
__device__ __forceinline__ void xcd_map(int& row0, int& col0) {
  const int gx = gridDim.x, gy = gridDim.y;
  const int bid = blockIdx.y * gx + blockIdx.x;
  const int rows_px = gy >> 3;
  const int xcd = bid & 7, l = bid >> 3;
  row0 = (xcd * rows_px + (l % rows_px)) * 128;
  col0 = (l / rows_px) * 128;
}

// ============ prep: all 6 weight transposes + x->bf16 in ONE dispatch ============
// [0,1024): wq/wk/wv/wo; [1024,2048): w1; [2048,3072): w2; [3072,5120): xb.
__global__ __launch_bounds__(256) void k_prep(
    const float* __restrict__ wq, const float* __restrict__ wk,
    const float* __restrict__ wv, const float* __restrict__ wo,
    const float* __restrict__ w1, const float* __restrict__ w2,
    const float* __restrict__ x,
    short* __restrict__ wqT, short* __restrict__ wkT, short* __restrict__ wvT,
    short* __restrict__ woT, short* __restrict__ w1T, short* __restrict__ w2T,
    short* __restrict__ xb) {
  __shared__ float t[64][65];
  const int bid = blockIdx.x;
  if (bid >= 3072) {
    const int i = (bid - 3072) * 256 + threadIdx.x;
    const float4 a = ((const float4*)x)[i * 2];
    const float4 b = ((const float4*)x)[i * 2 + 1];
    short tmp[8] = { f2bf(a.x), f2bf(a.y), f2bf(a.z), f2bf(a.w),
                     f2bf(b.x), f2bf(b.y), f2bf(b.z), f2bf(b.w) };
    *(int4*)&xb[(size_t)i * 8] = *(const int4*)tmp;
    return;
  }
  const float* W; short* Wt; int K, N, local;
  if (bid < 1024) {
    const int wsel = bid >> 8; local = bid & 255;
    W  = wsel == 0 ? wq  : wsel == 1 ? wk  : wsel == 2 ? wv  : wo;
    Wt = wsel == 0 ? wqT : wsel == 1 ? wkT : wsel == 2 ? wvT : woT;
    K = ND; N = ND;
  } else if (bid < 2048) {
    local = bid - 1024; W = w1; Wt = w1T; K = ND; N = NDFF;
  } else {
    local = bid - 2048; W = w2; Wt = w2T; K = NDFF; N = ND;
  }
  const int nx = N >> 6;
  const int n0 = (local % nx) * 64, k0 = (local / nx) * 64;
  for (int i = threadIdx.x; i < 4096; i += 256) {
    const int r = i >> 6, c = i & 63;
    t[r][c] = W[(size_t)(k0 + r) * N + n0 + c];
  }
  __syncthreads();
  for (int i = threadIdx.x; i < 4096; i += 256) {
    const int r = i >> 6, c = i & 63;
    Wt[(size_t)(n0 + r) * K + k0 + c] = f2bf(t[c][r]);
  }
}

// ============ PoPE + V-transpose in ONE dispatch ============
// [0,2048): pope elementwise (q side pre-scaled by 1/sqrt(128)*log2e so the
// attention softmax is a single v_exp_f32); [2048,3072): prep_v tiles.
__global__ __launch_bounds__(256) void k_pope_pv(const short* __restrict__ qb,
    const short* __restrict__ kb, const short* __restrict__ vb,
    const int* __restrict__ positions, const float* __restrict__ phb,
    short* __restrict__ qp, short* __restrict__ kp, short* __restrict__ vt) {
  __shared__ short t[64][72];
  const int bid = blockIdx.x;
  if (bid < 2048) {
    const size_t i8 = ((size_t)bid * 256 + threadIdx.x) * 8;
    const int d0 = (int)(i8 & 63);
    const int h  = (int)((i8 >> 6) & 15);
    const int s  = (int)((i8 >> 10) & 2047);
    const int b  = (int)(i8 >> 21);
    const float posf = (float)positions[s];
    const float QSC = 0.12751743305610407f;  // 1/sqrt(128) * log2(e)
    int4 qv = *(const int4*)&qb[i8];
    int4 kv = *(const int4*)&kb[i8];
    const short* qs = (const short*)&qv;
    const short* ks = (const short*)&kv;
    short qc[8], qsn[8], kc[8], ksn[8];
#pragma unroll
    for (int j = 0; j < 8; j++) {
      const int d = d0 + j;
      const float freq = __expf(-(float)d * (float)(9.210340371976184 / 64.0));
      const float muq = softplus_f(bf2f((unsigned short)qs[j])) * QSC;
      const float muk = softplus_f(bf2f((unsigned short)ks[j]));
      float cb = phb[h * 64 + d];
      cb = fminf(fmaxf(cb, -6.283185307179586f), 0.f);
      float snq, csq, snk, csk;
      __sincosf(posf * freq, &snq, &csq);
      __sincosf(posf * freq + cb, &snk, &csk);
      qc[j] = f2bf(muq * csq); qsn[j] = f2bf(muq * snq);
      kc[j] = f2bf(muk * csk); ksn[j] = f2bf(muk * snk);
    }
    const size_t o = (((size_t)(b * 16 + h) * NS + s) * 128) + d0;
    *(int4*)&qp[o] = *(const int4*)qc;
    *(int4*)&qp[o + 64] = *(const int4*)qsn;
    *(int4*)&kp[o] = *(const int4*)kc;
    *(int4*)&kp[o + 64] = *(const int4*)ksn;
  } else {
    const int local = bid - 2048;
    const int bh = local >> 5, b = bh >> 4, h = bh & 15;
    const int s0 = (local & 31) * 64;
    for (int i = threadIdx.x; i < 512; i += 256) {
      const int sl = i >> 3, d8 = (i & 7) * 8;
      int4 vv = *(const int4*)&vb[((size_t)(b * NS + s0 + sl) * NH + h) * NHD + d8];
      const short* sp = (const short*)&vv;
#pragma unroll
      for (int j = 0; j < 8; j++) t[d8 + j][sl] = sp[j];
    }
    __syncthreads();
    for (int i = threadIdx.x; i < 512; i += 256) {
      const int d = i >> 3, c8 = (i & 7) * 8;
      *(int4*)&vt[((size_t)bh * 64 + d) * NS + s0 + c8] = *(const int4*)&t[d][c8];
    }
  }
}

// ==== GEMM core: 2-phase double-buffered, global_load_lds, prefetch-first ====
#define BKK 32

__device__ __forceinline__ void gemm_core(const short* __restrict__ A,
    const short* __restrict__ Wt, const int K, const int kbeg, const int kend,
    const int row0, const int col0, short* lsA, short* lsB, f32x4 acc[4][4]) {
  const int tid = threadIdx.x;
  const int lane = tid & 63, wave = tid >> 6;
  const int lr = lane & 15, lk8 = (lane >> 4) << 3;
  const int wr = wave >> 1, wc = wave & 1;
  const int srow = lane >> 2, scol = (lane & 3) << 3;
  const int wbase = wave * 32;
#pragma unroll
  for (int m = 0; m < 4; m++)
#pragma unroll
    for (int n = 0; n < 4; n++) acc[m][n] = 0.f;
  const short* gA0 = &A[(size_t)(row0 + wbase + srow) * K + scol];
  const short* gA1 = gA0 + (size_t)16 * K;
  const short* gB0 = &Wt[(size_t)(col0 + wbase + srow) * K + scol];
  const short* gB1 = gB0 + (size_t)16 * K;
  short* const lA0 = lsA + wbase * 32;
  short* const lB0 = lsB + wbase * 32;
  auto stage = [&](int buf, int kk) {
    const int o = buf * 4096;
    gl16(gA0 + kk, lA0 + o);
    gl16(gA1 + kk, lA0 + o + 512);
    gl16(gB0 + kk, lB0 + o);
    gl16(gB1 + kk, lB0 + o + 512);
  };
  stage(0, kbeg);
  __syncthreads();
  int cur = 0;
  for (int k0 = kbeg; k0 < kend; k0 += BKK) {
    if (k0 + BKK < kend) stage(cur ^ 1, k0 + BKK);  // issue-early: overlaps compute
    const short* la = lsA + cur * 4096;
    const short* lb = lsB + cur * 4096;
    bf16x8 af[4], bf_[4];
#pragma unroll
    for (int m = 0; m < 4; m++)
      af[m] = *(const bf16x8*)&la[(wr * 64 + m * 16 + lr) * 32 + lk8];
#pragma unroll
    for (int n = 0; n < 4; n++)
      bf_[n] = *(const bf16x8*)&lb[(wc * 64 + n * 16 + lr) * 32 + lk8];
#pragma unroll
    for (int m = 0; m < 4; m++)
#pragma unroll
      for (int n = 0; n < 4; n++)
        acc[m][n] = __builtin_amdgcn_mfma_f32_16x16x32_bf16(af[m], bf_[n], acc[m][n], 0, 0, 0);
    __syncthreads();  // drains this iter's prefetch (vmcnt) + read-done (lgkm)
    cur ^= 1;
  }
}

template<int RELU, int OUTBF16>
__global__ __launch_bounds__(256) void k_gemm(const short* __restrict__ A,
    const short* __restrict__ Wt, const float* __restrict__ bias,
    void* __restrict__ C, int M, int N, int K) {
  __shared__ short lsA[2 * 4096], lsB[2 * 4096];
  f32x4 acc[4][4];
  int row0, col0;
  xcd_map(row0, col0);
  gemm_core(A, Wt, K, 0, K, row0, col0, lsA, lsB, acc);
  const int lane = threadIdx.x & 63, wave = threadIdx.x >> 6;
  const int lr = lane & 15, r4 = (lane >> 4) << 2;
  const int wr = wave >> 1, wc = wave & 1;
#pragma unroll
  for (int m = 0; m < 4; m++) {
#pragma unroll
    for (int n = 0; n < 4; n++) {
      const int col = col0 + wc * 64 + n * 16 + lr;
      const float bv = bias[col];
#pragma unroll
      for (int r = 0; r < 4; r++) {
        const int row = row0 + wr * 64 + m * 16 + r4 + r;
        float val = acc[m][n][r] + bv;
        if (RELU) val = fmaxf(val, 0.f);
        if (OUTBF16) ((short*)C)[(size_t)row * N + col] = f2bf(val);
        else ((float*)C)[(size_t)row * N + col] = val;
      }
    }
  }
}

// QKV merged: grid.z picks weight/bias/output. bf16 out.
__global__ __launch_bounds__(256) void k_gemm3(const short* __restrict__ xb,
    const short* __restrict__ wqT, const short* __restrict__ wkT,
    const short* __restrict__ wvT, const float* __restrict__ bq,
    const float* __restrict__ bk, const float* __restrict__ bv,
    short* __restrict__ qb, short* __restrict__ kb, short* __restrict__ vb) {
  __shared__ short lsA[2 * 4096], lsB[2 * 4096];
  const int z = blockIdx.z;
  const short* Wt = (z == 0) ? wqT : (z == 1) ? wkT : wvT;
  const float* bias = (z == 0) ? bq : (z == 1) ? bk : bv;
  short* C = (z == 0) ? qb : (z == 1) ? kb : vb;
  f32x4 acc[4][4];
  int row0, col0;
  xcd_map(row0, col0);
  gemm_core(xb, Wt, ND, 0, ND, row0, col0, lsA, lsB, acc);
  const int lane = threadIdx.x & 63, wave = threadIdx.x >> 6;
  const int lr = lane & 15, r4 = (lane >> 4) << 2;
  const int wr = wave >> 1, wc = wave & 1;
#pragma unroll
  for (int m = 0; m < 4; m++) {
#pragma unroll
    for (int n = 0; n < 4; n++) {
      const int col = col0 + wc * 64 + n * 16 + lr;
      const float bvs = bias[col];
#pragma unroll
      for (int r = 0; r < 4; r++) {
        const int row = row0 + wr * 64 + m * 16 + r4 + r;
        C[(size_t)row * ND + col] = f2bf(acc[m][n][r] + bvs);
      }
    }
  }
}

// Split-K GEMM: grid.z=2 halves of K; writes unbiased f32 partials to C0/C1.
__global__ __launch_bounds__(256) void k_gemm_sk(const short* __restrict__ A,
    const short* __restrict__ Wt, float* __restrict__ C0, float* __restrict__ C1,
    int M, int N, int K) {
  __shared__ short lsA[2 * 4096], lsB[2 * 4096];
  f32x4 acc[4][4];
  const int z = blockIdx.z;
  const int khalf = K >> 1, kbeg = z * khalf, kend = kbeg + khalf;
  int row0, col0;
  xcd_map(row0, col0);
  gemm_core(A, Wt, K, kbeg, kend, row0, col0, lsA, lsB, acc);
  float* C = z ? C1 : C0;
  const int lane = threadIdx.x & 63, wave = threadIdx.x >> 6;
  const int lr = lane & 15, r4 = (lane >> 4) << 2;
  const int wr = wave >> 1, wc = wave & 1;
#pragma unroll
  for (int m = 0; m < 4; m++) {
#pragma unroll
    for (int n = 0; n < 4; n++) {
      const int col = col0 + wc * 64 + n * 16 + lr;
#pragma unroll
      for (int r = 0; r < 4; r++) {
        const int row = row0 + wr * 64 + m * 16 + r4 + r;
        C[(size_t)row * N + col] = acc[m][n][r];
      }
    }
  }
}

// ============ Attention (causal, softmax1), MFMA flash ============
// m=0 fixed (softmax1 is shift-invariant; scores provably < ~6, no overflow).
// q_p carries scale*log2e -> p = v_exp_f32(s) directly. P truncated to bf16
// (<=0.8% rel err); lsum accumulates the SAME truncated value (consistent).
__device__ __forceinline__ void attn_proc(const bf16x8 aq[4], f32x4 acc_o[4],
    float l_p[4], const int rowb, const int kb,
    const short (*kpl)[136], const short (*vl)[72], short (*pl)[72],
    const int lr, const int lk) {
  f32x4 s_acc[4];
#pragma unroll
  for (int n = 0; n < 4; n++) s_acc[n] = 0.f;
#pragma unroll
  for (int ks = 0; ks < 4; ks++) {
    bf16x8 bk_[4];
#pragma unroll
    for (int n = 0; n < 4; n++)
      bk_[n] = *(const bf16x8*)&kpl[n * 16 + lr][ks * 32 + lk * 8];
#pragma unroll
    for (int n = 0; n < 4; n++)
      s_acc[n] = __builtin_amdgcn_mfma_f32_16x16x32_bf16(aq[ks], bk_[n], s_acc[n], 0, 0, 0);
  }
  const bool domask = (kb + 63 > rowb);  // wave-uniform: diagonal-crossing chunk
#pragma unroll
  for (int n = 0; n < 4; n++) {
#pragma unroll
    for (int r = 0; r < 4; r++) {
      float p = __builtin_amdgcn_exp2f(s_acc[n][r]);  // raw v_exp_f32
      if (domask) {
        const int rel = rowb + lk * 4 + r - kb;
        p = (n * 16 + lr <= rel) ? p : 0.f;
      }
      unsigned pu = __float_as_uint(p) & 0xFFFF0000u;  // truncate to bf16
      l_p[r] += __uint_as_float(pu);
      pl[lk * 4 + r][n * 16 + lr] = (short)(pu >> 16);
    }
  }
#pragma unroll
  for (int ks = 0; ks < 2; ks++) {
    const bf16x8 ap = *(const bf16x8*)&pl[lr][ks * 32 + lk * 8];
    bf16x8 bv_[4];
#pragma unroll
    for (int nd = 0; nd < 4; nd++)
      bv_[nd] = *(const bf16x8*)&vl[nd * 16 + lr][ks * 32 + lk * 8];
#pragma unroll
    for (int nd = 0; nd < 4; nd++)
      acc_o[nd] = __builtin_amdgcn_mfma_f32_16x16x32_bf16(ap, bv_[nd], acc_o[nd], 0, 0, 0);
  }
}

// grid (16, 32), 512 threads, 2 blocks/CU. XCD-grouped remap: each XCD owns
// 4 whole (b,h) heads so one head's K/V panel lives in ONE L2.
// Block: waves 0-3 own 64-row tile tH=31-bx, waves 4-7 own tile bx.
__global__ __launch_bounds__(512) void k_attn3(
    const short* __restrict__ qp, const short* __restrict__ kp,
    const short* __restrict__ vt, short* __restrict__ attn) {
  __shared__ short kp_l[2][64][136];
  __shared__ short v_l[2][64][72];
  __shared__ short p_l[8][16][72];
  const int bid = blockIdx.y * gridDim.x + blockIdx.x;
  const int xcd = bid & 7, o = bid >> 3;
  const int bh = xcd * 4 + (o >> 4);
  const int bx = o & 15;
  const int b = bh >> 4, h = bh & 15;
  const int tid = threadIdx.x, wave = tid >> 6, lane = tid & 63;
  const int lr = lane & 15, lk = lane >> 4;
  const int tHeavy = 31 - bx;
  const int myTile = (wave < 4) ? tHeavy : bx;
  const int rowb = myTile * 64 + (wave & 3) * 16;
  const int nch = tHeavy + 1;

  bf16x8 aq[4];
  {
    const short* qrow = qp + ((size_t)bh * NS + rowb + lr) * 128;
#pragma unroll
    for (int ks = 0; ks < 4; ks++)
      aq[ks] = *(const bf16x8*)&qrow[ks * 32 + lk * 8];
  }
  f32x4 acc[4];
  float lsum[4];
#pragma unroll
  for (int r = 0; r < 4; r++) lsum[r] = 0.f;
#pragma unroll
  for (int n = 0; n < 4; n++) acc[n] = 0.f;

  const short* kpb = kp + (size_t)bh * NS * 128;
  const short* vtb = vt + (size_t)bh * 64 * NS;
  const int krow = tid >> 3, kcol = (tid & 7) * 16;
  const int vrow = tid >> 3, vcol = (tid & 7) * 8;

  int4 rk0, rk1, rv;
  {
    const short* s = &kpb[(size_t)krow * 128 + kcol];
    rk0 = ((const int4*)s)[0]; rk1 = ((const int4*)s)[1];
    rv = *(const int4*)&vtb[(size_t)vrow * NS + vcol];
  }
  ((int4*)&kp_l[0][krow][kcol])[0] = rk0;
  ((int4*)&kp_l[0][krow][kcol])[1] = rk1;
  *(int4*)&v_l[0][vrow][vcol] = rv;
  __syncthreads();

  for (int c = 0; c < nch; c++) {
    const int kb = c * 64;
    const int cur = c & 1;
    const bool more = (c + 1) < nch;
    if (more) {
      const int kb2 = kb + 64;
      const short* s = &kpb[(size_t)(kb2 + krow) * 128 + kcol];
      rk0 = ((const int4*)s)[0]; rk1 = ((const int4*)s)[1];
      rv = *(const int4*)&vtb[(size_t)vrow * NS + kb2 + vcol];
    }
    if (rowb + 15 >= kb)
      attn_proc(aq, acc, lsum, rowb, kb, kp_l[cur], v_l[cur], p_l[wave], lr, lk);
    if (more) {
      // writes target buffer cur^1 (nobody reads it this iteration); the single
      // barrier below both publishes these writes and closes the read phase.
      ((int4*)&kp_l[cur ^ 1][krow][kcol])[0] = rk0;
      ((int4*)&kp_l[cur ^ 1][krow][kcol])[1] = rk1;
      *(int4*)&v_l[cur ^ 1][vrow][vcol] = rv;
    }
    __syncthreads();
  }
  // epilogue: single cross-lane reduce of the deferred row sums (lane bits 0-3)
#pragma unroll
  for (int r = 0; r < 4; r++) {
    float s = lsum[r];
#pragma unroll
    for (int off = 8; off; off >>= 1) s += __shfl_xor(s, off);
    lsum[r] = 1.f / (1.f + s);   // softmax1 with m=0: denom = 1 + sum
  }
#pragma unroll
  for (int nd = 0; nd < 4; nd++) {
#pragma unroll
    for (int r = 0; r < 4; r++) {
      const int d = nd * 16 + lr;
      const int row = rowb + lk * 4 + r;
      attn[(((size_t)b * NS + row) * NH + h) * NHD + d] = f2bf(acc[nd][r] * lsum[r]);
    }
  }
}

// ==== LayerNorm with fused partial-sum + bias: x = A0 + A1 + badd + R ====
template<int RBF16, int OUTBF16>
__global__ __launch_bounds__(256) void k_ln3(const float* __restrict__ A0,
    const float* __restrict__ A1, const float* __restrict__ badd,
    const void* __restrict__ Rv, const float* __restrict__ g,
    const float* __restrict__ be, void* __restrict__ out) {
  const int row = blockIdx.x, tid = threadIdx.x;
  const float4 a0 = ((const float4*)(A0 + (size_t)row * ND))[tid];
  const float4 a1 = ((const float4*)(A1 + (size_t)row * ND))[tid];
  const float4 bd = ((const float4*)badd)[tid];
  float r0, r1, r2, r3;
  if (RBF16) {
    short4 rr = *(const short4*)((const short*)Rv + (size_t)row * ND + tid * 4);
    r0 = bf2f((unsigned short)rr.x); r1 = bf2f((unsigned short)rr.y);
    r2 = bf2f((unsigned short)rr.z); r3 = bf2f((unsigned short)rr.w);
  } else {
    const float4 rr = ((const float4*)((const float*)Rv + (size_t)row * ND))[tid];
    r0 = rr.x; r1 = rr.y; r2 = rr.z; r3 = rr.w;
  }
  const float x0 = a0.x + a1.x + bd.x + r0;
  const float x1 = a0.y + a1.y + bd.y + r1;
  const float x2 = a0.z + a1.z + bd.z + r2;
  const float x3 = a0.w + a1.w + bd.w + r3;
  float s = x0 + x1 + x2 + x3;
  float sq = x0 * x0 + x1 * x1 + x2 * x2 + x3 * x3;
#pragma unroll
  for (int off = 32; off; off >>= 1) {
    s += __shfl_xor(s, off);
    sq += __shfl_xor(sq, off);
  }
  __shared__ float ss[4], ssq[4];
  const int wave = tid >> 6, lane = tid & 63;
  if (lane == 0) { ss[wave] = s; ssq[wave] = sq; }
  __syncthreads();
  s = ss[0] + ss[1] + ss[2] + ss[3];
  sq = ssq[0] + ssq[1] + ssq[2] + ssq[3];
  const float mu = s * (1.f / (float)ND);
  const float var = sq * (1.f / (float)ND) - mu * mu;
  const float rstd = rsqrtf(var + 1e-5f);
  const float4 gg = ((const float4*)g)[tid];
  const float4 bb = ((const float4*)be)[tid];
  const float o0 = (x0 - mu) * rstd * gg.x + bb.x;
  const float o1 = (x1 - mu) * rstd * gg.y + bb.y;
  const float o2 = (x2 - mu) * rstd * gg.z + bb.z;
  const float o3 = (x3 - mu) * rstd * gg.w + bb.w;
  if (OUTBF16) {
    short4 ov = { f2bf(o0), f2bf(o1), f2bf(o2), f2bf(o3) };
    *(short4*)((short*)out + (size_t)row * ND + tid * 4) = ov;
  } else {
    float4 ov = { o0, o1, o2, o3 };
    ((float4*)((float*)out + (size_t)row * ND))[tid] = ov;
  }
}

extern "C" void kernel_launch(void* const* d_in, const int* in_sizes, int n_in,
                              void* d_out, int out_size, void* d_ws, size_t ws_size,
                              hipStream_t stream) {
  const float* x   = (const float*)d_in[0];
  const int*   pos = (const int*)d_in[1];
  const float* wq  = (const float*)d_in[2];
  const float* bq  = (const float*)d_in[3];
  const float* wk  = (const float*)d_in[4];
  const float* bk  = (const float*)d_in[5];
  const float* wv  = (const float*)d_in[6];
  const float* bv  = (const float*)d_in[7];
  const float* wo  = (const float*)d_in[8];
  const float* bo  = (const float*)d_in[9];
  const float* phb = (const float*)d_in[10];
  const float* w1  = (const float*)d_in[11];
  const float* b1  = (const float*)d_in[12];
  const float* w2  = (const float*)d_in[13];
  const float* b2  = (const float*)d_in[14];
  const float* g1  = (const float*)d_in[15];
  const float* be1 = (const float*)d_in[16];
  const float* g2  = (const float*)d_in[17];
  const float* be2 = (const float*)d_in[18];

  char* ws = (char*)d_ws;
  const size_t MB = 1024 * 1024;
  if (ws_size < 112 * MB) return;
  short* qb     = (short*)(ws + 0 * MB);    // 8MB
  short* kb     = (short*)(ws + 8 * MB);    // 8MB
  short* vb     = (short*)(ws + 16 * MB);   // 8MB
  short* qp     = (short*)(ws + 24 * MB);   // 16MB
  short* kp     = (short*)(ws + 40 * MB);   // 16MB
  short* vt     = (short*)(ws + 56 * MB);   // 8MB
  short* xb     = (short*)(ws + 64 * MB);   // 8MB
  short* attnb  = (short*)(ws + 72 * MB);   // 8MB
  float* attnC0 = (float*)(ws + 0 * MB);    // 16MB (over qb+kb, dead after pope)
  float* attnC1 = (float*)(ws + 24 * MB);   // 16MB (over qp, dead after attn)
  short* hb     = (short*)(ws + 16 * MB);   // 8MB (over vb, dead after prep_v)
  short* ffh    = (short*)(ws + 40 * MB);   // 32MB (over kp+vt+xb, dead)
  float* ffC0   = (float*)(ws + 72 * MB);   // 16MB (over attnb, dead after wo)
  float* ffC1   = (float*)(ws + 0 * MB);    // 16MB (over attnC0, dead after ln1)
  short* wqT    = (short*)(ws + 88 * MB);
  short* wkT    = (short*)(ws + 90 * MB);
  short* wvT    = (short*)(ws + 92 * MB);
  short* woT    = (short*)(ws + 94 * MB);
  short* w1T    = (short*)(ws + 96 * MB);   // 8MB [DFF][D]
  short* w2T    = (short*)(ws + 104 * MB);  // 8MB [D][DFF]

  dim3 blk(256);
  // weight transposes + x->bf16, one dispatch
  k_prep<<<dim3(5120), blk, 0, stream>>>(wq, wk, wv, wo, w1, w2, x,
                                         wqT, wkT, wvT, woT, w1T, w2T, xb);
  // QKV: one merged launch, 768 blocks co-resident
  k_gemm3<<<dim3(ND / 128, (NB * NS) / 128, 3), blk, 0, stream>>>(
      xb, wqT, wkT, wvT, bq, bk, bv, qb, kb, vb);
  // PoPE + V transpose, one dispatch
  k_pope_pv<<<dim3(3072), blk, 0, stream>>>(qb, kb, vb, pos, phb, qp, kp, vt);
  // attention: 512 blocks, 2/CU, XCD-grouped heads
  k_attn3<<<dim3(16, NB * NH), dim3(512), 0, stream>>>(qp, kp, vt, attnb);
  // wo: split-K (z=2), partials summed in ln1
  k_gemm_sk<<<dim3(ND / 128, (NB * NS) / 128, 2), blk, 0, stream>>>(
      attnb, woT, attnC0, attnC1, NB * NS, ND, ND);
  k_ln3<0, 1><<<dim3(NB * NS), blk, 0, stream>>>(attnC0, attnC1, bo, x, g1, be1, hb);
  // ffn1: full-K (grid 1024 blocks already)
  k_gemm<1, 1><<<dim3(NDFF / 128, (NB * NS) / 128), blk, 0, stream>>>(
      hb, w1T, b1, ffh, NB * NS, NDFF, ND);
  // ffn2: split-K (z=2), partials + b2 summed in ln2
  k_gemm_sk<<<dim3(ND / 128, (NB * NS) / 128, 2), blk, 0, stream>>>(
      ffh, w2T, ffC0, ffC1, NB * NS, ND, NDFF);
  k_ln3<1, 0><<<dim3(NB * NS), blk, 0, stream>>>(ffC0, ffC1, b2, hb, g2, be2, (float*)d_out);
}